// Round 1
// baseline (5061.542 us; speedup 1.0000x reference)
//
#include <hip/hip_runtime.h>
#include <hip/hip_bf16.h>

// Whisper decoder step: L=6, D=768, H=12, FF=3072, V=51865, A=1500, B=32, S=8
#define HH 12
#define DD 768
#define DHH 64
#define FFD 3072
#define AAn 1500
#define BBn 32
#define SSn 8
#define RR 256          // B*S token rows
#define VV 51865
#define VPAD 51968      // 406*128

#define OP_BIAS 1
#define OP_GELU 2
#define OP_RES  4
#define OP_BF16 8

typedef float f32x4 __attribute__((ext_vector_type(4)));
typedef short s16x8 __attribute__((ext_vector_type(8)));

__device__ __forceinline__ unsigned short f2bf(float f) {
  union { float f; unsigned int u; } v; v.f = f;
  unsigned int r = (v.u + 0x7fffu + ((v.u >> 16) & 1u)) >> 16;
  return (unsigned short)r;
}
__device__ __forceinline__ float bf2f(unsigned short u) {
  union { unsigned int u; float f; } v; v.u = ((unsigned int)u) << 16;
  return v.f;
}

__device__ __forceinline__ void gld_lds16(const unsigned short* g, unsigned short* l) {
  __builtin_amdgcn_global_load_lds(
      (const __attribute__((address_space(1))) void*)g,
      (__attribute__((address_space(3))) void*)l, 16, 0, 0);
}

// ---------------- embedding ----------------
__global__ void embed_k(const int* __restrict__ toks, const float* __restrict__ emb,
                        const float* __restrict__ pos, float* __restrict__ x) {
  int r = blockIdx.x;            // 0..255 = b*8+s
  int s = r & 7;
  int t = toks[r];
  for (int c = threadIdx.x; c < DD; c += 256)
    x[(size_t)r * DD + c] = emb[(size_t)t * DD + c] + pos[(size_t)s * DD + c];
}

// ---------------- f32 -> bf16 convert (with zero pad) ----------------
__global__ void cvt_bf16(const float* __restrict__ src, unsigned short* __restrict__ dst,
                         long long n_src, long long n_tot) {
  long long i = (long long)blockIdx.x * 256 + threadIdx.x;
  long long stride = (long long)gridDim.x * 256;
  for (; i < n_tot; i += stride)
    dst[i] = (i < n_src) ? f2bf(src[i]) : (unsigned short)0;
}

// ---------------- LayerNorm -> bf16 ----------------
__global__ __launch_bounds__(256) void ln_to_bf16(
    const float* __restrict__ x, const float* __restrict__ w,
    const float* __restrict__ b, unsigned short* __restrict__ out) {
  int row = blockIdx.x;
  const float* xr = x + (size_t)row * DD;
  int t = threadIdx.x;
  float v0 = xr[t], v1 = xr[t + 256], v2 = xr[t + 512];
  float s = v0 + v1 + v2;
  for (int o = 32; o; o >>= 1) s += __shfl_down(s, o);
  __shared__ float red[4], red2[4];
  int wid = t >> 6, lane = t & 63;
  if (!lane) red[wid] = s;
  __syncthreads();
  float mean = (red[0] + red[1] + red[2] + red[3]) * (1.f / DD);
  float d0 = v0 - mean, d1 = v1 - mean, d2 = v2 - mean;
  float s2 = d0 * d0 + d1 * d1 + d2 * d2;
  for (int o = 32; o; o >>= 1) s2 += __shfl_down(s2, o);
  if (!lane) red2[wid] = s2;
  __syncthreads();
  float var = (red2[0] + red2[1] + red2[2] + red2[3]) * (1.f / DD);
  float rstd = rsqrtf(var + 1e-5f);
  out[(size_t)row * DD + t]       = f2bf(d0 * rstd * w[t] + b[t]);
  out[(size_t)row * DD + t + 256] = f2bf(d1 * rstd * w[t + 256] + b[t + 256]);
  out[(size_t)row * DD + t + 512] = f2bf(d2 * rstd * w[t + 512] + b[t + 512]);
}

// ---------------- transpose + convert: W[R][C] f32 -> Wt[C][R] bf16 ----------------
__global__ __launch_bounds__(256) void transpose_to_bf16(
    const float* __restrict__ W, unsigned short* __restrict__ Wt, int R, int C) {
  __shared__ unsigned short tile[32][33];
  int c0 = blockIdx.x * 32, r0 = blockIdx.y * 32;
  int tx = threadIdx.x & 31, ty = threadIdx.x >> 5;   // ty 0..7
  #pragma unroll
  for (int i = 0; i < 32; i += 8)
    tile[ty + i][tx] = f2bf(W[(size_t)(r0 + ty + i) * C + (c0 + tx)]);
  __syncthreads();
  #pragma unroll
  for (int i = 0; i < 32; i += 8)
    Wt[(size_t)(c0 + ty + i) * R + (r0 + tx)] = tile[tx][ty + i];
}

// ---------------- GEMM: C[M][Nout] = A[M][K](bf16) * Bt[N][K](bf16)^T ----------------
// grid = (M/128, Npad/128), block = 256 (4 waves, each wave a 64x64 quadrant)
__global__ __launch_bounds__(256, 2) void gemm_bt(
    const unsigned short* __restrict__ A, const unsigned short* __restrict__ Bt,
    void* __restrict__ Cv, const float* __restrict__ bias,
    const float* __restrict__ resid, int K, int Nout, int op) {
  __shared__ unsigned short As[128 * 32];
  __shared__ unsigned short Bs[128 * 32];
  const int m0 = blockIdx.x * 128, n0 = blockIdx.y * 128;
  const int tid = threadIdx.x, w = tid >> 6, l = tid & 63;
  const int wr = w >> 1, wc = w & 1;
  f32x4 acc[4][4] = {};

  // staging addresses: wave w covers tile rows [w*32, w*32+32) in two 16-row calls
  const int rA = w * 32 + (l >> 2);
  const int cA = (l & 3) * 8;
  const unsigned short* gA = A + (size_t)(m0 + rA) * K + cA;
  const unsigned short* gB = Bt + (size_t)(n0 + rA) * K + cA;

  for (int k0 = 0; k0 < K; k0 += 32) {
    __syncthreads();
    gld_lds16(gA + k0,                 &As[w * 1024]);
    gld_lds16(gA + (size_t)16 * K + k0, &As[w * 1024 + 512]);
    gld_lds16(gB + k0,                 &Bs[w * 1024]);
    gld_lds16(gB + (size_t)16 * K + k0, &Bs[w * 1024 + 512]);
    __syncthreads();
    s16x8 aF[4], bF[4];
    #pragma unroll
    for (int m = 0; m < 4; m++)
      aF[m] = *(const s16x8*)&As[(wr * 64 + m * 16 + (l & 15)) * 32 + (l >> 4) * 8];
    #pragma unroll
    for (int n = 0; n < 4; n++)
      bF[n] = *(const s16x8*)&Bs[(wc * 64 + n * 16 + (l & 15)) * 32 + (l >> 4) * 8];
    #pragma unroll
    for (int m = 0; m < 4; m++)
      #pragma unroll
      for (int n = 0; n < 4; n++)
        acc[m][n] = __builtin_amdgcn_mfma_f32_16x16x32_bf16(aF[m], bF[n], acc[m][n], 0, 0, 0);
  }

  #pragma unroll
  for (int m = 0; m < 4; m++) {
    int r0 = m0 + wr * 64 + m * 16 + (l >> 4) * 4;
    #pragma unroll
    for (int n = 0; n < 4; n++) {
      int c = n0 + wc * 64 + n * 16 + (l & 15);
      if (c < Nout) {
        float bval = (op & OP_BIAS) ? bias[c] : 0.f;
        #pragma unroll
        for (int j = 0; j < 4; j++) {
          int r = r0 + j;
          float val = acc[m][n][j] + bval;
          if (op & OP_GELU) val = 0.5f * val * (1.f + erff(val * 0.70710678118f));
          if (op & OP_RES)  val += resid[(size_t)r * Nout + c];
          if (op & OP_BF16) ((unsigned short*)Cv)[(size_t)r * Nout + c] = f2bf(val);
          else              ((float*)Cv)[(size_t)r * Nout + c] = val;
        }
      }
    }
  }
}

// ---------------- self attention (S=8, causal), writes bf16 ----------------
__global__ __launch_bounds__(64) void self_attn_k(
    const float* __restrict__ q, const float* __restrict__ k,
    const float* __restrict__ v, unsigned short* __restrict__ out) {
  int bh = blockIdx.x;
  int b = bh / HH, h = bh % HH;
  __shared__ float qs[8][65], ks[8][65], vs[8][65], ps[8][9];
  int l = threadIdx.x;
  for (int s = 0; s < 8; s++) {
    size_t base = ((size_t)(b * 8 + s)) * DD + h * 64 + l;
    qs[s][l] = q[base]; ks[s][l] = k[base]; vs[s][l] = v[base];
  }
  __syncthreads();
  int s = l >> 3, t = l & 7;
  float sc = 0.f;
  #pragma unroll
  for (int d = 0; d < 64; d++) sc += qs[s][d] * ks[t][d];
  sc *= 0.125f;
  if (t > s) sc = -1e30f;
  float mx = sc;
  for (int o = 4; o; o >>= 1) mx = fmaxf(mx, __shfl_xor(mx, o, 8));
  float e = __expf(sc - mx);
  float sum = e;
  for (int o = 4; o; o >>= 1) sum += __shfl_xor(sum, o, 8);
  ps[s][t] = e / sum;
  __syncthreads();
  for (int s2 = 0; s2 < 8; s2++) {
    float acc = 0.f;
    #pragma unroll
    for (int t2 = 0; t2 < 8; t2++) acc += ps[s2][t2] * vs[t2][l];
    out[((size_t)(b * 8 + s2)) * DD + h * 64 + l] = f2bf(acc);
  }
}

// ---------------- cross attention (T=1500), K/V bf16, writes bf16 ----------------
__global__ __launch_bounds__(256) void cross_attn_k(
    const float* __restrict__ q, const unsigned short* __restrict__ Kc,
    const unsigned short* __restrict__ Vc, unsigned short* __restrict__ out) {
  int bh = blockIdx.x;
  int b = bh / HH, h = bh % HH;
  __shared__ float qs[8][64];
  __shared__ float ps[8][1504];
  __shared__ float ssum[8];
  int tid = threadIdx.x;
  for (int i = tid; i < 512; i += 256) {
    int s = i >> 6, d = i & 63;
    qs[s][d] = q[((size_t)(b * 8 + s)) * DD + h * 64 + d] * 0.125f;
  }
  __syncthreads();
  for (int t = tid; t < AAn; t += 256) {
    const unsigned short* kr = Kc + ((size_t)(b * AAn + t)) * DD + h * 64;
    const uint4* kr4 = (const uint4*)kr;
    float kv[64];
    #pragma unroll
    for (int j = 0; j < 8; j++) {
      uint4 u = kr4[j];
      unsigned int ws[4] = {u.x, u.y, u.z, u.w};
      #pragma unroll
      for (int o = 0; o < 4; o++) {
        kv[j * 8 + o * 2]     = __uint_as_float(ws[o] << 16);
        kv[j * 8 + o * 2 + 1] = __uint_as_float(ws[o] & 0xffff0000u);
      }
    }
    #pragma unroll
    for (int s = 0; s < 8; s++) {
      float acc = 0.f;
      #pragma unroll 16
      for (int d = 0; d < 64; d++) acc += qs[s][d] * kv[d];
      ps[s][t] = acc;
    }
  }
  __syncthreads();
  int wv = tid >> 6, ln = tid & 63;
  for (int s = wv; s < 8; s += 4) {
    float mx = -1e30f;
    for (int t = ln; t < AAn; t += 64) mx = fmaxf(mx, ps[s][t]);
    for (int o = 32; o; o >>= 1) mx = fmaxf(mx, __shfl_xor(mx, o));
    float sum = 0.f;
    for (int t = ln; t < AAn; t += 64) {
      float e = __expf(ps[s][t] - mx);
      ps[s][t] = e; sum += e;
    }
    for (int o = 32; o; o >>= 1) sum += __shfl_xor(sum, o);
    if (!ln) ssum[s] = sum;
  }
  __syncthreads();
  int d = tid & 63, s0 = tid >> 6;       // s0 in 0..3, handles s0 and s0+4
  float a0 = 0.f, a1 = 0.f;
  for (int t = 0; t < AAn; t++) {
    float vv = bf2f(Vc[((size_t)(b * AAn + t)) * DD + h * 64 + d]);
    a0 += ps[s0][t] * vv;
    a1 += ps[s0 + 4][t] * vv;
  }
  out[((size_t)(b * 8 + s0)) * DD + h * 64 + d]     = f2bf(a0 / ssum[s0]);
  out[((size_t)(b * 8 + s0 + 4)) * DD + h * 64 + d] = f2bf(a1 / ssum[s0 + 4]);
}

// ---------------- host ----------------
static inline void* carve(char*& p, size_t bytes) {
  void* r = p;
  p += (bytes + 255) & ~(size_t)255;
  return r;
}

extern "C" void kernel_launch(void* const* d_in, const int* in_sizes, int n_in,
                              void* d_out, int out_size, void* d_ws, size_t ws_size,
                              hipStream_t stream) {
  const int*   tokens = (const int*)d_in[0];
  const float* audio  = (const float*)d_in[1];
  const float* temb   = (const float*)d_in[2];
  const float* pemb   = (const float*)d_in[3];
  const float* aln_w  = (const float*)d_in[4];
  const float* aln_b  = (const float*)d_in[5];
  const float* Wq = (const float*)d_in[6];
  const float* bq = (const float*)d_in[7];
  const float* Wk = (const float*)d_in[8];
  const float* Wv = (const float*)d_in[9];
  const float* bv = (const float*)d_in[10];
  const float* Wo = (const float*)d_in[11];
  const float* bo = (const float*)d_in[12];
  const float* cln_w = (const float*)d_in[13];
  const float* cln_b = (const float*)d_in[14];
  const float* cWq = (const float*)d_in[15];
  const float* cbq = (const float*)d_in[16];
  const float* cWk = (const float*)d_in[17];
  const float* cWv = (const float*)d_in[18];
  const float* cbv = (const float*)d_in[19];
  const float* cWo = (const float*)d_in[20];
  const float* cbo = (const float*)d_in[21];
  const float* mln_w = (const float*)d_in[22];
  const float* mln_b = (const float*)d_in[23];
  const float* W1 = (const float*)d_in[24];
  const float* b1 = (const float*)d_in[25];
  const float* W2 = (const float*)d_in[26];
  const float* b2 = (const float*)d_in[27];
  const float* lnw = (const float*)d_in[28];
  const float* lnb = (const float*)d_in[29];

  char* cur = (char*)d_ws;
  float* x  = (float*)carve(cur, (size_t)RR * DD * 4);
  float* qb = (float*)carve(cur, (size_t)RR * DD * 4);
  float* kb = (float*)carve(cur, (size_t)RR * DD * 4);
  float* vb = (float*)carve(cur, (size_t)RR * DD * 4);
  unsigned short* hb    = (unsigned short*)carve(cur, (size_t)RR * DD * 2);
  unsigned short* attnb = (unsigned short*)carve(cur, (size_t)RR * DD * 2);
  unsigned short* ffb   = (unsigned short*)carve(cur, (size_t)RR * FFD * 2);
  unsigned short* wt    = (unsigned short*)carve(cur, (size_t)FFD * DD * 2);
  unsigned short* audio_bf = (unsigned short*)carve(cur, (size_t)BBn * AAn * DD * 2);
  unsigned short* Kc = (unsigned short*)carve(cur, (size_t)BBn * AAn * DD * 2);
  unsigned short* Vc = (unsigned short*)carve(cur, (size_t)BBn * AAn * DD * 2);
  unsigned short* emb_bf = (unsigned short*)carve(cur, (size_t)VPAD * DD * 2);

  auto GEMM = [&](const unsigned short* A_, const unsigned short* Bt_, void* C_,
                  const float* bias_, const float* res_, int M_, int Np_, int K_,
                  int Nout_, int op_) {
    dim3 g(M_ / 128, Np_ / 128);
    gemm_bt<<<g, 256, 0, stream>>>(A_, Bt_, C_, bias_, res_, K_, Nout_, op_);
  };
  auto TR = [&](const float* W_, int R_, int C_) {
    transpose_to_bf16<<<dim3(C_ / 32, R_ / 32), 256, 0, stream>>>(W_, wt, R_, C_);
  };

  embed_k<<<RR, 256, 0, stream>>>(tokens, temb, pemb, x);
  cvt_bf16<<<2048, 256, 0, stream>>>(audio, audio_bf,
      (long long)BBn * AAn * DD, (long long)BBn * AAn * DD);
  cvt_bf16<<<2048, 256, 0, stream>>>(temb, emb_bf,
      (long long)VV * DD, (long long)VPAD * DD);

  for (int l = 0; l < 6; l++) {
    size_t wD = (size_t)l * DD * DD;
    size_t wF = (size_t)l * DD * FFD;
    size_t vD = (size_t)l * DD;
    size_t vF = (size_t)l * FFD;

    // --- self attention block ---
    ln_to_bf16<<<RR, 256, 0, stream>>>(x, aln_w + vD, aln_b + vD, hb);
    TR(Wq + wD, DD, DD);
    GEMM(hb, wt, qb, bq + vD, nullptr, RR, DD, DD, DD, OP_BIAS);
    TR(Wk + wD, DD, DD);
    GEMM(hb, wt, kb, nullptr, nullptr, RR, DD, DD, DD, 0);
    TR(Wv + wD, DD, DD);
    GEMM(hb, wt, vb, bv + vD, nullptr, RR, DD, DD, DD, OP_BIAS);
    self_attn_k<<<BBn * HH, 64, 0, stream>>>(qb, kb, vb, attnb);
    TR(Wo + wD, DD, DD);
    GEMM(attnb, wt, x, bo + vD, x, RR, DD, DD, DD, OP_BIAS | OP_RES);

    // --- cross attention block ---
    ln_to_bf16<<<RR, 256, 0, stream>>>(x, cln_w + vD, cln_b + vD, hb);
    TR(cWq + wD, DD, DD);
    GEMM(hb, wt, qb, cbq + vD, nullptr, RR, DD, DD, DD, OP_BIAS);
    TR(cWk + wD, DD, DD);
    GEMM(audio_bf, wt, Kc, nullptr, nullptr, BBn * AAn, DD, DD, DD, OP_BF16);
    TR(cWv + wD, DD, DD);
    GEMM(audio_bf, wt, Vc, cbv + vD, nullptr, BBn * AAn, DD, DD, DD, OP_BIAS | OP_BF16);
    cross_attn_k<<<BBn * HH, 256, 0, stream>>>(qb, Kc, Vc, attnb);
    TR(cWo + wD, DD, DD);
    GEMM(attnb, wt, x, cbo + vD, x, RR, DD, DD, DD, OP_BIAS | OP_RES);

    // --- MLP block ---
    ln_to_bf16<<<RR, 256, 0, stream>>>(x, mln_w + vD, mln_b + vD, hb);
    TR(W1 + wF, DD, FFD);
    GEMM(hb, wt, ffb, b1 + vF, nullptr, RR, FFD, DD, FFD, OP_BIAS | OP_GELU | OP_BF16);
    TR(W2 + wF, FFD, DD);
    GEMM(ffb, wt, x, b2 + vD, x, RR, DD, FFD, DD, OP_BIAS | OP_RES);
  }

  // --- final LN + logits ---
  ln_to_bf16<<<RR, 256, 0, stream>>>(x, lnw, lnb, hb);
  GEMM(hb, emb_bf, d_out, nullptr, nullptr, RR, VPAD, DD, VV, 0);
}

// Round 2
// 3829.548 us; speedup vs baseline: 1.3217x; 1.3217x over previous
//
#include <hip/hip_runtime.h>
#include <hip/hip_bf16.h>

// Whisper decoder step: L=6, D=768, H=12, FF=3072, V=51865, A=1500, B=32, S=8
#define HH 12
#define DD 768
#define DHH 64
#define FFD 3072
#define AAn 1500
#define BBn 32
#define SSn 8
#define RR 256          // B*S token rows
#define VV 51865
#define VPAD 51968      // 406*128
#define TCH 375         // cross-attn T chunk (1500/4)
#define NCH 4

#define OP_BIAS 1
#define OP_GELU 2
#define OP_RES  4
#define OP_BF16 8

typedef float f32x4 __attribute__((ext_vector_type(4)));
typedef short s16x8 __attribute__((ext_vector_type(8)));

__device__ __forceinline__ unsigned short f2bf(float f) {
  union { float f; unsigned int u; } v; v.f = f;
  unsigned int r = (v.u + 0x7fffu + ((v.u >> 16) & 1u)) >> 16;
  return (unsigned short)r;
}
__device__ __forceinline__ float bf2f(unsigned short u) {
  union { unsigned int u; float f; } v; v.u = ((unsigned int)u) << 16;
  return v.f;
}

__device__ __forceinline__ void gld_lds16(const unsigned short* g, unsigned short* l) {
  __builtin_amdgcn_global_load_lds(
      (const __attribute__((address_space(1))) void*)g,
      (__attribute__((address_space(3))) void*)l, 16, 0, 0);
}

// ---------------- embedding ----------------
__global__ void embed_k(const int* __restrict__ toks, const float* __restrict__ emb,
                        const float* __restrict__ pos, float* __restrict__ x) {
  int r = blockIdx.x;            // 0..255 = b*8+s
  int s = r & 7;
  int t = toks[r];
  for (int c = threadIdx.x; c < DD; c += 256)
    x[(size_t)r * DD + c] = emb[(size_t)t * DD + c] + pos[(size_t)s * DD + c];
}

// ---------------- f32 -> bf16 convert (with zero pad) ----------------
__global__ void cvt_bf16(const float* __restrict__ src, unsigned short* __restrict__ dst,
                         long long n_src, long long n_tot) {
  long long i = (long long)blockIdx.x * 256 + threadIdx.x;
  long long stride = (long long)gridDim.x * 256;
  for (; i < n_tot; i += stride)
    dst[i] = (i < n_src) ? f2bf(src[i]) : (unsigned short)0;
}

// ---------------- build combined K|V bias for all layers ----------------
__global__ void build_kvb(const float* __restrict__ cbv, float* __restrict__ kvb) {
  int i = blockIdx.x * 256 + threadIdx.x;   // 6*1536
  if (i >= 6 * 1536) return;
  int l = i / 1536, n = i % 1536;
  kvb[i] = (n < DD) ? 0.f : cbv[l * DD + (n - DD)];
}

// ---------------- LayerNorm -> bf16 ----------------
__global__ __launch_bounds__(256) void ln_to_bf16(
    const float* __restrict__ x, const float* __restrict__ w,
    const float* __restrict__ b, unsigned short* __restrict__ out) {
  int row = blockIdx.x;
  const float* xr = x + (size_t)row * DD;
  int t = threadIdx.x;
  float v0 = xr[t], v1 = xr[t + 256], v2 = xr[t + 512];
  float s = v0 + v1 + v2;
  for (int o = 32; o; o >>= 1) s += __shfl_down(s, o);
  __shared__ float red[4], red2[4];
  int wid = t >> 6, lane = t & 63;
  if (!lane) red[wid] = s;
  __syncthreads();
  float mean = (red[0] + red[1] + red[2] + red[3]) * (1.f / DD);
  float d0 = v0 - mean, d1 = v1 - mean, d2 = v2 - mean;
  float s2 = d0 * d0 + d1 * d1 + d2 * d2;
  for (int o = 32; o; o >>= 1) s2 += __shfl_down(s2, o);
  if (!lane) red2[wid] = s2;
  __syncthreads();
  float var = (red2[0] + red2[1] + red2[2] + red2[3]) * (1.f / DD);
  float rstd = rsqrtf(var + 1e-5f);
  out[(size_t)row * DD + t]       = f2bf(d0 * rstd * w[t] + b[t]);
  out[(size_t)row * DD + t + 256] = f2bf(d1 * rstd * w[t + 256] + b[t + 256]);
  out[(size_t)row * DD + t + 512] = f2bf(d2 * rstd * w[t + 512] + b[t + 512]);
}

// ---------------- transpose + convert: W[R][C] f32 -> Wt[C][R] bf16 ----------------
__global__ __launch_bounds__(256) void transpose_to_bf16(
    const float* __restrict__ W, unsigned short* __restrict__ Wt, int R, int C) {
  __shared__ unsigned short tile[32][33];
  int c0 = blockIdx.x * 32, r0 = blockIdx.y * 32;
  int tx = threadIdx.x & 31, ty = threadIdx.x >> 5;   // ty 0..7
  #pragma unroll
  for (int i = 0; i < 32; i += 8)
    tile[ty + i][tx] = f2bf(W[(size_t)(r0 + ty + i) * C + (c0 + tx)]);
  __syncthreads();
  #pragma unroll
  for (int i = 0; i < 32; i += 8)
    Wt[(size_t)(c0 + ty + i) * R + (r0 + tx)] = tile[tx][ty + i];
}

// ---------------- GEMM: C[M][Nout] = A[M][K](bf16) * Bt[N][K](bf16)^T ----------------
// grid = (M/128, Npad/128), block = 256 (4 waves, each wave a 64x64 quadrant)
__global__ __launch_bounds__(256, 2) void gemm_bt(
    const unsigned short* __restrict__ A, const unsigned short* __restrict__ Bt,
    void* __restrict__ Cv, const float* __restrict__ bias,
    const float* __restrict__ resid, int K, int Nout, int op) {
  __shared__ unsigned short As[128 * 32];
  __shared__ unsigned short Bs[128 * 32];
  const int m0 = blockIdx.x * 128, n0 = blockIdx.y * 128;
  const int tid = threadIdx.x, w = tid >> 6, l = tid & 63;
  const int wr = w >> 1, wc = w & 1;
  f32x4 acc[4][4] = {};

  const int rA = w * 32 + (l >> 2);
  const int cA = (l & 3) * 8;
  const unsigned short* gA = A + (size_t)(m0 + rA) * K + cA;
  const unsigned short* gB = Bt + (size_t)(n0 + rA) * K + cA;

  for (int k0 = 0; k0 < K; k0 += 32) {
    __syncthreads();
    gld_lds16(gA + k0,                  &As[w * 1024]);
    gld_lds16(gA + (size_t)16 * K + k0, &As[w * 1024 + 512]);
    gld_lds16(gB + k0,                  &Bs[w * 1024]);
    gld_lds16(gB + (size_t)16 * K + k0, &Bs[w * 1024 + 512]);
    __syncthreads();
    s16x8 aF[4], bF[4];
    #pragma unroll
    for (int m = 0; m < 4; m++)
      aF[m] = *(const s16x8*)&As[(wr * 64 + m * 16 + (l & 15)) * 32 + (l >> 4) * 8];
    #pragma unroll
    for (int n = 0; n < 4; n++)
      bF[n] = *(const s16x8*)&Bs[(wc * 64 + n * 16 + (l & 15)) * 32 + (l >> 4) * 8];
    #pragma unroll
    for (int m = 0; m < 4; m++)
      #pragma unroll
      for (int n = 0; n < 4; n++)
        acc[m][n] = __builtin_amdgcn_mfma_f32_16x16x32_bf16(aF[m], bF[n], acc[m][n], 0, 0, 0);
  }

  #pragma unroll
  for (int m = 0; m < 4; m++) {
    int r0 = m0 + wr * 64 + m * 16 + (l >> 4) * 4;
    #pragma unroll
    for (int n = 0; n < 4; n++) {
      int c = n0 + wc * 64 + n * 16 + (l & 15);
      if (c < Nout) {
        float bval = (op & OP_BIAS) ? bias[c] : 0.f;
        #pragma unroll
        for (int j = 0; j < 4; j++) {
          int r = r0 + j;
          float val = acc[m][n][j] + bval;
          if (op & OP_GELU) val = 0.5f * val * (1.f + erff(val * 0.70710678118f));
          if (op & OP_RES)  val += resid[(size_t)r * Nout + c];
          if (op & OP_BF16) ((unsigned short*)Cv)[(size_t)r * Nout + c] = f2bf(val);
          else              ((float*)Cv)[(size_t)r * Nout + c] = val;
        }
      }
    }
  }
}

// ---------------- self attention (S=8, causal), writes bf16 ----------------
__global__ __launch_bounds__(64) void self_attn_k(
    const float* __restrict__ q, const float* __restrict__ k,
    const float* __restrict__ v, unsigned short* __restrict__ out) {
  int bh = blockIdx.x;
  int b = bh / HH, h = bh % HH;
  __shared__ float qs[8][65], ks[8][65], vs[8][65], ps[8][9];
  int l = threadIdx.x;
  for (int s = 0; s < 8; s++) {
    size_t base = ((size_t)(b * 8 + s)) * DD + h * 64 + l;
    qs[s][l] = q[base]; ks[s][l] = k[base]; vs[s][l] = v[base];
  }
  __syncthreads();
  int s = l >> 3, t = l & 7;
  float sc = 0.f;
  #pragma unroll
  for (int d = 0; d < 64; d++) sc += qs[s][d] * ks[t][d];
  sc *= 0.125f;
  if (t > s) sc = -1e30f;
  float mx = sc;
  for (int o = 4; o; o >>= 1) mx = fmaxf(mx, __shfl_xor(mx, o, 8));
  float e = __expf(sc - mx);
  float sum = e;
  for (int o = 4; o; o >>= 1) sum += __shfl_xor(sum, o, 8);
  ps[s][t] = e / sum;
  __syncthreads();
  for (int s2 = 0; s2 < 8; s2++) {
    float acc = 0.f;
    #pragma unroll
    for (int t2 = 0; t2 < 8; t2++) acc += ps[s2][t2] * vs[t2][l];
    out[((size_t)(b * 8 + s2)) * DD + h * 64 + l] = f2bf(acc);
  }
}

// ---------------- cross attention phase A: per (b,h,chunk) partials ----------------
// KV layout: [b*1500][1536] bf16, cols 0-767 = K, 768-1535 = V
__global__ __launch_bounds__(256) void xattn_part(
    const float* __restrict__ q, const unsigned short* __restrict__ KV,
    float* __restrict__ part_o,      // [b*H*4 + hc][8][64]
    float* __restrict__ part_ml) {   // [b*H*4 + hc][16]  (m[8], l[8])
  int blk = blockIdx.x;                   // b*48 + h*4 + c
  int c = blk & 3, h = (blk >> 2) % HH, b = blk / (HH * NCH);
  const int cstart = c * TCH;
  __shared__ float qs[8][64];
  __shared__ float ps[8][TCH + 1];
  __shared__ float o_red[4][8][64];
  int tid = threadIdx.x;
  for (int i = tid; i < 512; i += 256) {
    int s = i >> 6, d = i & 63;
    qs[s][d] = q[((size_t)(b * 8 + s)) * DD + h * 64 + d] * 0.125f;
  }
  __syncthreads();
  // scores: each thread handles strided t rows
  for (int tt = tid; tt < TCH; tt += 256) {
    int t = cstart + tt;
    const uint4* kr4 = (const uint4*)(KV + ((size_t)(b * AAn + t)) * 1536 + h * 64);
    float kv[64];
    #pragma unroll
    for (int j = 0; j < 8; j++) {
      uint4 u = kr4[j];
      unsigned int w4[4] = {u.x, u.y, u.z, u.w};
      #pragma unroll
      for (int o = 0; o < 4; o++) {
        kv[j * 8 + o * 2]     = __uint_as_float(w4[o] << 16);
        kv[j * 8 + o * 2 + 1] = __uint_as_float(w4[o] & 0xffff0000u);
      }
    }
    #pragma unroll
    for (int s = 0; s < 8; s++) {
      float acc = 0.f;
      #pragma unroll
      for (int d = 0; d < 64; d++) acc += qs[s][d] * kv[d];
      ps[s][tt] = acc;
    }
  }
  __syncthreads();
  // per-row softmax over this chunk: wave w handles rows w and w+4
  int w = tid >> 6, ln = tid & 63;
  for (int s = w; s < 8; s += 4) {
    float mx = -1e30f;
    for (int tt = ln; tt < TCH; tt += 64) mx = fmaxf(mx, ps[s][tt]);
    for (int o = 32; o; o >>= 1) mx = fmaxf(mx, __shfl_xor(mx, o));
    float sum = 0.f;
    for (int tt = ln; tt < TCH; tt += 64) {
      float e = __expf(ps[s][tt] - mx);
      ps[s][tt] = e; sum += e;
    }
    for (int o = 32; o; o >>= 1) sum += __shfl_xor(sum, o);
    if (!ln) {
      part_ml[(size_t)blk * 16 + s] = mx;
      part_ml[(size_t)blk * 16 + 8 + s] = sum;
    }
  }
  __syncthreads();
  // PV: wave w, lane ln: rows tt = i*16 + w*4 + (ln>>4), d = (ln&15)*4 + j
  float oacc[8][4] = {};
  const int rowoff = w * 4 + (ln >> 4);
  const int dbase = (ln & 15) * 4;
  for (int i = 0; i < (TCH + 15) / 16; i++) {
    int tt = i * 16 + rowoff;
    if (tt < TCH) {
      int t = cstart + tt;
      const uint2* vr = (const uint2*)(KV + ((size_t)(b * AAn + t)) * 1536 + DD + h * 64 + dbase);
      uint2 u = *vr;
      float v0 = __uint_as_float(u.x << 16);
      float v1 = __uint_as_float(u.x & 0xffff0000u);
      float v2 = __uint_as_float(u.y << 16);
      float v3 = __uint_as_float(u.y & 0xffff0000u);
      #pragma unroll
      for (int s = 0; s < 8; s++) {
        float p = ps[s][tt];
        oacc[s][0] += p * v0; oacc[s][1] += p * v1;
        oacc[s][2] += p * v2; oacc[s][3] += p * v3;
      }
    }
  }
  #pragma unroll
  for (int s = 0; s < 8; s++)
    #pragma unroll
    for (int j = 0; j < 4; j++) {
      float v = oacc[s][j];
      v += __shfl_xor(v, 16);
      v += __shfl_xor(v, 32);
      oacc[s][j] = v;
    }
  if (ln < 16) {
    #pragma unroll
    for (int s = 0; s < 8; s++)
      #pragma unroll
      for (int j = 0; j < 4; j++)
        o_red[w][s][ln * 4 + j] = oacc[s][j];
  }
  __syncthreads();
  for (int i = tid; i < 512; i += 256) {
    int s = i >> 6, d = i & 63;
    float v = o_red[0][s][d] + o_red[1][s][d] + o_red[2][s][d] + o_red[3][s][d];
    part_o[((size_t)blk * 8 + s) * 64 + d] = v;
  }
}

// ---------------- cross attention phase B: combine 4 chunks ----------------
__global__ __launch_bounds__(64) void xattn_reduce(
    const float* __restrict__ part_o, const float* __restrict__ part_ml,
    unsigned short* __restrict__ out) {
  int bh = blockIdx.x;                 // b*12 + h
  int b = bh / HH, h = bh % HH;
  int d = threadIdx.x;
  #pragma unroll
  for (int s = 0; s < 8; s++) {
    float mv[NCH], lv[NCH];
    float m = -1e30f;
    #pragma unroll
    for (int c = 0; c < NCH; c++) {
      mv[c] = part_ml[((size_t)bh * NCH + c) * 16 + s];
      lv[c] = part_ml[((size_t)bh * NCH + c) * 16 + 8 + s];
      m = fmaxf(m, mv[c]);
    }
    float acc = 0.f, lsum = 0.f;
    #pragma unroll
    for (int c = 0; c < NCH; c++) {
      float sc = __expf(mv[c] - m);
      acc += sc * part_o[(((size_t)bh * NCH + c) * 8 + s) * 64 + d];
      lsum += sc * lv[c];
    }
    out[((size_t)(b * 8 + s)) * DD + h * 64 + d] = f2bf(acc / lsum);
  }
}

// ---------------- host ----------------
static inline void* carve(char*& p, size_t bytes) {
  void* r = p;
  p += (bytes + 255) & ~(size_t)255;
  return r;
}

extern "C" void kernel_launch(void* const* d_in, const int* in_sizes, int n_in,
                              void* d_out, int out_size, void* d_ws, size_t ws_size,
                              hipStream_t stream) {
  const int*   tokens = (const int*)d_in[0];
  const float* audio  = (const float*)d_in[1];
  const float* temb   = (const float*)d_in[2];
  const float* pemb   = (const float*)d_in[3];
  const float* aln_w  = (const float*)d_in[4];
  const float* aln_b  = (const float*)d_in[5];
  const float* Wq = (const float*)d_in[6];
  const float* bq = (const float*)d_in[7];
  const float* Wk = (const float*)d_in[8];
  const float* Wv = (const float*)d_in[9];
  const float* bv = (const float*)d_in[10];
  const float* Wo = (const float*)d_in[11];
  const float* bo = (const float*)d_in[12];
  const float* cln_w = (const float*)d_in[13];
  const float* cln_b = (const float*)d_in[14];
  const float* cWq = (const float*)d_in[15];
  const float* cbq = (const float*)d_in[16];
  const float* cWk = (const float*)d_in[17];
  const float* cWv = (const float*)d_in[18];
  const float* cbv = (const float*)d_in[19];
  const float* cWo = (const float*)d_in[20];
  const float* cbo = (const float*)d_in[21];
  const float* mln_w = (const float*)d_in[22];
  const float* mln_b = (const float*)d_in[23];
  const float* W1 = (const float*)d_in[24];
  const float* b1 = (const float*)d_in[25];
  const float* W2 = (const float*)d_in[26];
  const float* b2 = (const float*)d_in[27];
  const float* lnw = (const float*)d_in[28];
  const float* lnb = (const float*)d_in[29];

  char* cur = (char*)d_ws;
  float* x  = (float*)carve(cur, (size_t)RR * DD * 4);
  float* qb = (float*)carve(cur, (size_t)RR * DD * 4);
  float* kb = (float*)carve(cur, (size_t)RR * DD * 4);
  float* vb = (float*)carve(cur, (size_t)RR * DD * 4);
  unsigned short* hb    = (unsigned short*)carve(cur, (size_t)RR * DD * 2);
  unsigned short* attnb = (unsigned short*)carve(cur, (size_t)RR * DD * 2);
  unsigned short* ffb   = (unsigned short*)carve(cur, (size_t)RR * FFD * 2);
  unsigned short* wt    = (unsigned short*)carve(cur, (size_t)FFD * DD * 2);
  unsigned short* audio_bf = (unsigned short*)carve(cur, (size_t)BBn * AAn * DD * 2);
  unsigned short* KVc = (unsigned short*)carve(cur, (size_t)BBn * AAn * 1536 * 2);
  unsigned short* emb_bf = (unsigned short*)carve(cur, (size_t)VPAD * DD * 2);
  float* part_o  = (float*)carve(cur, (size_t)BBn * HH * NCH * 8 * 64 * 4);
  float* part_ml = (float*)carve(cur, (size_t)BBn * HH * NCH * 16 * 4);
  float* kvb     = (float*)carve(cur, (size_t)6 * 1536 * 4);

  auto GEMM = [&](const unsigned short* A_, const unsigned short* Bt_, void* C_,
                  const float* bias_, const float* res_, int M_, int Np_, int K_,
                  int Nout_, int op_) {
    dim3 g(M_ / 128, Np_ / 128);
    gemm_bt<<<g, 256, 0, stream>>>(A_, Bt_, C_, bias_, res_, K_, Nout_, op_);
  };
  auto TR = [&](const float* W_, unsigned short* dst, int R_, int C_) {
    transpose_to_bf16<<<dim3(C_ / 32, R_ / 32), 256, 0, stream>>>(W_, dst, R_, C_);
  };

  embed_k<<<RR, 256, 0, stream>>>(tokens, temb, pemb, x);
  cvt_bf16<<<2048, 256, 0, stream>>>(audio, audio_bf,
      (long long)BBn * AAn * DD, (long long)BBn * AAn * DD);
  cvt_bf16<<<2048, 256, 0, stream>>>(temb, emb_bf,
      (long long)VV * DD, (long long)VPAD * DD);
  build_kvb<<<(6 * 1536 + 255) / 256, 256, 0, stream>>>(cbv, kvb);

  for (int l = 0; l < 6; l++) {
    size_t wD = (size_t)l * DD * DD;
    size_t wF = (size_t)l * DD * FFD;
    size_t vD = (size_t)l * DD;
    size_t vF = (size_t)l * FFD;

    // --- self attention block ---
    ln_to_bf16<<<RR, 256, 0, stream>>>(x, aln_w + vD, aln_b + vD, hb);
    TR(Wq + wD, wt, DD, DD);
    GEMM(hb, wt, qb, bq + vD, nullptr, RR, DD, DD, DD, OP_BIAS);
    TR(Wk + wD, wt, DD, DD);
    GEMM(hb, wt, kb, nullptr, nullptr, RR, DD, DD, DD, 0);
    TR(Wv + wD, wt, DD, DD);
    GEMM(hb, wt, vb, bv + vD, nullptr, RR, DD, DD, DD, OP_BIAS);
    self_attn_k<<<BBn * HH, 64, 0, stream>>>(qb, kb, vb, attnb);
    TR(Wo + wD, wt, DD, DD);
    GEMM(attnb, wt, x, bo + vD, x, RR, DD, DD, DD, OP_BIAS | OP_RES);

    // --- cross attention block ---
    ln_to_bf16<<<RR, 256, 0, stream>>>(x, cln_w + vD, cln_b + vD, hb);
    TR(cWq + wD, wt, DD, DD);
    GEMM(hb, wt, qb, cbq + vD, nullptr, RR, DD, DD, DD, OP_BIAS);
    // fused K|V projection: Bt rows 0-767 = cWk^T, 768-1535 = cWv^T
    TR(cWk + wD, wt, DD, DD);
    TR(cWv + wD, wt + (size_t)DD * DD, DD, DD);
    GEMM(audio_bf, wt, KVc, kvb + l * 1536, nullptr, BBn * AAn, 1536, DD, 1536,
         OP_BIAS | OP_BF16);
    xattn_part<<<BBn * HH * NCH, 256, 0, stream>>>(qb, KVc, part_o, part_ml);
    xattn_reduce<<<BBn * HH, 64, 0, stream>>>(part_o, part_ml, attnb);
    TR(cWo + wD, wt, DD, DD);
    GEMM(attnb, wt, x, cbo + vD, x, RR, DD, DD, DD, OP_BIAS | OP_RES);

    // --- MLP block ---
    ln_to_bf16<<<RR, 256, 0, stream>>>(x, mln_w + vD, mln_b + vD, hb);
    TR(W1 + wF, wt, DD, FFD);
    GEMM(hb, wt, ffb, b1 + vF, nullptr, RR, FFD, DD, FFD, OP_BIAS | OP_GELU | OP_BF16);
    TR(W2 + wF, wt, FFD, DD);
    GEMM(ffb, wt, x, b2 + vD, x, RR, DD, FFD, DD, OP_BIAS | OP_RES);
  }

  // --- final LN + logits ---
  ln_to_bf16<<<RR, 256, 0, stream>>>(x, lnw, lnb, hb);
  GEMM(hb, emb_bf, d_out, nullptr, nullptr, RR, VPAD, DD, VV, 0);
}

// Round 3
// 3159.468 us; speedup vs baseline: 1.6020x; 1.2121x over previous
//
#include <hip/hip_runtime.h>
#include <hip/hip_bf16.h>

// Whisper decoder step: L=6, D=768, H=12, FF=3072, V=51865, A=1500, B=32, S=8
#define HH 12
#define DD 768
#define DHH 64
#define FFD 3072
#define AAn 1500
#define BBn 32
#define RR 256          // B*S token rows
#define VV 51865
#define VPAD 51968      // 406*128
#define TCH 375         // cross-attn T chunk (1500/4)
#define NCH 4
#define MAT (768*768)   // 589824

#define OP_BIAS 1
#define OP_GELU 2
#define OP_RES  4
#define OP_BF16 8

typedef float f32x4 __attribute__((ext_vector_type(4)));
typedef short s16x8 __attribute__((ext_vector_type(8)));

__device__ __forceinline__ unsigned short f2bf(float f) {
  union { float f; unsigned int u; } v; v.f = f;
  unsigned int r = (v.u + 0x7fffu + ((v.u >> 16) & 1u)) >> 16;
  return (unsigned short)r;
}
__device__ __forceinline__ float bf2f(unsigned short u) {
  union { unsigned int u; float f; } v; v.u = ((unsigned int)u) << 16;
  return v.f;
}

__device__ __forceinline__ void gld_lds16(const unsigned short* g, unsigned short* l) {
  __builtin_amdgcn_global_load_lds(
      (const __attribute__((address_space(1))) void*)g,
      (__attribute__((address_space(3))) void*)l, 16, 0, 0);
}

// ---------------- embedding ----------------
__global__ void embed_k(const int* __restrict__ toks, const float* __restrict__ emb,
                        const float* __restrict__ pos, float* __restrict__ x) {
  int r = blockIdx.x;            // 0..255 = b*8+s
  int s = r & 7;
  int t = toks[r];
  for (int c = threadIdx.x; c < DD; c += 256)
    x[(size_t)r * DD + c] = emb[(size_t)t * DD + c] + pos[(size_t)s * DD + c];
}

// ---------------- f32 -> bf16 convert (with zero pad) ----------------
__global__ void cvt_bf16(const float* __restrict__ src, unsigned short* __restrict__ dst,
                         long long n_src, long long n_tot) {
  long long i = (long long)blockIdx.x * 256 + threadIdx.x;
  long long stride = (long long)gridDim.x * 256;
  for (; i < n_tot; i += stride)
    dst[i] = (i < n_src) ? f2bf(src[i]) : (unsigned short)0;
}

// ---------------- build combined biases (qkv for self, k|v for cross) ----------------
__global__ void build_biases(const float* __restrict__ bq, const float* __restrict__ bv,
                             const float* __restrict__ cbv,
                             float* __restrict__ qkvb, float* __restrict__ kvb) {
  int i = blockIdx.x * 256 + threadIdx.x;
  if (i < 6 * 2304) {
    int l = i / 2304, n = i % 2304;
    qkvb[i] = (n < 768) ? bq[l * 768 + n] : (n < 1536 ? 0.f : bv[l * 768 + (n - 1536)]);
  }
  if (i < 6 * 1536) {
    int l = i / 1536, n = i % 1536;
    kvb[i] = (n < 768) ? 0.f : cbv[l * 768 + (n - 768)];
  }
}

// ---------------- LayerNorm -> bf16 ----------------
__global__ __launch_bounds__(256) void ln_to_bf16(
    const float* __restrict__ x, const float* __restrict__ w,
    const float* __restrict__ b, unsigned short* __restrict__ out) {
  int row = blockIdx.x;
  const float* xr = x + (size_t)row * DD;
  int t = threadIdx.x;
  float v0 = xr[t], v1 = xr[t + 256], v2 = xr[t + 512];
  float s = v0 + v1 + v2;
  for (int o = 32; o; o >>= 1) s += __shfl_down(s, o);
  __shared__ float red[4], red2[4];
  int wid = t >> 6, lane = t & 63;
  if (!lane) red[wid] = s;
  __syncthreads();
  float mean = (red[0] + red[1] + red[2] + red[3]) * (1.f / DD);
  float d0 = v0 - mean, d1 = v1 - mean, d2 = v2 - mean;
  float s2 = d0 * d0 + d1 * d1 + d2 * d2;
  for (int o = 32; o; o >>= 1) s2 += __shfl_down(s2, o);
  if (!lane) red2[wid] = s2;
  __syncthreads();
  float var = (red2[0] + red2[1] + red2[2] + red2[3]) * (1.f / DD);
  float rstd = rsqrtf(var + 1e-5f);
  out[(size_t)row * DD + t]       = f2bf(d0 * rstd * w[t] + b[t]);
  out[(size_t)row * DD + t + 256] = f2bf(d1 * rstd * w[t + 256] + b[t + 256]);
  out[(size_t)row * DD + t + 512] = f2bf(d2 * rstd * w[t + 512] + b[t + 512]);
}

// ---------------- batched per-layer transpose: 10 weight mats -> bf16 ----------------
// dst layout (elements): q,k,v,o,cq,ck,cv,co at which*MAT; W1t at 8*MAT (3072x768);
// W2t at 8*MAT+FFD*DD (768x3072)
struct WPtrs { const float* p[10]; };
__global__ __launch_bounds__(256) void transpose_layer(
    WPtrs wp, int l, unsigned short* __restrict__ dst) {
  int z = blockIdx.z;
  int R = (z == 9) ? FFD : DD;
  int C = (z == 8) ? FFD : DD;
  int ctile, rtile;
  if (z == 9) { rtile = blockIdx.x; ctile = blockIdx.y; }
  else        { ctile = blockIdx.x; rtile = blockIdx.y; }
  if (ctile * 32 >= C || rtile * 32 >= R) return;
  const float* W = wp.p[z] + (size_t)l * ((z < 8) ? MAT : (size_t)DD * FFD);
  size_t doff = (z < 8) ? (size_t)z * MAT
                        : ((z == 8) ? (size_t)8 * MAT : (size_t)8 * MAT + (size_t)FFD * DD);
  unsigned short* Wt = dst + doff;
  __shared__ unsigned short tile[32][33];
  int r0 = rtile * 32, c0 = ctile * 32;
  int tx = threadIdx.x & 31, ty = threadIdx.x >> 5;
  #pragma unroll
  for (int i = 0; i < 32; i += 8)
    tile[ty + i][tx] = f2bf(W[(size_t)(r0 + ty + i) * C + (c0 + tx)]);
  __syncthreads();
  #pragma unroll
  for (int i = 0; i < 32; i += 8)
    Wt[(size_t)(c0 + ty + i) * R + (r0 + tx)] = tile[tx][ty + i];
}

// ---------------- GEMM: C[M][Nout] = A[M][Klen](bf16) * Bt[N][Klen](bf16)^T --------
// grid = (Npad/128, M/128, SK); block = 256 (4 waves, each a 64x64 quadrant)
// split-K: z-th block handles K range [z*Klen, (z+1)*Klen), writes f32 partial
// at Cv + z*zstride.
__global__ __launch_bounds__(256, 2) void gemm_bt(
    const unsigned short* __restrict__ A, const unsigned short* __restrict__ Bt,
    void* __restrict__ Cv, const float* __restrict__ bias,
    const float* __restrict__ resid, int Klen, int Kstride, int Nout,
    size_t zstride, int op) {
  __shared__ unsigned short As[128 * 32];
  __shared__ unsigned short Bs[128 * 32];
  const int n0 = blockIdx.x * 128, m0 = blockIdx.y * 128;
  const int kbeg = blockIdx.z * Klen;
  const int tid = threadIdx.x, w = tid >> 6, l = tid & 63;
  const int wr = w >> 1, wc = w & 1;
  f32x4 acc[4][4] = {};

  const int rA = w * 32 + (l >> 2);
  const int cA = (l & 3) * 8;
  const unsigned short* gA = A + (size_t)(m0 + rA) * Kstride + cA + kbeg;
  const unsigned short* gB = Bt + (size_t)(n0 + rA) * Kstride + cA + kbeg;

  for (int k0 = 0; k0 < Klen; k0 += 32) {
    __syncthreads();
    gld_lds16(gA + k0,                        &As[w * 1024]);
    gld_lds16(gA + (size_t)16 * Kstride + k0, &As[w * 1024 + 512]);
    gld_lds16(gB + k0,                        &Bs[w * 1024]);
    gld_lds16(gB + (size_t)16 * Kstride + k0, &Bs[w * 1024 + 512]);
    __syncthreads();
    s16x8 aF[4], bF[4];
    #pragma unroll
    for (int m = 0; m < 4; m++)
      aF[m] = *(const s16x8*)&As[(wr * 64 + m * 16 + (l & 15)) * 32 + (l >> 4) * 8];
    #pragma unroll
    for (int n = 0; n < 4; n++)
      bF[n] = *(const s16x8*)&Bs[(wc * 64 + n * 16 + (l & 15)) * 32 + (l >> 4) * 8];
    #pragma unroll
    for (int m = 0; m < 4; m++)
      #pragma unroll
      for (int n = 0; n < 4; n++)
        acc[m][n] = __builtin_amdgcn_mfma_f32_16x16x32_bf16(aF[m], bF[n], acc[m][n], 0, 0, 0);
  }

  float* Cf = (float*)Cv + (size_t)blockIdx.z * zstride;
  #pragma unroll
  for (int m = 0; m < 4; m++) {
    int r0 = m0 + wr * 64 + m * 16 + (l >> 4) * 4;
    #pragma unroll
    for (int n = 0; n < 4; n++) {
      int c = n0 + wc * 64 + n * 16 + (l & 15);
      if (c < Nout) {
        float bval = (op & OP_BIAS) ? bias[c] : 0.f;
        #pragma unroll
        for (int j = 0; j < 4; j++) {
          int r = r0 + j;
          float val = acc[m][n][j] + bval;
          if (op & OP_GELU) val = 0.5f * val * (1.f + erff(val * 0.70710678118f));
          if (op & OP_RES)  val += resid[(size_t)r * Nout + c];
          if (op & OP_BF16) ((unsigned short*)Cv)[(size_t)r * Nout + c] = f2bf(val);
          else              Cf[(size_t)r * Nout + c] = val;
        }
      }
    }
  }
}

// ---------------- MLP2 split-K reduce + bias + residual ----------------
__global__ void mlp2_reduce(const float* __restrict__ part, const float* __restrict__ b2,
                            float* __restrict__ x) {
  int i = blockIdx.x * 256 + threadIdx.x;   // 256*768
  int c = i % DD;
  x[i] += b2[c] + part[i] + part[i + RR * DD] + part[i + 2 * RR * DD] + part[i + 3 * RR * DD];
}

// ---------------- self attention (S=8, causal), q/k/v packed [256][2304] ----------------
__global__ __launch_bounds__(64) void self_attn_k(
    const float* __restrict__ qkv, unsigned short* __restrict__ out) {
  int bh = blockIdx.x;
  int b = bh / HH, h = bh % HH;
  __shared__ float qs[8][65], ks[8][65], vs[8][65], ps[8][9];
  int l = threadIdx.x;
  for (int s = 0; s < 8; s++) {
    size_t base = ((size_t)(b * 8 + s)) * 2304 + h * 64 + l;
    qs[s][l] = qkv[base]; ks[s][l] = qkv[base + 768]; vs[s][l] = qkv[base + 1536];
  }
  __syncthreads();
  int s = l >> 3, t = l & 7;
  float sc = 0.f;
  #pragma unroll
  for (int d = 0; d < 64; d++) sc += qs[s][d] * ks[t][d];
  sc *= 0.125f;
  if (t > s) sc = -1e30f;
  float mx = sc;
  for (int o = 4; o; o >>= 1) mx = fmaxf(mx, __shfl_xor(mx, o, 8));
  float e = __expf(sc - mx);
  float sum = e;
  for (int o = 4; o; o >>= 1) sum += __shfl_xor(sum, o, 8);
  ps[s][t] = e / sum;
  __syncthreads();
  for (int s2 = 0; s2 < 8; s2++) {
    float acc = 0.f;
    #pragma unroll
    for (int t2 = 0; t2 < 8; t2++) acc += ps[s2][t2] * vs[t2][l];
    out[((size_t)(b * 8 + s2)) * DD + h * 64 + l] = f2bf(acc);
  }
}

// ---------------- cross attention phase A: per (b,h,chunk) partials ----------------
// KV layout: [b*1500][1536] bf16, cols 0-767 = K, 768-1535 = V
__global__ __launch_bounds__(256) void xattn_part(
    const float* __restrict__ q, const unsigned short* __restrict__ KV,
    float* __restrict__ part_o,      // [b*H*4 + hc][8][64]
    float* __restrict__ part_ml) {   // [b*H*4 + hc][16]  (m[8], l[8])
  int blk = blockIdx.x;                   // b*48 + h*4 + c
  int c = blk & 3, h = (blk >> 2) % HH, b = blk / (HH * NCH);
  const int cstart = c * TCH;
  __shared__ float qs[8][64];
  __shared__ float ps[8][TCH + 1];
  __shared__ float o_red[4][8][64];
  int tid = threadIdx.x;
  for (int i = tid; i < 512; i += 256) {
    int s = i >> 6, d = i & 63;
    qs[s][d] = q[((size_t)(b * 8 + s)) * DD + h * 64 + d] * 0.125f;
  }
  __syncthreads();
  for (int tt = tid; tt < TCH; tt += 256) {
    int t = cstart + tt;
    const uint4* kr4 = (const uint4*)(KV + ((size_t)(b * AAn + t)) * 1536 + h * 64);
    float kv[64];
    #pragma unroll
    for (int j = 0; j < 8; j++) {
      uint4 u = kr4[j];
      unsigned int w4[4] = {u.x, u.y, u.z, u.w};
      #pragma unroll
      for (int o = 0; o < 4; o++) {
        kv[j * 8 + o * 2]     = __uint_as_float(w4[o] << 16);
        kv[j * 8 + o * 2 + 1] = __uint_as_float(w4[o] & 0xffff0000u);
      }
    }
    #pragma unroll
    for (int s = 0; s < 8; s++) {
      float acc = 0.f;
      #pragma unroll
      for (int d = 0; d < 64; d++) acc += qs[s][d] * kv[d];
      ps[s][tt] = acc;
    }
  }
  __syncthreads();
  int w = tid >> 6, ln = tid & 63;
  for (int s = w; s < 8; s += 4) {
    float mx = -1e30f;
    for (int tt = ln; tt < TCH; tt += 64) mx = fmaxf(mx, ps[s][tt]);
    for (int o = 32; o; o >>= 1) mx = fmaxf(mx, __shfl_xor(mx, o));
    float sum = 0.f;
    for (int tt = ln; tt < TCH; tt += 64) {
      float e = __expf(ps[s][tt] - mx);
      ps[s][tt] = e; sum += e;
    }
    for (int o = 32; o; o >>= 1) sum += __shfl_xor(sum, o);
    if (!ln) {
      part_ml[(size_t)blk * 16 + s] = mx;
      part_ml[(size_t)blk * 16 + 8 + s] = sum;
    }
  }
  __syncthreads();
  float oacc[8][4] = {};
  const int rowoff = w * 4 + (ln >> 4);
  const int dbase = (ln & 15) * 4;
  for (int i = 0; i < (TCH + 15) / 16; i++) {
    int tt = i * 16 + rowoff;
    if (tt < TCH) {
      int t = cstart + tt;
      const uint2* vr = (const uint2*)(KV + ((size_t)(b * AAn + t)) * 1536 + DD + h * 64 + dbase);
      uint2 u = *vr;
      float v0 = __uint_as_float(u.x << 16);
      float v1 = __uint_as_float(u.x & 0xffff0000u);
      float v2 = __uint_as_float(u.y << 16);
      float v3 = __uint_as_float(u.y & 0xffff0000u);
      #pragma unroll
      for (int s = 0; s < 8; s++) {
        float p = ps[s][tt];
        oacc[s][0] += p * v0; oacc[s][1] += p * v1;
        oacc[s][2] += p * v2; oacc[s][3] += p * v3;
      }
    }
  }
  #pragma unroll
  for (int s = 0; s < 8; s++)
    #pragma unroll
    for (int j = 0; j < 4; j++) {
      float v = oacc[s][j];
      v += __shfl_xor(v, 16);
      v += __shfl_xor(v, 32);
      oacc[s][j] = v;
    }
  if (ln < 16) {
    #pragma unroll
    for (int s = 0; s < 8; s++)
      #pragma unroll
      for (int j = 0; j < 4; j++)
        o_red[w][s][ln * 4 + j] = oacc[s][j];
  }
  __syncthreads();
  for (int i = tid; i < 512; i += 256) {
    int s = i >> 6, d = i & 63;
    float v = o_red[0][s][d] + o_red[1][s][d] + o_red[2][s][d] + o_red[3][s][d];
    part_o[((size_t)blk * 8 + s) * 64 + d] = v;
  }
}

// ---------------- cross attention phase B: combine 4 chunks ----------------
__global__ __launch_bounds__(64) void xattn_reduce(
    const float* __restrict__ part_o, const float* __restrict__ part_ml,
    unsigned short* __restrict__ out) {
  int bh = blockIdx.x;                 // b*12 + h
  int b = bh / HH, h = bh % HH;
  int d = threadIdx.x;
  #pragma unroll
  for (int s = 0; s < 8; s++) {
    float mv[NCH], lv[NCH];
    float m = -1e30f;
    #pragma unroll
    for (int c = 0; c < NCH; c++) {
      mv[c] = part_ml[((size_t)bh * NCH + c) * 16 + s];
      lv[c] = part_ml[((size_t)bh * NCH + c) * 16 + 8 + s];
      m = fmaxf(m, mv[c]);
    }
    float acc = 0.f, lsum = 0.f;
    #pragma unroll
    for (int c = 0; c < NCH; c++) {
      float sc = __expf(mv[c] - m);
      acc += sc * part_o[(((size_t)bh * NCH + c) * 8 + s) * 64 + d];
      lsum += sc * lv[c];
    }
    out[((size_t)(b * 8 + s)) * DD + h * 64 + d] = f2bf(acc / lsum);
  }
}

// ---------------- host ----------------
static inline void* carve(char*& p, size_t bytes) {
  void* r = p;
  p += (bytes + 255) & ~(size_t)255;
  return r;
}

extern "C" void kernel_launch(void* const* d_in, const int* in_sizes, int n_in,
                              void* d_out, int out_size, void* d_ws, size_t ws_size,
                              hipStream_t stream) {
  const int*   tokens = (const int*)d_in[0];
  const float* audio  = (const float*)d_in[1];
  const float* temb   = (const float*)d_in[2];
  const float* pemb   = (const float*)d_in[3];
  const float* aln_w  = (const float*)d_in[4];
  const float* aln_b  = (const float*)d_in[5];
  const float* Wq = (const float*)d_in[6];
  const float* bq = (const float*)d_in[7];
  const float* Wk = (const float*)d_in[8];
  const float* Wv = (const float*)d_in[9];
  const float* bv = (const float*)d_in[10];
  const float* Wo = (const float*)d_in[11];
  const float* bo = (const float*)d_in[12];
  const float* cln_w = (const float*)d_in[13];
  const float* cln_b = (const float*)d_in[14];
  const float* cWq = (const float*)d_in[15];
  const float* cbq = (const float*)d_in[16];
  const float* cWk = (const float*)d_in[17];
  const float* cWv = (const float*)d_in[18];
  const float* cbv = (const float*)d_in[19];
  const float* cWo = (const float*)d_in[20];
  const float* cbo = (const float*)d_in[21];
  const float* mln_w = (const float*)d_in[22];
  const float* mln_b = (const float*)d_in[23];
  const float* W1 = (const float*)d_in[24];
  const float* b1 = (const float*)d_in[25];
  const float* W2 = (const float*)d_in[26];
  const float* b2 = (const float*)d_in[27];
  const float* lnw = (const float*)d_in[28];
  const float* lnb = (const float*)d_in[29];

  char* cur = (char*)d_ws;
  float* x    = (float*)carve(cur, (size_t)RR * DD * 4);
  float* qkv  = (float*)carve(cur, (size_t)RR * 2304 * 4);   // also reused as cross-q
  unsigned short* hb    = (unsigned short*)carve(cur, (size_t)RR * DD * 2);
  unsigned short* attnb = (unsigned short*)carve(cur, (size_t)RR * DD * 2);
  unsigned short* ffb   = (unsigned short*)carve(cur, (size_t)RR * FFD * 2);
  unsigned short* wt    = (unsigned short*)carve(cur, ((size_t)8 * MAT + 2 * (size_t)DD * FFD) * 2);
  unsigned short* audio_bf = (unsigned short*)carve(cur, (size_t)BBn * AAn * DD * 2);
  unsigned short* KVc = (unsigned short*)carve(cur, (size_t)BBn * AAn * 1536 * 2);
  unsigned short* emb_bf = (unsigned short*)carve(cur, (size_t)VPAD * DD * 2);
  float* part_o  = (float*)carve(cur, (size_t)BBn * HH * NCH * 8 * 64 * 4);
  float* part_ml = (float*)carve(cur, (size_t)BBn * HH * NCH * 16 * 4);
  float* qkvb    = (float*)carve(cur, (size_t)6 * 2304 * 4);
  float* kvb     = (float*)carve(cur, (size_t)6 * 1536 * 4);
  float* mlp2p   = (float*)carve(cur, (size_t)4 * RR * DD * 4);

  auto GEMM = [&](const unsigned short* A_, const unsigned short* Bt_, void* C_,
                  const float* bias_, const float* res_, int M_, int Np_,
                  int Klen_, int Kstr_, int Nout_, int op_, int SK_ = 1,
                  size_t zs_ = 0) {
    dim3 g(Np_ / 128, M_ / 128, SK_);
    gemm_bt<<<g, 256, 0, stream>>>(A_, Bt_, C_, bias_, res_, Klen_, Kstr_, Nout_, zs_, op_);
  };

  embed_k<<<RR, 256, 0, stream>>>(tokens, temb, pemb, x);
  cvt_bf16<<<2048, 256, 0, stream>>>(audio, audio_bf,
      (long long)BBn * AAn * DD, (long long)BBn * AAn * DD);
  cvt_bf16<<<2048, 256, 0, stream>>>(temb, emb_bf,
      (long long)VV * DD, (long long)VPAD * DD);
  build_biases<<<54, 256, 0, stream>>>(bq, bv, cbv, qkvb, kvb);

  WPtrs wp;
  wp.p[0] = Wq; wp.p[1] = Wk; wp.p[2] = Wv; wp.p[3] = Wo;
  wp.p[4] = cWq; wp.p[5] = cWk; wp.p[6] = cWv; wp.p[7] = cWo;
  wp.p[8] = W1; wp.p[9] = W2;

  for (int l = 0; l < 6; l++) {
    size_t vD = (size_t)l * DD;
    size_t vF = (size_t)l * FFD;

    transpose_layer<<<dim3(96, 24, 10), 256, 0, stream>>>(wp, l, wt);

    // --- self attention block ---
    ln_to_bf16<<<RR, 256, 0, stream>>>(x, aln_w + vD, aln_b + vD, hb);
    GEMM(hb, wt, qkv, qkvb + (size_t)l * 2304, nullptr, RR, 2304, DD, DD, 2304, OP_BIAS);
    self_attn_k<<<BBn * HH, 64, 0, stream>>>(qkv, attnb);
    GEMM(attnb, wt + (size_t)3 * MAT, x, bo + vD, x, RR, DD, DD, DD, DD, OP_BIAS | OP_RES);

    // --- cross attention block ---
    ln_to_bf16<<<RR, 256, 0, stream>>>(x, cln_w + vD, cln_b + vD, hb);
    GEMM(hb, wt + (size_t)4 * MAT, qkv, cbq + vD, nullptr, RR, DD, DD, DD, DD, OP_BIAS);
    GEMM(audio_bf, wt + (size_t)5 * MAT, KVc, kvb + (size_t)l * 1536, nullptr,
         BBn * AAn, 1536, DD, DD, 1536, OP_BIAS | OP_BF16);
    xattn_part<<<BBn * HH * NCH, 256, 0, stream>>>(qkv, KVc, part_o, part_ml);
    xattn_reduce<<<BBn * HH, 64, 0, stream>>>(part_o, part_ml, attnb);
    GEMM(attnb, wt + (size_t)7 * MAT, x, cbo + vD, x, RR, DD, DD, DD, DD, OP_BIAS | OP_RES);

    // --- MLP block ---
    ln_to_bf16<<<RR, 256, 0, stream>>>(x, mln_w + vD, mln_b + vD, hb);
    GEMM(hb, wt + (size_t)8 * MAT, ffb, b1 + vF, nullptr, RR, FFD, DD, DD, FFD,
         OP_BIAS | OP_GELU | OP_BF16);
    GEMM(ffb, wt + (size_t)8 * MAT + (size_t)DD * FFD, mlp2p, nullptr, nullptr,
         RR, DD, DD, FFD, DD, 0, 4, (size_t)RR * DD);
    mlp2_reduce<<<RR * DD / 256, 256, 0, stream>>>(mlp2p, b2 + vD, x);
  }

  // --- final LN + logits ---
  ln_to_bf16<<<RR, 256, 0, stream>>>(x, lnw, lnb, hb);
  GEMM(hb, emb_bf, d_out, nullptr, nullptr, RR, VPAD, DD, DD, VV, 0);
}

// Round 5
// 2334.534 us; speedup vs baseline: 2.1681x; 1.3534x over previous
//
#include <hip/hip_runtime.h>
#include <hip/hip_bf16.h>

// Whisper decoder step: L=6, D=768, H=12, FF=3072, V=51865, A=1500, B=32, S=8
#define HH 12
#define DD 768
#define FFD 3072
#define AAn 1500
#define BBn 32
#define RR 256          // B*S token rows
#define VV 51865
#define VPAD 51968      // 406*128
#define MAT (768*768)   // 589824
#define LSTR ((size_t)8 * MAT + 2 * (size_t)DD * FFD)   // wt elements per layer
#define TPAD 1536       // padded audio T

#define OP_BIAS 1
#define OP_GELU 2
#define OP_RES  4
#define OP_BF16 8
#define OP_SCAT 16

typedef float f32x4 __attribute__((ext_vector_type(4)));
typedef short s16x8 __attribute__((ext_vector_type(8)));

__device__ __forceinline__ unsigned short f2bf(float f) {
  union { float f; unsigned int u; } v; v.f = f;
  unsigned int r = (v.u + 0x7fffu + ((v.u >> 16) & 1u)) >> 16;
  return (unsigned short)r;
}

__device__ __forceinline__ void gld_lds16(const unsigned short* g, unsigned short* l) {
  __builtin_amdgcn_global_load_lds(
      (const __attribute__((address_space(1))) void*)g,
      (__attribute__((address_space(3))) void*)l, 16, 0, 0);
}

// ---------------- embedding ----------------
__global__ void embed_k(const int* __restrict__ toks, const float* __restrict__ emb,
                        const float* __restrict__ pos, float* __restrict__ x) {
  int r = blockIdx.x;
  int s = r & 7;
  int t = toks[r];
  for (int c = threadIdx.x; c < DD; c += 256)
    x[(size_t)r * DD + c] = emb[(size_t)t * DD + c] + pos[(size_t)s * DD + c];
}

// ---------------- f32 -> bf16 convert (with zero pad) ----------------
__global__ void cvt_bf16(const float* __restrict__ src, unsigned short* __restrict__ dst,
                         long long n_src, long long n_tot) {
  long long i = (long long)blockIdx.x * 256 + threadIdx.x;
  long long stride = (long long)gridDim.x * 256;
  for (; i < n_tot; i += stride)
    dst[i] = (i < n_src) ? f2bf(src[i]) : (unsigned short)0;
}

// ---------------- build combined qkv bias ----------------
__global__ void build_biases(const float* __restrict__ bq, const float* __restrict__ bv,
                             float* __restrict__ qkvb) {
  int i = blockIdx.x * 256 + threadIdx.x;
  if (i < 6 * 2304) {
    int l = i / 2304, n = i % 2304;
    qkvb[i] = (n < 768) ? bq[l * 768 + n] : (n < 1536 ? 0.f : bv[l * 768 + (n - 1536)]);
  }
}

// ---------------- LayerNorm -> bf16 ----------------
__global__ __launch_bounds__(256) void ln_to_bf16(
    const float* __restrict__ x, const float* __restrict__ w,
    const float* __restrict__ b, unsigned short* __restrict__ out) {
  int row = blockIdx.x;
  const float* xr = x + (size_t)row * DD;
  int t = threadIdx.x;
  float v0 = xr[t], v1 = xr[t + 256], v2 = xr[t + 512];
  float s = v0 + v1 + v2;
  for (int o = 32; o; o >>= 1) s += __shfl_down(s, o);
  __shared__ float red[4], red2[4];
  int wid = t >> 6, lane = t & 63;
  if (!lane) red[wid] = s;
  __syncthreads();
  float mean = (red[0] + red[1] + red[2] + red[3]) * (1.f / DD);
  float d0 = v0 - mean, d1 = v1 - mean, d2 = v2 - mean;
  float s2 = d0 * d0 + d1 * d1 + d2 * d2;
  for (int o = 32; o; o >>= 1) s2 += __shfl_down(s2, o);
  if (!lane) red2[wid] = s2;
  __syncthreads();
  float var = (red2[0] + red2[1] + red2[2] + red2[3]) * (1.f / DD);
  float rstd = rsqrtf(var + 1e-5f);
  out[(size_t)row * DD + t]       = f2bf(d0 * rstd * w[t] + b[t]);
  out[(size_t)row * DD + t + 256] = f2bf(d1 * rstd * w[t + 256] + b[t + 256]);
  out[(size_t)row * DD + t + 512] = f2bf(d2 * rstd * w[t + 512] + b[t + 512]);
}

// ---------------- batched transpose of ALL layer weights -> bf16 ----------------
struct WPtrs { const float* p[10]; };
__global__ __launch_bounds__(256) void transpose_layer(
    WPtrs wp, unsigned short* __restrict__ dst) {
  int zz = blockIdx.z % 10, l = blockIdx.z / 10;
  int R = (zz == 9) ? FFD : DD;
  int C = (zz == 8) ? FFD : DD;
  int ctile, rtile;
  if (zz == 9) { rtile = blockIdx.x; ctile = blockIdx.y; }
  else         { ctile = blockIdx.x; rtile = blockIdx.y; }
  if (ctile * 32 >= C || rtile * 32 >= R) return;
  const float* W = wp.p[zz] + (size_t)l * ((zz < 8) ? MAT : (size_t)DD * FFD);
  size_t doff = (zz < 8) ? (size_t)zz * MAT
                         : ((zz == 8) ? (size_t)8 * MAT : (size_t)8 * MAT + (size_t)FFD * DD);
  unsigned short* Wt = dst + (size_t)l * LSTR + doff;
  __shared__ unsigned short tile[32][33];
  int r0 = rtile * 32, c0 = ctile * 32;
  int tx = threadIdx.x & 31, ty = threadIdx.x >> 5;
  #pragma unroll
  for (int i = 0; i < 32; i += 8)
    tile[ty + i][tx] = f2bf(W[(size_t)(r0 + ty + i) * C + (c0 + tx)]);
  __syncthreads();
  #pragma unroll
  for (int i = 0; i < 32; i += 8)
    Wt[(size_t)(c0 + ty + i) * R + (r0 + tx)] = tile[tx][ty + i];
}

// ---------------- audio transpose: [b][1500][768] f32 -> [b][768][1536] bf16 -------
__global__ __launch_bounds__(256) void transpose_audio(
    const float* __restrict__ audio, unsigned short* __restrict__ aT) {
  int b = blockIdx.z;
  int t0 = blockIdx.x * 32, e0 = blockIdx.y * 32;
  __shared__ unsigned short tile[32][33];
  int tx = threadIdx.x & 31, ty = threadIdx.x >> 5;
  const float* src = audio + (size_t)b * AAn * DD;
  #pragma unroll
  for (int i = 0; i < 32; i += 8) {
    int t = t0 + ty + i;
    tile[ty + i][tx] = (t < AAn) ? f2bf(src[(size_t)t * DD + e0 + tx]) : (unsigned short)0;
  }
  __syncthreads();
  unsigned short* dst = aT + (size_t)b * DD * TPAD;
  #pragma unroll
  for (int i = 0; i < 32; i += 8)
    dst[(size_t)(e0 + ty + i) * TPAD + t0 + tx] = tile[tx][ty + i];
}

// ---------------- GEMM: C[M][*] = A[M][Klen](bf16) * Bt[N][Klen](bf16)^T ------------
// grid = (Npad/128, M/128, Z). Per-z offsets zsA/zsB/zsC/zsBias (elements).
// kz=1: split-K (kbeg = z*Klen, C partial at z*zsC, f32).
// OP_SCAT: write bf16 at [(r>>3)*256 + z*8 + (r&7)]*768 + c, rows r>>3<12 only.
__global__ __launch_bounds__(256, 2) void gemm_bt(
    const unsigned short* __restrict__ A, const unsigned short* __restrict__ Bt,
    void* __restrict__ Cv, const float* __restrict__ bias,
    const float* __restrict__ resid, int Klen, int Kstride, int Nout, int Cld,
    long zsA, long zsB, long zsC, long zsBias, int kz, int op) {
  __shared__ unsigned short As[128 * 32];
  __shared__ unsigned short Bs[128 * 32];
  const int n0 = blockIdx.x * 128, m0 = blockIdx.y * 128;
  const int z = blockIdx.z;
  const int kbeg = kz ? z * Klen : 0;
  const int tid = threadIdx.x, w = tid >> 6, l = tid & 63;
  const int wr = w >> 1, wc = w & 1;
  f32x4 acc[4][4] = {};

  const int rA = w * 32 + (l >> 2);
  const int cA = (l & 3) * 8;
  const unsigned short* gA = A + (size_t)z * zsA + (size_t)(m0 + rA) * Kstride + cA + kbeg;
  const unsigned short* gB = Bt + (size_t)z * zsB + (size_t)(n0 + rA) * Kstride + cA + kbeg;

  for (int k0 = 0; k0 < Klen; k0 += 32) {
    __syncthreads();
    gld_lds16(gA + k0,                        &As[w * 1024]);
    gld_lds16(gA + (size_t)16 * Kstride + k0, &As[w * 1024 + 512]);
    gld_lds16(gB + k0,                        &Bs[w * 1024]);
    gld_lds16(gB + (size_t)16 * Kstride + k0, &Bs[w * 1024 + 512]);
    __syncthreads();
    s16x8 aF[4], bF[4];
    #pragma unroll
    for (int m = 0; m < 4; m++)
      aF[m] = *(const s16x8*)&As[(wr * 64 + m * 16 + (l & 15)) * 32 + (l >> 4) * 8];
    #pragma unroll
    for (int n = 0; n < 4; n++)
      bF[n] = *(const s16x8*)&Bs[(wc * 64 + n * 16 + (l & 15)) * 32 + (l >> 4) * 8];
    #pragma unroll
    for (int m = 0; m < 4; m++)
      #pragma unroll
      for (int n = 0; n < 4; n++)
        acc[m][n] = __builtin_amdgcn_mfma_f32_16x16x32_bf16(aF[m], bF[n], acc[m][n], 0, 0, 0);
  }

  const float* biasz = bias + (size_t)z * zsBias;
  #pragma unroll
  for (int m = 0; m < 4; m++) {
    int rr0 = m0 + wr * 64 + m * 16 + (l >> 4) * 4;
    #pragma unroll
    for (int n = 0; n < 4; n++) {
      int c = n0 + wc * 64 + n * 16 + (l & 15);
      if (c < Nout) {
        float bval = (op & OP_BIAS) ? biasz[c] : 0.f;
        #pragma unroll
        for (int j = 0; j < 4; j++) {
          int r = rr0 + j;
          float val = acc[m][n][j] + bval;
          if (op & OP_GELU) val = 0.5f * val * (1.f + erff(val * 0.70710678118f));
          if (op & OP_RES)  val += resid[(size_t)r * Cld + c];
          if (op & OP_SCAT) {
            int hh = r >> 3;
            if (hh < HH)
              ((unsigned short*)Cv)[((size_t)hh * 256 + z * 8 + (r & 7)) * 768 + c] = f2bf(val);
          } else if (op & OP_BF16) {
            ((unsigned short*)Cv)[(size_t)z * zsC + (size_t)r * Cld + c] = f2bf(val);
          } else {
            ((float*)Cv)[(size_t)z * zsC + (size_t)r * Cld + c] = val;
          }
        }
      }
    }
  }
}

// ---------------- MLP2 split-K reduce + bias + residual ----------------
__global__ void mlp2_reduce(const float* __restrict__ part, const float* __restrict__ b2,
                            float* __restrict__ x) {
  int i = blockIdx.x * 256 + threadIdx.x;
  int c = i % DD;
  x[i] += b2[c] + part[i] + part[i + RR * DD] + part[i + 2 * RR * DD] + part[i + 3 * RR * DD];
}

// ---------------- self attention (S=8, causal), q/k/v packed [256][2304] ----------
__global__ __launch_bounds__(64) void self_attn_k(
    const float* __restrict__ qkv, unsigned short* __restrict__ out) {
  int bh = blockIdx.x;
  int b = bh / HH, h = bh % HH;
  __shared__ float qs[8][65], ks[8][65], vs[8][65], ps[8][9];
  int l = threadIdx.x;
  for (int s = 0; s < 8; s++) {
    size_t base = ((size_t)(b * 8 + s)) * 2304 + h * 64 + l;
    qs[s][l] = qkv[base]; ks[s][l] = qkv[base + 768]; vs[s][l] = qkv[base + 1536];
  }
  __syncthreads();
  int s = l >> 3, t = l & 7;
  float sc = 0.f;
  #pragma unroll
  for (int d = 0; d < 64; d++) sc += qs[s][d] * ks[t][d];
  sc *= 0.125f;
  if (t > s) sc = -1e30f;
  float mx = sc;
  for (int o = 4; o; o >>= 1) mx = fmaxf(mx, __shfl_xor(mx, o, 8));
  float e = __expf(sc - mx);
  float sum = e;
  for (int o = 4; o; o >>= 1) sum += __shfl_xor(sum, o, 8);
  ps[s][t] = e / sum;
  __syncthreads();
  for (int s2 = 0; s2 < 8; s2++) {
    float acc = 0.f;
    #pragma unroll
    for (int t2 = 0; t2 < 8; t2++) acc += ps[s2][t2] * vs[t2][l];
    out[((size_t)(b * 8 + s2)) * DD + h * 64 + l] = f2bf(acc);
  }
}

// ---------------- Q' build: Q'[b*128 + h*8 + s][e] = 0.125 * Qh[s] . cWk[e, h-block]
__global__ __launch_bounds__(256) void qprime_k(
    const float* __restrict__ qproj, const float* __restrict__ cWk,
    unsigned short* __restrict__ Qp) {
  int bh = blockIdx.x;              // b*12 + h
  int b = bh / HH, h = bh % HH;
  __shared__ float qs[8][64];
  int tid = threadIdx.x;
  for (int i = tid; i < 512; i += 256) {
    int s = i >> 6, d = i & 63;
    qs[s][d] = qproj[(size_t)(b * 8 + s) * 768 + h * 64 + d] * 0.125f;
  }
  __syncthreads();
  for (int e = tid; e < 768; e += 256) {
    const float* wr = cWk + (size_t)e * 768 + h * 64;
    float acc[8] = {};
    #pragma unroll 16
    for (int k = 0; k < 64; k++) {
      float wv = wr[k];
      #pragma unroll
      for (int s = 0; s < 8; s++) acc[s] += qs[s][k] * wv;
    }
    #pragma unroll
    for (int s = 0; s < 8; s++)
      Qp[((size_t)b * 128 + h * 8 + s) * 768 + e] = f2bf(acc[s]);
  }
}

// ---------------- cross softmax: S f32 [32][128][1536] -> P bf16 (normalized) ------
__global__ __launch_bounds__(256) void xsoftmax_k(
    const float* __restrict__ S, unsigned short* __restrict__ P) {
  int bh = blockIdx.x;              // b*12 + h
  int b = bh / HH, h = bh % HH;
  int w = threadIdx.x >> 6, ln = threadIdx.x & 63;
  for (int rr = w; rr < 8; rr += 4) {
    size_t row = (size_t)b * 128 + h * 8 + rr;
    const float* sr = S + row * TPAD;
    unsigned short* pr = P + row * TPAD;
    float v[24];
    float mx = -1e30f;
    #pragma unroll
    for (int i = 0; i < 24; i++) {
      int t = ln + i * 64;
      v[i] = (t < AAn) ? sr[t] : -1e30f;
      mx = fmaxf(mx, v[i]);
    }
    for (int o = 32; o; o >>= 1) mx = fmaxf(mx, __shfl_xor(mx, o));
    float sum = 0.f;
    #pragma unroll
    for (int i = 0; i < 24; i++) { v[i] = __expf(v[i] - mx); sum += v[i]; }
    for (int o = 32; o; o >>= 1) sum += __shfl_xor(sum, o);
    float inv = 1.f / sum;
    #pragma unroll
    for (int i = 0; i < 24; i++) {
      int t = ln + i * 64;
      pr[t] = f2bf((t < AAn) ? v[i] * inv : 0.f);
    }
  }
}

// ---------------- host ----------------
static inline void* carve(char*& p, size_t bytes) {
  void* r = p;
  p += (bytes + 255) & ~(size_t)255;
  return r;
}

extern "C" void kernel_launch(void* const* d_in, const int* in_sizes, int n_in,
                              void* d_out, int out_size, void* d_ws, size_t ws_size,
                              hipStream_t stream) {
  const int*   tokens = (const int*)d_in[0];
  const float* audio  = (const float*)d_in[1];
  const float* temb   = (const float*)d_in[2];
  const float* pemb   = (const float*)d_in[3];
  const float* aln_w  = (const float*)d_in[4];
  const float* aln_b  = (const float*)d_in[5];
  const float* Wq = (const float*)d_in[6];
  const float* bq = (const float*)d_in[7];
  const float* Wk = (const float*)d_in[8];
  const float* Wv = (const float*)d_in[9];
  const float* bv = (const float*)d_in[10];
  const float* Wo = (const float*)d_in[11];
  const float* bo = (const float*)d_in[12];
  const float* cln_w = (const float*)d_in[13];
  const float* cln_b = (const float*)d_in[14];
  const float* cWq = (const float*)d_in[15];
  const float* cbq = (const float*)d_in[16];
  const float* cWk = (const float*)d_in[17];
  const float* cWv = (const float*)d_in[18];
  const float* cbv = (const float*)d_in[19];
  const float* cWo = (const float*)d_in[20];
  const float* cbo = (const float*)d_in[21];
  const float* mln_w = (const float*)d_in[22];
  const float* mln_b = (const float*)d_in[23];
  const float* W1 = (const float*)d_in[24];
  const float* b1 = (const float*)d_in[25];
  const float* W2 = (const float*)d_in[26];
  const float* b2 = (const float*)d_in[27];
  const float* lnw = (const float*)d_in[28];
  const float* lnb = (const float*)d_in[29];

  char* cur = (char*)d_ws;
  float* x    = (float*)carve(cur, (size_t)RR * DD * 4);
  float* qkv  = (float*)carve(cur, (size_t)RR * 2304 * 4);
  unsigned short* hb    = (unsigned short*)carve(cur, (size_t)RR * DD * 2);
  unsigned short* attnb = (unsigned short*)carve(cur, (size_t)RR * DD * 2);
  unsigned short* ffb   = (unsigned short*)carve(cur, (size_t)RR * FFD * 2);
  unsigned short* wt    = (unsigned short*)carve(cur, LSTR * 6 * 2);
  unsigned short* audio_bf = (unsigned short*)carve(cur, (size_t)BBn * AAn * DD * 2);
  unsigned short* audioT   = (unsigned short*)carve(cur, (size_t)BBn * DD * TPAD * 2);
  unsigned short* emb_bf = (unsigned short*)carve(cur, (size_t)VPAD * DD * 2);
  float* Sb = (float*)carve(cur, (size_t)BBn * 128 * TPAD * 4);
  unsigned short* Pb  = (unsigned short*)carve(cur, (size_t)BBn * 128 * TPAD * 2);
  unsigned short* Qp  = (unsigned short*)carve(cur, (size_t)BBn * 128 * DD * 2);
  unsigned short* Rbf = (unsigned short*)carve(cur, (size_t)HH * 256 * DD * 2);
  float* qkvb  = (float*)carve(cur, (size_t)6 * 2304 * 4);
  float* mlp2p = (float*)carve(cur, (size_t)4 * RR * DD * 4);

  auto GEMM = [&](const unsigned short* A_, const unsigned short* Bt_, void* C_,
                  const float* bias_, const float* res_, int M_, int Np_,
                  int Klen_, int Kstr_, int Nout_, int Cld_, int op_,
                  int Z_ = 1, long zsA_ = 0, long zsB_ = 0, long zsC_ = 0,
                  long zsBias_ = 0, int kz_ = 0) {
    dim3 g(Np_ / 128, M_ / 128, Z_);
    gemm_bt<<<g, 256, 0, stream>>>(A_, Bt_, C_, bias_, res_, Klen_, Kstr_,
                                   Nout_, Cld_, zsA_, zsB_, zsC_, zsBias_, kz_, op_);
  };

  embed_k<<<RR, 256, 0, stream>>>(tokens, temb, pemb, x);
  cvt_bf16<<<2048, 256, 0, stream>>>(audio, audio_bf,
      (long long)BBn * AAn * DD, (long long)BBn * AAn * DD);
  cvt_bf16<<<2048, 256, 0, stream>>>(temb, emb_bf,
      (long long)VV * DD, (long long)VPAD * DD);
  build_biases<<<54, 256, 0, stream>>>(bq, bv, qkvb);
  transpose_audio<<<dim3(48, 24, BBn), 256, 0, stream>>>(audio, audioT);

  WPtrs wp;
  wp.p[0] = Wq; wp.p[1] = Wk; wp.p[2] = Wv; wp.p[3] = Wo;
  wp.p[4] = cWq; wp.p[5] = cWk; wp.p[6] = cWv; wp.p[7] = cWo;
  wp.p[8] = W1; wp.p[9] = W2;
  transpose_layer<<<dim3(96, 24, 60), 256, 0, stream>>>(wp, wt);

  for (int l = 0; l < 6; l++) {
    size_t vD = (size_t)l * DD;
    size_t vF = (size_t)l * FFD;
    unsigned short* wtl = wt + (size_t)l * LSTR;

    // --- self attention block ---
    ln_to_bf16<<<RR, 256, 0, stream>>>(x, aln_w + vD, aln_b + vD, hb);
    GEMM(hb, wtl, qkv, qkvb + (size_t)l * 2304, nullptr, RR, 2304, DD, DD, 2304, 2304, OP_BIAS);
    self_attn_k<<<BBn * HH, 64, 0, stream>>>(qkv, attnb);
    GEMM(attnb, wtl + (size_t)3 * MAT, x, bo + vD, x, RR, DD, DD, DD, DD, DD, OP_BIAS | OP_RES);

    // --- cross attention block (KV-free formulation) ---
    ln_to_bf16<<<RR, 256, 0, stream>>>(x, cln_w + vD, cln_b + vD, hb);
    GEMM(hb, wtl + (size_t)4 * MAT, qkv, cbq + vD, nullptr, RR, DD, DD, DD, DD, DD, OP_BIAS);
    qprime_k<<<BBn * HH, 256, 0, stream>>>(qkv, cWk + (size_t)l * MAT, Qp);
    // scores: per b, S[b] = Qp[b] (128x768) @ audio_b^T  -> [128][1536] f32
    GEMM(Qp, audio_bf, Sb, nullptr, nullptr, 128, TPAD, DD, DD, TPAD, TPAD, 0,
         BBn, (long)128 * DD, (long)AAn * DD, (long)128 * TPAD, 0, 0);
    xsoftmax_k<<<BBn * HH, 256, 0, stream>>>(Sb, Pb);
    // PV: per b, R = P[b] (128x1536) @ audioT_b^T -> scatter to Rbf[h][b*8+s][e]
    GEMM(Pb, audioT, Rbf, nullptr, nullptr, 128, DD, TPAD, TPAD, DD, DD, OP_SCAT,
         BBn, (long)128 * TPAD, (long)DD * TPAD, 0, 0, 0);
    // O head-proj: per h, attnb[.,h*64..] = Rbf[h] @ cWv_h + cbv_h
    GEMM(Rbf, wtl + (size_t)6 * MAT, attnb, cbv + vD, nullptr, RR, 128, DD, DD, 64, DD,
         OP_BIAS | OP_BF16, HH, (long)256 * DD, (long)64 * DD, 64, 64, 0);
    GEMM(attnb, wtl + (size_t)7 * MAT, x, cbo + vD, x, RR, DD, DD, DD, DD, DD, OP_BIAS | OP_RES);

    // --- MLP block ---
    ln_to_bf16<<<RR, 256, 0, stream>>>(x, mln_w + vD, mln_b + vD, hb);
    GEMM(hb, wtl + (size_t)8 * MAT, ffb, b1 + vF, nullptr, RR, FFD, DD, DD, FFD, FFD,
         OP_BIAS | OP_GELU | OP_BF16);
    GEMM(ffb, wtl + (size_t)8 * MAT + (size_t)DD * FFD, mlp2p, nullptr, nullptr,
         RR, DD, DD, FFD, DD, DD, 0, 4, 0, 0, (long)RR * DD, 0, 1);
    mlp2_reduce<<<RR * DD / 256, 256, 0, stream>>>(mlp2p, b2 + vD, x);
  }

  // --- final LN + logits ---
  ln_to_bf16<<<RR, 256, 0, stream>>>(x, lnw, lnb, hb);
  GEMM(hb, emb_bf, d_out, nullptr, nullptr, RR, VPAD, DD, DD, VV, VV, 0);
}

// Round 6
// 1618.034 us; speedup vs baseline: 3.1282x; 1.4428x over previous
//
#include <hip/hip_runtime.h>
#include <hip/hip_bf16.h>

// Whisper decoder step: L=6, D=768, H=12, FF=3072, V=51865, A=1500, B=32, S=8
#define HH 12
#define DD 768
#define FFD 3072
#define AAn 1500
#define BBn 32
#define RR 256          // B*S token rows
#define VV 51865
#define VPAD 51968      // 406*128
#define MAT (768*768)   // 589824
#define LSTR ((size_t)8 * MAT + 2 * (size_t)DD * FFD)   // wt elements per layer
#define TPAD 1536       // padded audio T

#define OP_BIAS 1
#define OP_GELU 2
#define OP_RES  4
#define OP_BF16 8
#define OP_SCAT 16

typedef float f32x4 __attribute__((ext_vector_type(4)));
typedef short s16x8 __attribute__((ext_vector_type(8)));

__device__ __forceinline__ unsigned short f2bf(float f) {
  union { float f; unsigned int u; } v; v.f = f;
  unsigned int r = (v.u + 0x7fffu + ((v.u >> 16) & 1u)) >> 16;
  return (unsigned short)r;
}

__device__ __forceinline__ void gld_lds16(const unsigned short* g, unsigned short* l) {
  __builtin_amdgcn_global_load_lds(
      (const __attribute__((address_space(1))) void*)g,
      (__attribute__((address_space(3))) void*)l, 16, 0, 0);
}

// ---------------- embedding ----------------
__global__ void embed_k(const int* __restrict__ toks, const float* __restrict__ emb,
                        const float* __restrict__ pos, float* __restrict__ x) {
  int r = blockIdx.x;
  int s = r & 7;
  int t = toks[r];
  for (int c = threadIdx.x; c < DD; c += 256)
    x[(size_t)r * DD + c] = emb[(size_t)t * DD + c] + pos[(size_t)s * DD + c];
}

// ---------------- f32 -> bf16 convert (with zero pad) ----------------
__global__ void cvt_bf16(const float* __restrict__ src, unsigned short* __restrict__ dst,
                         long long n_src, long long n_tot) {
  long long i = (long long)blockIdx.x * 256 + threadIdx.x;
  long long stride = (long long)gridDim.x * 256;
  for (; i < n_tot; i += stride)
    dst[i] = (i < n_src) ? f2bf(src[i]) : (unsigned short)0;
}

// ---------------- build combined qkv bias ----------------
__global__ void build_biases(const float* __restrict__ bq, const float* __restrict__ bv,
                             float* __restrict__ qkvb) {
  int i = blockIdx.x * 256 + threadIdx.x;
  if (i < 6 * 2304) {
    int l = i / 2304, n = i % 2304;
    qkvb[i] = (n < 768) ? bq[l * 768 + n] : (n < 1536 ? 0.f : bv[l * 768 + (n - 1536)]);
  }
}

// ---------------- LayerNorm -> bf16 ----------------
__global__ __launch_bounds__(256) void ln_to_bf16(
    const float* __restrict__ x, const float* __restrict__ w,
    const float* __restrict__ b, unsigned short* __restrict__ out) {
  int row = blockIdx.x;
  const float* xr = x + (size_t)row * DD;
  int t = threadIdx.x;
  float v0 = xr[t], v1 = xr[t + 256], v2 = xr[t + 512];
  float s = v0 + v1 + v2;
  for (int o = 32; o; o >>= 1) s += __shfl_down(s, o);
  __shared__ float red[4], red2[4];
  int wid = t >> 6, lane = t & 63;
  if (!lane) red[wid] = s;
  __syncthreads();
  float mean = (red[0] + red[1] + red[2] + red[3]) * (1.f / DD);
  float d0 = v0 - mean, d1 = v1 - mean, d2 = v2 - mean;
  float s2 = d0 * d0 + d1 * d1 + d2 * d2;
  for (int o = 32; o; o >>= 1) s2 += __shfl_down(s2, o);
  if (!lane) red2[wid] = s2;
  __syncthreads();
  float var = (red2[0] + red2[1] + red2[2] + red2[3]) * (1.f / DD);
  float rstd = rsqrtf(var + 1e-5f);
  out[(size_t)row * DD + t]       = f2bf(d0 * rstd * w[t] + b[t]);
  out[(size_t)row * DD + t + 256] = f2bf(d1 * rstd * w[t + 256] + b[t + 256]);
  out[(size_t)row * DD + t + 512] = f2bf(d2 * rstd * w[t + 512] + b[t + 512]);
}

// ---------------- fused MLP2 split-K reduce + residual + next LayerNorm ----------
__global__ __launch_bounds__(256) void mlp2_reduce_ln(
    const float* __restrict__ part, const float* __restrict__ b2,
    float* __restrict__ x, const float* __restrict__ w,
    const float* __restrict__ b, unsigned short* __restrict__ out) {
  int row = blockIdx.x;
  int t = threadIdx.x;
  float v[3];
  #pragma unroll
  for (int j = 0; j < 3; j++) {
    int c = t + j * 256;
    size_t i = (size_t)row * DD + c;
    float nv = x[i] + b2[c] + part[i] + part[i + (size_t)RR * DD]
             + part[i + 2 * (size_t)RR * DD] + part[i + 3 * (size_t)RR * DD];
    x[i] = nv;
    v[j] = nv;
  }
  float s = v[0] + v[1] + v[2];
  for (int o = 32; o; o >>= 1) s += __shfl_down(s, o);
  __shared__ float red[4], red2[4];
  int wid = t >> 6, lane = t & 63;
  if (!lane) red[wid] = s;
  __syncthreads();
  float mean = (red[0] + red[1] + red[2] + red[3]) * (1.f / DD);
  float d0 = v[0] - mean, d1 = v[1] - mean, d2 = v[2] - mean;
  float s2 = d0 * d0 + d1 * d1 + d2 * d2;
  for (int o = 32; o; o >>= 1) s2 += __shfl_down(s2, o);
  if (!lane) red2[wid] = s2;
  __syncthreads();
  float var = (red2[0] + red2[1] + red2[2] + red2[3]) * (1.f / DD);
  float rstd = rsqrtf(var + 1e-5f);
  out[(size_t)row * DD + t]       = f2bf(d0 * rstd * w[t] + b[t]);
  out[(size_t)row * DD + t + 256] = f2bf(d1 * rstd * w[t + 256] + b[t + 256]);
  out[(size_t)row * DD + t + 512] = f2bf(d2 * rstd * w[t + 512] + b[t + 512]);
}

// ---------------- batched transpose of ALL layer weights -> bf16 ----------------
struct WPtrs { const float* p[10]; };
__global__ __launch_bounds__(256) void transpose_layer(
    WPtrs wp, unsigned short* __restrict__ dst) {
  int zz = blockIdx.z % 10, l = blockIdx.z / 10;
  int R = (zz == 9) ? FFD : DD;
  int C = (zz == 8) ? FFD : DD;
  int ctile, rtile;
  if (zz == 9) { rtile = blockIdx.x; ctile = blockIdx.y; }
  else         { ctile = blockIdx.x; rtile = blockIdx.y; }
  if (ctile * 32 >= C || rtile * 32 >= R) return;
  const float* W = wp.p[zz] + (size_t)l * ((zz < 8) ? MAT : (size_t)DD * FFD);
  size_t doff = (zz < 8) ? (size_t)zz * MAT
                         : ((zz == 8) ? (size_t)8 * MAT : (size_t)8 * MAT + (size_t)FFD * DD);
  unsigned short* Wt = dst + (size_t)l * LSTR + doff;
  __shared__ unsigned short tile[32][33];
  int r0 = rtile * 32, c0 = ctile * 32;
  int tx = threadIdx.x & 31, ty = threadIdx.x >> 5;
  #pragma unroll
  for (int i = 0; i < 32; i += 8)
    tile[ty + i][tx] = f2bf(W[(size_t)(r0 + ty + i) * C + (c0 + tx)]);
  __syncthreads();
  #pragma unroll
  for (int i = 0; i < 32; i += 8)
    Wt[(size_t)(c0 + ty + i) * R + (r0 + tx)] = tile[tx][ty + i];
}

// ---------------- audio transpose: [b][1500][768] f32 -> [b][768][1536] bf16 -------
__global__ __launch_bounds__(256) void transpose_audio(
    const float* __restrict__ audio, unsigned short* __restrict__ aT) {
  int b = blockIdx.z;
  int t0 = blockIdx.x * 32, e0 = blockIdx.y * 32;
  __shared__ unsigned short tile[32][33];
  int tx = threadIdx.x & 31, ty = threadIdx.x >> 5;
  const float* src = audio + (size_t)b * AAn * DD;
  #pragma unroll
  for (int i = 0; i < 32; i += 8) {
    int t = t0 + ty + i;
    tile[ty + i][tx] = (t < AAn) ? f2bf(src[(size_t)t * DD + e0 + tx]) : (unsigned short)0;
  }
  __syncthreads();
  unsigned short* dst = aT + (size_t)b * DD * TPAD;
  #pragma unroll
  for (int i = 0; i < 32; i += 8)
    dst[(size_t)(e0 + ty + i) * TPAD + t0 + tx] = tile[tx][ty + i];
}

// ---------------- GEMM: C[M][*] = A[M][Klen](bf16) * Bt[N][Klen](bf16)^T ------------
// Template tile BM x BN (128x128 or 64x64). grid = (Npad/BN, M/BM, Z).
// Per-z offsets zsA/zsB/zsC/zsBias (elements). kz=1: split-K.
// OP_SCAT: write bf16 at [(r>>3)*256 + z*8 + (r&7)]*768 + c, rows r>>3<12 only.
template <int BM, int BN>
__global__ __launch_bounds__(256, 2) void gemm_t(
    const unsigned short* __restrict__ A, const unsigned short* __restrict__ Bt,
    void* __restrict__ Cv, const float* __restrict__ bias,
    const float* __restrict__ resid, int Klen, int Kstride, int Nout, int Cld,
    long zsA, long zsB, long zsC, long zsBias, int kz, int op) {
  constexpr int WM = BM / 2, WN = BN / 2;
  constexpr int MREP = WM / 16, NREP = WN / 16;
  __shared__ unsigned short As[BM * 32];
  __shared__ unsigned short Bs[BN * 32];
  const int n0 = blockIdx.x * BN, m0 = blockIdx.y * BM;
  const int z = blockIdx.z;
  const int kbeg = kz ? z * Klen : 0;
  const int tid = threadIdx.x, w = tid >> 6, l = tid & 63;
  const int wr = w >> 1, wc = w & 1;
  f32x4 acc[MREP][NREP] = {};

  const int rbase = w * 16 + (l >> 2);
  const int cA = (l & 3) * 8;
  const unsigned short* gA = A + (size_t)z * zsA + (size_t)(m0 + rbase) * Kstride + cA + kbeg;
  const unsigned short* gB = Bt + (size_t)z * zsB + (size_t)(n0 + rbase) * Kstride + cA + kbeg;

  for (int k0 = 0; k0 < Klen; k0 += 32) {
    __syncthreads();
    #pragma unroll
    for (int p = 0; p < BM / 64; p++)
      gld_lds16(gA + (size_t)(p * 64) * Kstride + k0, &As[(p * 64 + w * 16) * 32]);
    #pragma unroll
    for (int p = 0; p < BN / 64; p++)
      gld_lds16(gB + (size_t)(p * 64) * Kstride + k0, &Bs[(p * 64 + w * 16) * 32]);
    __syncthreads();
    s16x8 aF[MREP], bF[NREP];
    #pragma unroll
    for (int m = 0; m < MREP; m++)
      aF[m] = *(const s16x8*)&As[(wr * WM + m * 16 + (l & 15)) * 32 + (l >> 4) * 8];
    #pragma unroll
    for (int n = 0; n < NREP; n++)
      bF[n] = *(const s16x8*)&Bs[(wc * WN + n * 16 + (l & 15)) * 32 + (l >> 4) * 8];
    #pragma unroll
    for (int m = 0; m < MREP; m++)
      #pragma unroll
      for (int n = 0; n < NREP; n++)
        acc[m][n] = __builtin_amdgcn_mfma_f32_16x16x32_bf16(aF[m], bF[n], acc[m][n], 0, 0, 0);
  }

  const float* biasz = bias + (size_t)z * zsBias;
  #pragma unroll
  for (int m = 0; m < MREP; m++) {
    int rr0 = m0 + wr * WM + m * 16 + (l >> 4) * 4;
    #pragma unroll
    for (int n = 0; n < NREP; n++) {
      int c = n0 + wc * WN + n * 16 + (l & 15);
      if (c < Nout) {
        float bval = (op & OP_BIAS) ? biasz[c] : 0.f;
        #pragma unroll
        for (int j = 0; j < 4; j++) {
          int r = rr0 + j;
          float val = acc[m][n][j] + bval;
          if (op & OP_GELU) val = 0.5f * val * (1.f + erff(val * 0.70710678118f));
          if (op & OP_RES)  val += resid[(size_t)r * Cld + c];
          if (op & OP_SCAT) {
            int hh = r >> 3;
            if (hh < HH)
              ((unsigned short*)Cv)[((size_t)hh * 256 + z * 8 + (r & 7)) * 768 + c] = f2bf(val);
          } else if (op & OP_BF16) {
            ((unsigned short*)Cv)[(size_t)z * zsC + (size_t)r * Cld + c] = f2bf(val);
          } else {
            ((float*)Cv)[(size_t)z * zsC + (size_t)r * Cld + c] = val;
          }
        }
      }
    }
  }
}

// ---------------- self attention (S=8, causal), q/k/v packed [256][2304] ----------
__global__ __launch_bounds__(64) void self_attn_k(
    const float* __restrict__ qkv, unsigned short* __restrict__ out) {
  int bh = blockIdx.x;
  int b = bh / HH, h = bh % HH;
  __shared__ float qs[8][65], ks[8][65], vs[8][65], ps[8][9];
  int l = threadIdx.x;
  for (int s = 0; s < 8; s++) {
    size_t base = ((size_t)(b * 8 + s)) * 2304 + h * 64 + l;
    qs[s][l] = qkv[base]; ks[s][l] = qkv[base + 768]; vs[s][l] = qkv[base + 1536];
  }
  __syncthreads();
  int s = l >> 3, t = l & 7;
  float sc = 0.f;
  #pragma unroll
  for (int d = 0; d < 64; d++) sc += qs[s][d] * ks[t][d];
  sc *= 0.125f;
  if (t > s) sc = -1e30f;
  float mx = sc;
  for (int o = 4; o; o >>= 1) mx = fmaxf(mx, __shfl_xor(mx, o, 8));
  float e = __expf(sc - mx);
  float sum = e;
  for (int o = 4; o; o >>= 1) sum += __shfl_xor(sum, o, 8);
  ps[s][t] = e / sum;
  __syncthreads();
  for (int s2 = 0; s2 < 8; s2++) {
    float acc = 0.f;
    #pragma unroll
    for (int t2 = 0; t2 < 8; t2++) acc += ps[s2][t2] * vs[t2][l];
    out[((size_t)(b * 8 + s2)) * DD + h * 64 + l] = f2bf(acc);
  }
}

// ---------------- Q' build: Q'[b*128 + h*8 + s][e] = 0.125 * Qh[s] . cWk[e, h-block]
__global__ __launch_bounds__(256) void qprime_k(
    const float* __restrict__ qproj, const float* __restrict__ cWk,
    unsigned short* __restrict__ Qp) {
  int bh = blockIdx.x;              // b*12 + h
  int b = bh / HH, h = bh % HH;
  __shared__ float qs[8][64];
  int tid = threadIdx.x;
  for (int i = tid; i < 512; i += 256) {
    int s = i >> 6, d = i & 63;
    qs[s][d] = qproj[(size_t)(b * 8 + s) * 768 + h * 64 + d] * 0.125f;
  }
  __syncthreads();
  for (int e = tid; e < 768; e += 256) {
    const float* wr = cWk + (size_t)e * 768 + h * 64;
    float acc[8] = {};
    #pragma unroll 16
    for (int k = 0; k < 64; k++) {
      float wv = wr[k];
      #pragma unroll
      for (int s = 0; s < 8; s++) acc[s] += qs[s][k] * wv;
    }
    #pragma unroll
    for (int s = 0; s < 8; s++)
      Qp[((size_t)b * 128 + h * 8 + s) * 768 + e] = f2bf(acc[s]);
  }
}

// ---------------- cross softmax: S f32 [32][128][1536] -> P bf16 (normalized) ------
__global__ __launch_bounds__(256) void xsoftmax_k(
    const float* __restrict__ S, unsigned short* __restrict__ P) {
  int bh = blockIdx.x;              // b*12 + h
  int b = bh / HH, h = bh % HH;
  int w = threadIdx.x >> 6, ln = threadIdx.x & 63;
  for (int rr = w; rr < 8; rr += 4) {
    size_t row = (size_t)b * 128 + h * 8 + rr;
    const float* sr = S + row * TPAD;
    unsigned short* pr = P + row * TPAD;
    float v[24];
    float mx = -1e30f;
    #pragma unroll
    for (int i = 0; i < 24; i++) {
      int t = ln + i * 64;
      v[i] = (t < AAn) ? sr[t] : -1e30f;
      mx = fmaxf(mx, v[i]);
    }
    for (int o = 32; o; o >>= 1) mx = fmaxf(mx, __shfl_xor(mx, o));
    float sum = 0.f;
    #pragma unroll
    for (int i = 0; i < 24; i++) { v[i] = __expf(v[i] - mx); sum += v[i]; }
    for (int o = 32; o; o >>= 1) sum += __shfl_xor(sum, o);
    float inv = 1.f / sum;
    #pragma unroll
    for (int i = 0; i < 24; i++) {
      int t = ln + i * 64;
      pr[t] = f2bf((t < AAn) ? v[i] * inv : 0.f);
    }
  }
}

// ---------------- host ----------------
static inline void* carve(char*& p, size_t bytes) {
  void* r = p;
  p += (bytes + 255) & ~(size_t)255;
  return r;
}

extern "C" void kernel_launch(void* const* d_in, const int* in_sizes, int n_in,
                              void* d_out, int out_size, void* d_ws, size_t ws_size,
                              hipStream_t stream) {
  const int*   tokens = (const int*)d_in[0];
  const float* audio  = (const float*)d_in[1];
  const float* temb   = (const float*)d_in[2];
  const float* pemb   = (const float*)d_in[3];
  const float* aln_w  = (const float*)d_in[4];
  const float* aln_b  = (const float*)d_in[5];
  const float* Wq = (const float*)d_in[6];
  const float* bq = (const float*)d_in[7];
  const float* Wk = (const float*)d_in[8];
  const float* Wv = (const float*)d_in[9];
  const float* bv = (const float*)d_in[10];
  const float* Wo = (const float*)d_in[11];
  const float* bo = (const float*)d_in[12];
  const float* cln_w = (const float*)d_in[13];
  const float* cln_b = (const float*)d_in[14];
  const float* cWq = (const float*)d_in[15];
  const float* cbq = (const float*)d_in[16];
  const float* cWk = (const float*)d_in[17];
  const float* cWv = (const float*)d_in[18];
  const float* cbv = (const float*)d_in[19];
  const float* cWo = (const float*)d_in[20];
  const float* cbo = (const float*)d_in[21];
  const float* mln_w = (const float*)d_in[22];
  const float* mln_b = (const float*)d_in[23];
  const float* W1 = (const float*)d_in[24];
  const float* b1 = (const float*)d_in[25];
  const float* W2 = (const float*)d_in[26];
  const float* b2 = (const float*)d_in[27];
  const float* lnw = (const float*)d_in[28];
  const float* lnb = (const float*)d_in[29];

  char* cur = (char*)d_ws;
  float* x    = (float*)carve(cur, (size_t)RR * DD * 4);
  float* qkv  = (float*)carve(cur, (size_t)RR * 2304 * 4);
  unsigned short* hb    = (unsigned short*)carve(cur, (size_t)RR * DD * 2);
  unsigned short* attnb = (unsigned short*)carve(cur, (size_t)RR * DD * 2);
  unsigned short* ffb   = (unsigned short*)carve(cur, (size_t)RR * FFD * 2);
  unsigned short* wt    = (unsigned short*)carve(cur, LSTR * 6 * 2);
  unsigned short* audio_bf = (unsigned short*)carve(cur, (size_t)BBn * AAn * DD * 2);
  unsigned short* audioT   = (unsigned short*)carve(cur, (size_t)BBn * DD * TPAD * 2);
  unsigned short* emb_bf = (unsigned short*)carve(cur, (size_t)VPAD * DD * 2);
  float* Sb = (float*)carve(cur, (size_t)BBn * 128 * TPAD * 4);
  unsigned short* Pb  = (unsigned short*)carve(cur, (size_t)BBn * 128 * TPAD * 2);
  unsigned short* Qp  = (unsigned short*)carve(cur, (size_t)BBn * 128 * DD * 2);
  unsigned short* Rbf = (unsigned short*)carve(cur, (size_t)HH * 256 * DD * 2);
  float* qkvb  = (float*)carve(cur, (size_t)6 * 2304 * 4);
  float* mlp2p = (float*)carve(cur, (size_t)4 * RR * DD * 4);

  auto GEMM = [&](bool small, const unsigned short* A_, const unsigned short* Bt_,
                  void* C_, const float* bias_, const float* res_, int M_, int Np_,
                  int Klen_, int Kstr_, int Nout_, int Cld_, int op_,
                  int Z_ = 1, long zsA_ = 0, long zsB_ = 0, long zsC_ = 0,
                  long zsBias_ = 0, int kz_ = 0) {
    if (small) {
      dim3 g(Np_ / 64, M_ / 64, Z_);
      gemm_t<64, 64><<<g, 256, 0, stream>>>(A_, Bt_, C_, bias_, res_, Klen_, Kstr_,
                                            Nout_, Cld_, zsA_, zsB_, zsC_, zsBias_, kz_, op_);
    } else {
      dim3 g(Np_ / 128, M_ / 128, Z_);
      gemm_t<128, 128><<<g, 256, 0, stream>>>(A_, Bt_, C_, bias_, res_, Klen_, Kstr_,
                                              Nout_, Cld_, zsA_, zsB_, zsC_, zsBias_, kz_, op_);
    }
  };

  embed_k<<<RR, 256, 0, stream>>>(tokens, temb, pemb, x);
  cvt_bf16<<<2048, 256, 0, stream>>>(audio, audio_bf,
      (long long)BBn * AAn * DD, (long long)BBn * AAn * DD);
  cvt_bf16<<<2048, 256, 0, stream>>>(temb, emb_bf,
      (long long)VV * DD, (long long)VPAD * DD);
  build_biases<<<54, 256, 0, stream>>>(bq, bv, qkvb);
  transpose_audio<<<dim3(48, 24, BBn), 256, 0, stream>>>(audio, audioT);

  WPtrs wp;
  wp.p[0] = Wq; wp.p[1] = Wk; wp.p[2] = Wv; wp.p[3] = Wo;
  wp.p[4] = cWq; wp.p[5] = cWk; wp.p[6] = cWv; wp.p[7] = cWo;
  wp.p[8] = W1; wp.p[9] = W2;
  transpose_layer<<<dim3(96, 24, 60), 256, 0, stream>>>(wp, wt);

  // first LN (layer 0 self-attn)
  ln_to_bf16<<<RR, 256, 0, stream>>>(x, aln_w, aln_b, hb);

  for (int l = 0; l < 6; l++) {
    size_t vD = (size_t)l * DD;
    size_t vF = (size_t)l * FFD;
    unsigned short* wtl = wt + (size_t)l * LSTR;

    // --- self attention block (hb already holds LN(x)) ---
    GEMM(true, hb, wtl, qkv, qkvb + (size_t)l * 2304, nullptr, RR, 2304, DD, DD, 2304, 2304, OP_BIAS);
    self_attn_k<<<BBn * HH, 64, 0, stream>>>(qkv, attnb);
    GEMM(true, attnb, wtl + (size_t)3 * MAT, x, bo + vD, x, RR, DD, DD, DD, DD, DD, OP_BIAS | OP_RES);

    // --- cross attention block (KV-free formulation) ---
    ln_to_bf16<<<RR, 256, 0, stream>>>(x, cln_w + vD, cln_b + vD, hb);
    GEMM(true, hb, wtl + (size_t)4 * MAT, qkv, cbq + vD, nullptr, RR, DD, DD, DD, DD, DD, OP_BIAS);
    qprime_k<<<BBn * HH, 256, 0, stream>>>(qkv, cWk + (size_t)l * MAT, Qp);
    // scores: per b, S[b] = Qp[b] (128x768) @ audio_b^T  -> [128][1536] f32
    GEMM(true, Qp, audio_bf, Sb, nullptr, nullptr, 128, TPAD, DD, DD, TPAD, TPAD, 0,
         BBn, (long)128 * DD, (long)AAn * DD, (long)128 * TPAD, 0, 0);
    xsoftmax_k<<<BBn * HH, 256, 0, stream>>>(Sb, Pb);
    // PV: per b, R = P[b] (128x1536) @ audioT_b^T -> scatter to Rbf[h][b*8+s][e]
    GEMM(true, Pb, audioT, Rbf, nullptr, nullptr, 128, DD, TPAD, TPAD, DD, DD, OP_SCAT,
         BBn, (long)128 * TPAD, (long)DD * TPAD, 0, 0, 0);
    // O head-proj: per h, attnb[.,h*64..] = Rbf[h] @ cWv_h + cbv_h
    GEMM(true, Rbf, wtl + (size_t)6 * MAT, attnb, cbv + vD, nullptr, RR, 64, DD, DD, 64, DD,
         OP_BIAS | OP_BF16, HH, (long)256 * DD, (long)64 * DD, 64, 64, 0);
    GEMM(true, attnb, wtl + (size_t)7 * MAT, x, cbo + vD, x, RR, DD, DD, DD, DD, DD, OP_BIAS | OP_RES);

    // --- MLP block ---
    ln_to_bf16<<<RR, 256, 0, stream>>>(x, mln_w + vD, mln_b + vD, hb);
    GEMM(true, hb, wtl + (size_t)8 * MAT, ffb, b1 + vF, nullptr, RR, FFD, DD, DD, FFD, FFD,
         OP_BIAS | OP_GELU | OP_BF16);
    GEMM(true, ffb, wtl + (size_t)8 * MAT + (size_t)DD * FFD, mlp2p, nullptr, nullptr,
         RR, DD, DD, FFD, DD, DD, 0, 4, 0, 0, (long)RR * DD, 0, 1);
    // fused: x += mlp2 + b2, then LN for next consumer (next layer attn, or final LN)
    const float* nw = (l < 5) ? (aln_w + (size_t)(l + 1) * DD) : lnw;
    const float* nb = (l < 5) ? (aln_b + (size_t)(l + 1) * DD) : lnb;
    mlp2_reduce_ln<<<RR, 256, 0, stream>>>(mlp2p, b2 + vD, x, nw, nb, hb);
  }

  // --- logits (hb holds final LN) ---
  GEMM(false, hb, emb_bf, d_out, nullptr, nullptr, RR, VPAD, DD, DD, VV, VV, 0);
}

// Round 7
// 1464.349 us; speedup vs baseline: 3.4565x; 1.1050x over previous
//
#include <hip/hip_runtime.h>
#include <hip/hip_bf16.h>

// Whisper decoder step: L=6, D=768, H=12, FF=3072, V=51865, A=1500, B=32, S=8
#define HH 12
#define DD 768
#define FFD 3072
#define AAn 1500
#define BBn 32
#define RR 256          // B*S token rows
#define VV 51865
#define VPAD 51968      // 406*128
#define MAT (768*768)   // 589824
#define LSTR ((size_t)8 * MAT + 2 * (size_t)DD * FFD)   // wt elements per layer
#define TPAD 1536       // padded audio T

#define OP_BIAS 1
#define OP_GELU 2
#define OP_RES  4
#define OP_BF16 8
#define OP_SCAT 16

typedef float f32x4 __attribute__((ext_vector_type(4)));
typedef short s16x8 __attribute__((ext_vector_type(8)));

__device__ __forceinline__ unsigned short f2bf(float f) {
  union { float f; unsigned int u; } v; v.f = f;
  unsigned int r = (v.u + 0x7fffu + ((v.u >> 16) & 1u)) >> 16;
  return (unsigned short)r;
}

__device__ __forceinline__ void gld_lds16(const unsigned short* g, unsigned short* l) {
  __builtin_amdgcn_global_load_lds(
      (const __attribute__((address_space(1))) void*)g,
      (__attribute__((address_space(3))) void*)l, 16, 0, 0);
}

// ---------------- embedding ----------------
__global__ void embed_k(const int* __restrict__ toks, const float* __restrict__ emb,
                        const float* __restrict__ pos, float* __restrict__ x) {
  int r = blockIdx.x;
  int s = r & 7;
  int t = toks[r];
  for (int c = threadIdx.x; c < DD; c += 256)
    x[(size_t)r * DD + c] = emb[(size_t)t * DD + c] + pos[(size_t)s * DD + c];
}

// ---------------- build combined qkv bias ----------------
__global__ void build_biases(const float* __restrict__ bq, const float* __restrict__ bv,
                             float* __restrict__ qkvb) {
  int i = blockIdx.x * 256 + threadIdx.x;
  if (i < 6 * 2304) {
    int l = i / 2304, n = i % 2304;
    qkvb[i] = (n < 768) ? bq[l * 768 + n] : (n < 1536 ? 0.f : bv[l * 768 + (n - 1536)]);
  }
}

// ---------------- LayerNorm -> bf16 ----------------
__global__ __launch_bounds__(256) void ln_to_bf16(
    const float* __restrict__ x, const float* __restrict__ w,
    const float* __restrict__ b, unsigned short* __restrict__ out) {
  int row = blockIdx.x;
  const float* xr = x + (size_t)row * DD;
  int t = threadIdx.x;
  float v0 = xr[t], v1 = xr[t + 256], v2 = xr[t + 512];
  float s = v0 + v1 + v2;
  for (int o = 32; o; o >>= 1) s += __shfl_down(s, o);
  __shared__ float red[4], red2[4];
  int wid = t >> 6, lane = t & 63;
  if (!lane) red[wid] = s;
  __syncthreads();
  float mean = (red[0] + red[1] + red[2] + red[3]) * (1.f / DD);
  float d0 = v0 - mean, d1 = v1 - mean, d2 = v2 - mean;
  float s2 = d0 * d0 + d1 * d1 + d2 * d2;
  for (int o = 32; o; o >>= 1) s2 += __shfl_down(s2, o);
  if (!lane) red2[wid] = s2;
  __syncthreads();
  float var = (red2[0] + red2[1] + red2[2] + red2[3]) * (1.f / DD);
  float rstd = rsqrtf(var + 1e-5f);
  out[(size_t)row * DD + t]       = f2bf(d0 * rstd * w[t] + b[t]);
  out[(size_t)row * DD + t + 256] = f2bf(d1 * rstd * w[t + 256] + b[t + 256]);
  out[(size_t)row * DD + t + 512] = f2bf(d2 * rstd * w[t + 512] + b[t + 512]);
}

// ------- fused: x += bias + sum(nparts partials); out = LN(x) as bf16 --------
__global__ __launch_bounds__(256) void red_resid_ln(
    const float* __restrict__ part, int nparts, const float* __restrict__ bias,
    float* __restrict__ x, const float* __restrict__ w,
    const float* __restrict__ b, unsigned short* __restrict__ out) {
  int row = blockIdx.x;
  int t = threadIdx.x;
  float v[3];
  #pragma unroll
  for (int j = 0; j < 3; j++) {
    int c = t + j * 256;
    size_t i = (size_t)row * DD + c;
    float nv = x[i] + bias[c];
    for (int p = 0; p < nparts; p++) nv += part[(size_t)p * RR * DD + i];
    x[i] = nv;
    v[j] = nv;
  }
  float s = v[0] + v[1] + v[2];
  for (int o = 32; o; o >>= 1) s += __shfl_down(s, o);
  __shared__ float red[4], red2[4];
  int wid = t >> 6, lane = t & 63;
  if (!lane) red[wid] = s;
  __syncthreads();
  float mean = (red[0] + red[1] + red[2] + red[3]) * (1.f / DD);
  float d0 = v[0] - mean, d1 = v[1] - mean, d2 = v[2] - mean;
  float s2 = d0 * d0 + d1 * d1 + d2 * d2;
  for (int o = 32; o; o >>= 1) s2 += __shfl_down(s2, o);
  if (!lane) red2[wid] = s2;
  __syncthreads();
  float var = (red2[0] + red2[1] + red2[2] + red2[3]) * (1.f / DD);
  float rstd = rsqrtf(var + 1e-5f);
  out[(size_t)row * DD + t]       = f2bf(d0 * rstd * w[t] + b[t]);
  out[(size_t)row * DD + t + 256] = f2bf(d1 * rstd * w[t + 256] + b[t + 256]);
  out[(size_t)row * DD + t + 512] = f2bf(d2 * rstd * w[t + 512] + b[t + 512]);
}

// ---------------- batched transpose of ALL layer weights -> bf16 ----------------
struct WPtrs { const float* p[10]; };
__global__ __launch_bounds__(256) void transpose_layer(
    WPtrs wp, unsigned short* __restrict__ dst) {
  int zz = blockIdx.z % 10, l = blockIdx.z / 10;
  int R = (zz == 9) ? FFD : DD;
  int C = (zz == 8) ? FFD : DD;
  int ctile, rtile;
  if (zz == 9) { rtile = blockIdx.x; ctile = blockIdx.y; }
  else         { ctile = blockIdx.x; rtile = blockIdx.y; }
  if (ctile * 32 >= C || rtile * 32 >= R) return;
  const float* W = wp.p[zz] + (size_t)l * ((zz < 8) ? MAT : (size_t)DD * FFD);
  size_t doff = (zz < 8) ? (size_t)zz * MAT
                         : ((zz == 8) ? (size_t)8 * MAT : (size_t)8 * MAT + (size_t)FFD * DD);
  unsigned short* Wt = dst + (size_t)l * LSTR + doff;
  __shared__ unsigned short tile[32][33];
  int r0 = rtile * 32, c0 = ctile * 32;
  int tx = threadIdx.x & 31, ty = threadIdx.x >> 5;
  #pragma unroll
  for (int i = 0; i < 32; i += 8)
    tile[ty + i][tx] = f2bf(W[(size_t)(r0 + ty + i) * C + (c0 + tx)]);
  __syncthreads();
  #pragma unroll
  for (int i = 0; i < 32; i += 8)
    Wt[(size_t)(c0 + ty + i) * R + (r0 + tx)] = tile[tx][ty + i];
}

// ------- fused audio prep: f32 [b][1500][768] -> bf16 straight + transposed -------
__global__ __launch_bounds__(256) void audio_prep(
    const float* __restrict__ audio, unsigned short* __restrict__ a_bf,
    unsigned short* __restrict__ aT) {
  int b = blockIdx.z;
  int t0 = blockIdx.x * 32, e0 = blockIdx.y * 32;
  __shared__ unsigned short tile[32][33];
  int tx = threadIdx.x & 31, ty = threadIdx.x >> 5;
  const float* src = audio + (size_t)b * AAn * DD;
  unsigned short* dst_bf = a_bf + (size_t)b * AAn * DD;
  #pragma unroll
  for (int i = 0; i < 32; i += 8) {
    int t = t0 + ty + i;
    unsigned short v = 0;
    if (t < AAn) {
      v = f2bf(src[(size_t)t * DD + e0 + tx]);
      dst_bf[(size_t)t * DD + e0 + tx] = v;
    }
    tile[ty + i][tx] = v;
  }
  __syncthreads();
  unsigned short* dst = aT + (size_t)b * DD * TPAD;
  #pragma unroll
  for (int i = 0; i < 32; i += 8)
    dst[(size_t)(e0 + ty + i) * TPAD + t0 + tx] = tile[tx][ty + i];
}

// ---------------- GEMM: C[M][*] = A[M][Klen](bf16) * Bt[N][Klen](bf16)^T ------------
// Template tile BM x BN; BF32=1 stages B from f32 src (rows >= NrowsB read as 0).
// grid = (Npad/BN, M/BM, Z). Per-z offsets zsA/zsB/zsC/zsBias (elements). kz=1: split-K.
// OP_SCAT: write bf16 at [(r>>3)*256 + z*8 + (r&7)]*768 + c, rows r>>3<12 only.
template <int BM, int BN, int BF32>
__global__ __launch_bounds__(256, 2) void gemm_t(
    const unsigned short* __restrict__ A, const unsigned short* __restrict__ Bt,
    const float* __restrict__ Bf32, int NrowsB,
    void* __restrict__ Cv, const float* __restrict__ bias,
    const float* __restrict__ resid, int Klen, int Kstride, int Nout, int Cld,
    long zsA, long zsB, long zsC, long zsBias, int kz, int op) {
  constexpr int WM = BM / 2, WN = BN / 2;
  constexpr int MREP = WM / 16, NREP = WN / 16;
  __shared__ unsigned short As[BM * 32];
  __shared__ unsigned short Bs[BN * 32];
  const int n0 = blockIdx.x * BN, m0 = blockIdx.y * BM;
  const int z = blockIdx.z;
  const int kbeg = kz ? z * Klen : 0;
  const int tid = threadIdx.x, w = tid >> 6, l = tid & 63;
  const int wr = w >> 1, wc = w & 1;
  f32x4 acc[MREP][NREP] = {};

  const int rbase = w * 16 + (l >> 2);
  const int cA = (l & 3) * 8;
  const unsigned short* gA = A + (size_t)z * zsA + (size_t)(m0 + rbase) * Kstride + cA + kbeg;
  const unsigned short* gB = nullptr;
  if constexpr (!BF32)
    gB = Bt + (size_t)z * zsB + (size_t)(n0 + rbase) * Kstride + cA + kbeg;

  for (int k0 = 0; k0 < Klen; k0 += 32) {
    __syncthreads();
    #pragma unroll
    for (int p = 0; p < BM / 64; p++)
      gld_lds16(gA + (size_t)(p * 64) * Kstride + k0, &As[(p * 64 + w * 16) * 32]);
    if constexpr (!BF32) {
      #pragma unroll
      for (int p = 0; p < BN / 64; p++)
        gld_lds16(gB + (size_t)(p * 64) * Kstride + k0, &Bs[(p * 64 + w * 16) * 32]);
    } else {
      #pragma unroll
      for (int p = 0; p < BN / 64; p++) {
        int grow = n0 + p * 64 + w * 16 + (l >> 2);
        float4 f0 = make_float4(0.f, 0.f, 0.f, 0.f), f1 = f0;
        if (grow < NrowsB) {
          const float* srcp = Bf32 + (size_t)grow * Kstride + cA + k0 + kbeg;
          f0 = *(const float4*)srcp;
          f1 = *(const float4*)(srcp + 4);
        }
        union { unsigned short us[8]; s16x8 v; } pk;
        pk.us[0] = f2bf(f0.x); pk.us[1] = f2bf(f0.y);
        pk.us[2] = f2bf(f0.z); pk.us[3] = f2bf(f0.w);
        pk.us[4] = f2bf(f1.x); pk.us[5] = f2bf(f1.y);
        pk.us[6] = f2bf(f1.z); pk.us[7] = f2bf(f1.w);
        *(s16x8*)&Bs[(size_t)(p * 64 + w * 16 + (l >> 2)) * 32 + cA] = pk.v;
      }
    }
    __syncthreads();
    s16x8 aF[MREP], bF[NREP];
    #pragma unroll
    for (int m = 0; m < MREP; m++)
      aF[m] = *(const s16x8*)&As[(wr * WM + m * 16 + (l & 15)) * 32 + (l >> 4) * 8];
    #pragma unroll
    for (int n = 0; n < NREP; n++)
      bF[n] = *(const s16x8*)&Bs[(wc * WN + n * 16 + (l & 15)) * 32 + (l >> 4) * 8];
    #pragma unroll
    for (int m = 0; m < MREP; m++)
      #pragma unroll
      for (int n = 0; n < NREP; n++)
        acc[m][n] = __builtin_amdgcn_mfma_f32_16x16x32_bf16(aF[m], bF[n], acc[m][n], 0, 0, 0);
  }

  const float* biasz = (op & OP_BIAS) ? bias + (size_t)z * zsBias : nullptr;
  #pragma unroll
  for (int m = 0; m < MREP; m++) {
    int rr0 = m0 + wr * WM + m * 16 + (l >> 4) * 4;
    #pragma unroll
    for (int n = 0; n < NREP; n++) {
      int c = n0 + wc * WN + n * 16 + (l & 15);
      if (c < Nout) {
        float bval = (op & OP_BIAS) ? biasz[c] : 0.f;
        #pragma unroll
        for (int j = 0; j < 4; j++) {
          int r = rr0 + j;
          float val = acc[m][n][j] + bval;
          if (op & OP_GELU) val = 0.5f * val * (1.f + erff(val * 0.70710678118f));
          if (op & OP_RES)  val += resid[(size_t)r * Cld + c];
          if (op & OP_SCAT) {
            int hh = r >> 3;
            if (hh < HH)
              ((unsigned short*)Cv)[((size_t)hh * 256 + z * 8 + (r & 7)) * 768 + c] = f2bf(val);
          } else if (op & OP_BF16) {
            ((unsigned short*)Cv)[(size_t)z * zsC + (size_t)r * Cld + c] = f2bf(val);
          } else {
            ((float*)Cv)[(size_t)z * zsC + (size_t)r * Cld + c] = val;
          }
        }
      }
    }
  }
}

// ---------------- self attention (S=8, causal), q/k/v packed [256][2304] ----------
__global__ __launch_bounds__(64) void self_attn_k(
    const float* __restrict__ qkv, unsigned short* __restrict__ out) {
  int bh = blockIdx.x;
  int b = bh / HH, h = bh % HH;
  __shared__ float qs[8][65], ks[8][65], vs[8][65], ps[8][9];
  int l = threadIdx.x;
  for (int s = 0; s < 8; s++) {
    size_t base = ((size_t)(b * 8 + s)) * 2304 + h * 64 + l;
    qs[s][l] = qkv[base]; ks[s][l] = qkv[base + 768]; vs[s][l] = qkv[base + 1536];
  }
  __syncthreads();
  int s = l >> 3, t = l & 7;
  float sc = 0.f;
  #pragma unroll
  for (int d = 0; d < 64; d++) sc += qs[s][d] * ks[t][d];
  sc *= 0.125f;
  if (t > s) sc = -1e30f;
  float mx = sc;
  for (int o = 4; o; o >>= 1) mx = fmaxf(mx, __shfl_xor(mx, o, 8));
  float e = __expf(sc - mx);
  float sum = e;
  for (int o = 4; o; o >>= 1) sum += __shfl_xor(sum, o, 8);
  ps[s][t] = e / sum;
  __syncthreads();
  for (int s2 = 0; s2 < 8; s2++) {
    float acc = 0.f;
    #pragma unroll
    for (int t2 = 0; t2 < 8; t2++) acc += ps[s2][t2] * vs[t2][l];
    out[((size_t)(b * 8 + s2)) * DD + h * 64 + l] = f2bf(acc);
  }
}

// ---- Q' build from cq split-K partials: Q' = 0.125 * (p0+p1+cbq) . cWk[h-block] ----
__global__ __launch_bounds__(256) void qprime_k(
    const float* __restrict__ p2, const float* __restrict__ cbq,
    const float* __restrict__ cWk, unsigned short* __restrict__ Qp) {
  int bh = blockIdx.x;              // b*12 + h
  int b = bh / HH, h = bh % HH;
  __shared__ float qs[8][64];
  int tid = threadIdx.x;
  for (int i = tid; i < 512; i += 256) {
    int s = i >> 6, d = i & 63;
    size_t idx = (size_t)(b * 8 + s) * 768 + h * 64 + d;
    qs[s][d] = (p2[idx] + p2[(size_t)RR * DD + idx] + cbq[h * 64 + d]) * 0.125f;
  }
  __syncthreads();
  for (int e = tid; e < 768; e += 256) {
    const float* wr = cWk + (size_t)e * 768 + h * 64;
    float acc[8] = {};
    #pragma unroll 16
    for (int k = 0; k < 64; k++) {
      float wv = wr[k];
      #pragma unroll
      for (int s = 0; s < 8; s++) acc[s] += qs[s][k] * wv;
    }
    #pragma unroll
    for (int s = 0; s < 8; s++)
      Qp[((size_t)b * 128 + h * 8 + s) * 768 + e] = f2bf(acc[s]);
  }
}

// ---------------- cross softmax: S f32 [32][128][1536] -> P bf16 (normalized) ------
__global__ __launch_bounds__(256) void xsoftmax_k(
    const float* __restrict__ S, unsigned short* __restrict__ P) {
  int bh = blockIdx.x;              // b*12 + h
  int b = bh / HH, h = bh % HH;
  int w = threadIdx.x >> 6, ln = threadIdx.x & 63;
  for (int rr = w; rr < 8; rr += 4) {
    size_t row = (size_t)b * 128 + h * 8 + rr;
    const float* sr = S + row * TPAD;
    unsigned short* pr = P + row * TPAD;
    float v[24];
    float mx = -1e30f;
    #pragma unroll
    for (int i = 0; i < 24; i++) {
      int t = ln + i * 64;
      v[i] = (t < AAn) ? sr[t] : -1e30f;
      mx = fmaxf(mx, v[i]);
    }
    for (int o = 32; o; o >>= 1) mx = fmaxf(mx, __shfl_xor(mx, o));
    float sum = 0.f;
    #pragma unroll
    for (int i = 0; i < 24; i++) { v[i] = __expf(v[i] - mx); sum += v[i]; }
    for (int o = 32; o; o >>= 1) sum += __shfl_xor(sum, o);
    float inv = 1.f / sum;
    #pragma unroll
    for (int i = 0; i < 24; i++) {
      int t = ln + i * 64;
      pr[t] = f2bf((t < AAn) ? v[i] * inv : 0.f);
    }
  }
}

// ---------------- host ----------------
static inline void* carve(char*& p, size_t bytes) {
  void* r = p;
  p += (bytes + 255) & ~(size_t)255;
  return r;
}

extern "C" void kernel_launch(void* const* d_in, const int* in_sizes, int n_in,
                              void* d_out, int out_size, void* d_ws, size_t ws_size,
                              hipStream_t stream) {
  const int*   tokens = (const int*)d_in[0];
  const float* audio  = (const float*)d_in[1];
  const float* temb   = (const float*)d_in[2];
  const float* pemb   = (const float*)d_in[3];
  const float* aln_w  = (const float*)d_in[4];
  const float* aln_b  = (const float*)d_in[5];
  const float* Wq = (const float*)d_in[6];
  const float* bq = (const float*)d_in[7];
  const float* Wk = (const float*)d_in[8];
  const float* Wv = (const float*)d_in[9];
  const float* bv = (const float*)d_in[10];
  const float* Wo = (const float*)d_in[11];
  const float* bo = (const float*)d_in[12];
  const float* cln_w = (const float*)d_in[13];
  const float* cln_b = (const float*)d_in[14];
  const float* cWq = (const float*)d_in[15];
  const float* cbq = (const float*)d_in[16];
  const float* cWk = (const float*)d_in[17];
  const float* cWv = (const float*)d_in[18];
  const float* cbv = (const float*)d_in[19];
  const float* cWo = (const float*)d_in[20];
  const float* cbo = (const float*)d_in[21];
  const float* mln_w = (const float*)d_in[22];
  const float* mln_b = (const float*)d_in[23];
  const float* W1 = (const float*)d_in[24];
  const float* b1 = (const float*)d_in[25];
  const float* W2 = (const float*)d_in[26];
  const float* b2 = (const float*)d_in[27];
  const float* lnw = (const float*)d_in[28];
  const float* lnb = (const float*)d_in[29];

  char* cur = (char*)d_ws;
  float* x    = (float*)carve(cur, (size_t)RR * DD * 4);
  float* qkv  = (float*)carve(cur, (size_t)RR * 2304 * 4);
  unsigned short* hb    = (unsigned short*)carve(cur, (size_t)RR * DD * 2);
  unsigned short* attnb = (unsigned short*)carve(cur, (size_t)RR * DD * 2);
  unsigned short* ffb   = (unsigned short*)carve(cur, (size_t)RR * FFD * 2);
  unsigned short* wt    = (unsigned short*)carve(cur, LSTR * 6 * 2);
  unsigned short* audio_bf = (unsigned short*)carve(cur, (size_t)BBn * AAn * DD * 2);
  unsigned short* audioT   = (unsigned short*)carve(cur, (size_t)BBn * DD * TPAD * 2);
  float* Sb = (float*)carve(cur, (size_t)BBn * 128 * TPAD * 4);
  unsigned short* Pb  = (unsigned short*)carve(cur, (size_t)BBn * 128 * TPAD * 2);
  unsigned short* Qp  = (unsigned short*)carve(cur, (size_t)BBn * 128 * DD * 2);
  unsigned short* Rbf = (unsigned short*)carve(cur, (size_t)HH * 256 * DD * 2);
  float* qkvb  = (float*)carve(cur, (size_t)6 * 2304 * 4);
  float* mlp2p = (float*)carve(cur, (size_t)4 * RR * DD * 4);

  // bf16-B GEMM dispatch helpers
  auto G64 = [&](const unsigned short* A_, const unsigned short* Bt_, void* C_,
                 const float* bias_, const float* res_, int M_, int Np_,
                 int Klen_, int Kstr_, int Nout_, int Cld_, int op_,
                 int Z_ = 1, long zsA_ = 0, long zsB_ = 0, long zsC_ = 0,
                 long zsBias_ = 0, int kz_ = 0) {
    dim3 g(Np_ / 64, M_ / 64, Z_);
    gemm_t<64, 64, 0><<<g, 256, 0, stream>>>(A_, Bt_, nullptr, 0, C_, bias_, res_,
        Klen_, Kstr_, Nout_, Cld_, zsA_, zsB_, zsC_, zsBias_, kz_, op_);
  };
  auto G128 = [&](const unsigned short* A_, const unsigned short* Bt_, void* C_,
                  const float* bias_, const float* res_, int M_, int Np_,
                  int Klen_, int Kstr_, int Nout_, int Cld_, int op_,
                  int Z_ = 1, long zsA_ = 0, long zsB_ = 0, long zsC_ = 0,
                  long zsBias_ = 0, int kz_ = 0) {
    dim3 g(Np_ / 128, M_ / 128, Z_);
    gemm_t<128, 128, 0><<<g, 256, 0, stream>>>(A_, Bt_, nullptr, 0, C_, bias_, res_,
        Klen_, Kstr_, Nout_, Cld_, zsA_, zsB_, zsC_, zsBias_, kz_, op_);
  };

  embed_k<<<RR, 256, 0, stream>>>(tokens, temb, pemb, x);
  audio_prep<<<dim3(48, 24, BBn), 256, 0, stream>>>(audio, audio_bf, audioT);
  build_biases<<<54, 256, 0, stream>>>(bq, bv, qkvb);

  WPtrs wp;
  wp.p[0] = Wq; wp.p[1] = Wk; wp.p[2] = Wv; wp.p[3] = Wo;
  wp.p[4] = cWq; wp.p[5] = cWk; wp.p[6] = cWv; wp.p[7] = cWo;
  wp.p[8] = W1; wp.p[9] = W2;
  transpose_layer<<<dim3(96, 24, 60), 256, 0, stream>>>(wp, wt);

  // first LN (layer 0 self-attn)
  ln_to_bf16<<<RR, 256, 0, stream>>>(x, aln_w, aln_b, hb);

  for (int l = 0; l < 6; l++) {
    size_t vD = (size_t)l * DD;
    size_t vF = (size_t)l * FFD;
    unsigned short* wtl = wt + (size_t)l * LSTR;

    // --- self attention block (hb already holds LN(x)) ---
    G64(hb, wtl, qkv, qkvb + (size_t)l * 2304, nullptr, RR, 2304, DD, DD, 2304, 2304, OP_BIAS);
    self_attn_k<<<BBn * HH, 64, 0, stream>>>(qkv, attnb);
    // o-proj split-K x2 -> partials; fused residual+LN(cross)
    G64(attnb, wtl + (size_t)3 * MAT, mlp2p, nullptr, nullptr, RR, DD, 384, DD, DD, DD,
        0, 2, 0, 0, (long)RR * DD, 0, 1);
    red_resid_ln<<<RR, 256, 0, stream>>>(mlp2p, 2, bo + vD, x, cln_w + vD, cln_b + vD, hb);

    // --- cross attention block (KV-free formulation) ---
    // cq split-K x2 -> partials consumed by qprime
    G64(hb, wtl + (size_t)4 * MAT, mlp2p, nullptr, nullptr, RR, DD, 384, DD, DD, DD,
        0, 2, 0, 0, (long)RR * DD, 0, 1);
    qprime_k<<<BBn * HH, 256, 0, stream>>>(mlp2p, cbq + vD, cWk + (size_t)l * MAT, Qp);
    // scores: per b, S[b] = Qp[b] (128x768) @ audio_b^T  -> [128][1536] f32
    G128(Qp, audio_bf, Sb, nullptr, nullptr, 128, TPAD, DD, DD, TPAD, TPAD, 0,
         BBn, (long)128 * DD, (long)AAn * DD, (long)128 * TPAD, 0, 0);
    xsoftmax_k<<<BBn * HH, 256, 0, stream>>>(Sb, Pb);
    // PV: per b, R = P[b] (128x1536) @ audioT_b^T -> scatter to Rbf[h][b*8+s][e]
    {
      dim3 g(DD / 64, 1, BBn);
      gemm_t<128, 64, 0><<<g, 256, 0, stream>>>(Pb, audioT, nullptr, 0, Rbf, nullptr,
          nullptr, TPAD, TPAD, DD, DD, (long)128 * TPAD, (long)DD * TPAD, 0, 0, 0, OP_SCAT);
    }
    // O head-proj: per h, attnb[.,h*64..] = Rbf[h] @ cWv_h + cbv_h
    G64(Rbf, wtl + (size_t)6 * MAT, attnb, cbv + vD, nullptr, RR, 64, DD, DD, 64, DD,
        OP_BIAS | OP_BF16, HH, (long)256 * DD, (long)64 * DD, 64, 64, 0);
    // co-proj split-K x2 -> partials; fused residual+LN(mlp)
    G64(attnb, wtl + (size_t)7 * MAT, mlp2p, nullptr, nullptr, RR, DD, 384, DD, DD, DD,
        0, 2, 0, 0, (long)RR * DD, 0, 1);
    red_resid_ln<<<RR, 256, 0, stream>>>(mlp2p, 2, cbo + vD, x, mln_w + vD, mln_b + vD, hb);

    // --- MLP block ---
    G64(hb, wtl + (size_t)8 * MAT, ffb, b1 + vF, nullptr, RR, FFD, DD, DD, FFD, FFD,
        OP_BIAS | OP_GELU | OP_BF16);
    G64(ffb, wtl + (size_t)8 * MAT + (size_t)DD * FFD, mlp2p, nullptr, nullptr,
        RR, DD, DD, FFD, DD, DD, 0, 4, 0, 0, (long)RR * DD, 0, 1);
    // fused: x += mlp2 + b2, then LN for next consumer
    const float* nw = (l < 5) ? (aln_w + (size_t)(l + 1) * DD) : lnw;
    const float* nb = (l < 5) ? (aln_b + (size_t)(l + 1) * DD) : lnb;
    red_resid_ln<<<RR, 256, 0, stream>>>(mlp2p, 4, b2 + vD, x, nw, nb, hb);
  }

  // --- logits (hb holds final LN); B staged from f32 temb directly ---
  {
    dim3 g(VPAD / 128, RR / 128, 1);
    gemm_t<128, 128, 1><<<g, 256, 0, stream>>>(hb, nullptr, temb, VV, d_out, nullptr,
        nullptr, DD, DD, VV, VV, 0, 0, 0, 0, 0, 0);
  }
}

// Round 8
// 1461.302 us; speedup vs baseline: 3.4637x; 1.0021x over previous
//
#include <hip/hip_runtime.h>
#include <hip/hip_bf16.h>

// Whisper decoder step: L=6, D=768, H=12, FF=3072, V=51865, A=1500, B=32, S=8
#define HH 12
#define DD 768
#define FFD 3072
#define AAn 1500
#define BBn 32
#define RR 256          // B*S token rows
#define VV 51865
#define VPAD 51968      // 406*128
#define MAT (768*768)   // 589824
#define LSTR ((size_t)8 * MAT + 2 * (size_t)DD * FFD)   // wt elements per layer
#define TPAD 1536       // padded audio T

#define OP_BIAS 1
#define OP_GELU 2
#define OP_RES  4
#define OP_BF16 8
#define OP_SCAT 16

typedef float f32x4 __attribute__((ext_vector_type(4)));
typedef short s16x8 __attribute__((ext_vector_type(8)));

__device__ __forceinline__ unsigned short f2bf(float f) {
  union { float f; unsigned int u; } v; v.f = f;
  unsigned int r = (v.u + 0x7fffu + ((v.u >> 16) & 1u)) >> 16;
  return (unsigned short)r;
}

__device__ __forceinline__ void gld_lds16(const unsigned short* g, unsigned short* l) {
  __builtin_amdgcn_global_load_lds(
      (const __attribute__((address_space(1))) void*)g,
      (__attribute__((address_space(3))) void*)l, 16, 0, 0);
}

// ---------------- embedding ----------------
__global__ void embed_k(const int* __restrict__ toks, const float* __restrict__ emb,
                        const float* __restrict__ pos, float* __restrict__ x) {
  int r = blockIdx.x;
  int s = r & 7;
  int t = toks[r];
  for (int c = threadIdx.x; c < DD; c += 256)
    x[(size_t)r * DD + c] = emb[(size_t)t * DD + c] + pos[(size_t)s * DD + c];
}

// ---------------- build combined qkv bias ----------------
__global__ void build_biases(const float* __restrict__ bq, const float* __restrict__ bv,
                             float* __restrict__ qkvb) {
  int i = blockIdx.x * 256 + threadIdx.x;
  if (i < 6 * 2304) {
    int l = i / 2304, n = i % 2304;
    qkvb[i] = (n < 768) ? bq[l * 768 + n] : (n < 1536 ? 0.f : bv[l * 768 + (n - 1536)]);
  }
}

// ---------------- LayerNorm -> bf16 ----------------
__global__ __launch_bounds__(256) void ln_to_bf16(
    const float* __restrict__ x, const float* __restrict__ w,
    const float* __restrict__ b, unsigned short* __restrict__ out) {
  int row = blockIdx.x;
  const float* xr = x + (size_t)row * DD;
  int t = threadIdx.x;
  float v0 = xr[t], v1 = xr[t + 256], v2 = xr[t + 512];
  float s = v0 + v1 + v2;
  for (int o = 32; o; o >>= 1) s += __shfl_down(s, o);
  __shared__ float red[4], red2[4];
  int wid = t >> 6, lane = t & 63;
  if (!lane) red[wid] = s;
  __syncthreads();
  float mean = (red[0] + red[1] + red[2] + red[3]) * (1.f / DD);
  float d0 = v0 - mean, d1 = v1 - mean, d2 = v2 - mean;
  float s2 = d0 * d0 + d1 * d1 + d2 * d2;
  for (int o = 32; o; o >>= 1) s2 += __shfl_down(s2, o);
  if (!lane) red2[wid] = s2;
  __syncthreads();
  float var = (red2[0] + red2[1] + red2[2] + red2[3]) * (1.f / DD);
  float rstd = rsqrtf(var + 1e-5f);
  out[(size_t)row * DD + t]       = f2bf(d0 * rstd * w[t] + b[t]);
  out[(size_t)row * DD + t + 256] = f2bf(d1 * rstd * w[t + 256] + b[t + 256]);
  out[(size_t)row * DD + t + 512] = f2bf(d2 * rstd * w[t + 512] + b[t + 512]);
}

// ------- fused: x += bias + sum(nparts partials); out = LN(x) as bf16 --------
__global__ __launch_bounds__(256) void red_resid_ln(
    const float* __restrict__ part, int nparts, const float* __restrict__ bias,
    float* __restrict__ x, const float* __restrict__ w,
    const float* __restrict__ b, unsigned short* __restrict__ out) {
  int row = blockIdx.x;
  int t = threadIdx.x;
  float v[3];
  #pragma unroll
  for (int j = 0; j < 3; j++) {
    int c = t + j * 256;
    size_t i = (size_t)row * DD + c;
    float nv = x[i] + bias[c];
    for (int p = 0; p < nparts; p++) nv += part[(size_t)p * RR * DD + i];
    x[i] = nv;
    v[j] = nv;
  }
  float s = v[0] + v[1] + v[2];
  for (int o = 32; o; o >>= 1) s += __shfl_down(s, o);
  __shared__ float red[4], red2[4];
  int wid = t >> 6, lane = t & 63;
  if (!lane) red[wid] = s;
  __syncthreads();
  float mean = (red[0] + red[1] + red[2] + red[3]) * (1.f / DD);
  float d0 = v[0] - mean, d1 = v[1] - mean, d2 = v[2] - mean;
  float s2 = d0 * d0 + d1 * d1 + d2 * d2;
  for (int o = 32; o; o >>= 1) s2 += __shfl_down(s2, o);
  if (!lane) red2[wid] = s2;
  __syncthreads();
  float var = (red2[0] + red2[1] + red2[2] + red2[3]) * (1.f / DD);
  float rstd = rsqrtf(var + 1e-5f);
  out[(size_t)row * DD + t]       = f2bf(d0 * rstd * w[t] + b[t]);
  out[(size_t)row * DD + t + 256] = f2bf(d1 * rstd * w[t + 256] + b[t + 256]);
  out[(size_t)row * DD + t + 512] = f2bf(d2 * rstd * w[t + 512] + b[t + 512]);
}

// ---------- vectorized transpose of ALL layer weights -> bf16 (64x64 tiles) -------
// flat grid.x = 2304 tiles/layer, grid.y = layer
struct WPtrs { const float* p[10]; };
__global__ __launch_bounds__(256) void transpose_w(
    WPtrs wp, unsigned short* __restrict__ dst) {
  int l = blockIdx.y;
  int idx = blockIdx.x;
  int zz, ct, rt, R, C;
  if (idx < 1152)      { zz = idx / 144; int t = idx % 144; ct = t % 12; rt = t / 12; R = DD; C = DD; }
  else if (idx < 1728) { zz = 8; int t = idx - 1152; ct = t % 48; rt = t / 48; R = DD; C = FFD; }
  else                 { zz = 9; int t = idx - 1728; rt = t % 48; ct = t / 48; R = FFD; C = DD; }
  const float* W = wp.p[zz] + (size_t)l * ((zz < 8) ? MAT : (size_t)DD * FFD);
  size_t doff = (zz < 8) ? (size_t)zz * MAT
                         : ((zz == 8) ? (size_t)8 * MAT : (size_t)8 * MAT + (size_t)FFD * DD);
  unsigned short* Wt = dst + (size_t)l * LSTR + doff;
  __shared__ unsigned short tile[64][65];
  int r0 = rt * 64, c0 = ct * 64;
  int tid = threadIdx.x;
  int rr = tid >> 3, cc = (tid & 7) * 8;
  #pragma unroll
  for (int j = 0; j < 2; j++) {
    int r = r0 + j * 32 + rr;
    const float* sp = W + (size_t)r * C + c0 + cc;
    float4 f0 = *(const float4*)sp, f1 = *(const float4*)(sp + 4);
    unsigned short* tp = &tile[j * 32 + rr][cc];
    tp[0] = f2bf(f0.x); tp[1] = f2bf(f0.y); tp[2] = f2bf(f0.z); tp[3] = f2bf(f0.w);
    tp[4] = f2bf(f1.x); tp[5] = f2bf(f1.y); tp[6] = f2bf(f1.z); tp[7] = f2bf(f1.w);
  }
  __syncthreads();
  #pragma unroll
  for (int j = 0; j < 2; j++) {
    int c = c0 + j * 32 + rr;       // output row
    union { unsigned short us[8]; s16x8 v; } pk;
    #pragma unroll
    for (int i = 0; i < 8; i++) pk.us[i] = tile[cc + i][j * 32 + rr];
    *(s16x8*)&Wt[(size_t)c * R + r0 + cc] = pk.v;
  }
}

// ------- vectorized audio prep: f32 [b][1500][768] -> bf16 straight + transposed ---
__global__ __launch_bounds__(256) void audio_prep(
    const float* __restrict__ audio, unsigned short* __restrict__ a_bf,
    unsigned short* __restrict__ aT) {
  int b = blockIdx.z;
  int t0 = blockIdx.x * 64, e0 = blockIdx.y * 64;
  __shared__ unsigned short tile[64][65];
  int tid = threadIdx.x;
  const float* src = audio + (size_t)b * AAn * DD;
  unsigned short* dstb = a_bf + (size_t)b * AAn * DD;
  int rr = tid >> 3, cc = (tid & 7) * 8;
  #pragma unroll
  for (int j = 0; j < 2; j++) {
    int t = t0 + j * 32 + rr;
    union { unsigned short us[8]; s16x8 v; } pk;
    if (t < AAn) {
      const float* sp = src + (size_t)t * DD + e0 + cc;
      float4 f0 = *(const float4*)sp, f1 = *(const float4*)(sp + 4);
      pk.us[0] = f2bf(f0.x); pk.us[1] = f2bf(f0.y); pk.us[2] = f2bf(f0.z); pk.us[3] = f2bf(f0.w);
      pk.us[4] = f2bf(f1.x); pk.us[5] = f2bf(f1.y); pk.us[6] = f2bf(f1.z); pk.us[7] = f2bf(f1.w);
      *(s16x8*)&dstb[(size_t)t * DD + e0 + cc] = pk.v;
    } else {
      #pragma unroll
      for (int i = 0; i < 8; i++) pk.us[i] = 0;
    }
    unsigned short* tp = &tile[j * 32 + rr][cc];
    #pragma unroll
    for (int i = 0; i < 8; i++) tp[i] = pk.us[i];
  }
  __syncthreads();
  unsigned short* dstT = aT + (size_t)b * DD * TPAD;
  #pragma unroll
  for (int j = 0; j < 2; j++) {
    int e = e0 + j * 32 + rr;       // output row
    union { unsigned short us[8]; s16x8 v; } pk;
    #pragma unroll
    for (int i = 0; i < 8; i++) pk.us[i] = tile[cc + i][j * 32 + rr];
    *(s16x8*)&dstT[(size_t)e * TPAD + t0 + cc] = pk.v;
  }
}

// ---------------- GEMM: C[M][*] = A[M][Klen](bf16) * Bt[N][Klen](bf16)^T ------------
// BK=64. Template tile BM x BN; BF32=1 stages B from f32 src (rows >= NrowsB = 0).
// grid = (Npad/BN, M/BM, Z). Per-z offsets zsA/zsB/zsC/zsBias (elements). kz=1: split-K.
// OP_SCAT: write bf16 at [(r>>3)*256 + z*8 + (r&7)]*768 + c, rows r>>3<12 only.
template <int BM, int BN, int BF32>
__global__ __launch_bounds__(256, 2) void gemm_t(
    const unsigned short* __restrict__ A, const unsigned short* __restrict__ Bt,
    const float* __restrict__ Bf32, int NrowsB,
    void* __restrict__ Cv, const float* __restrict__ bias,
    const float* __restrict__ resid, int Klen, int Kstride, int Nout, int Cld,
    long zsA, long zsB, long zsC, long zsBias, int kz, int op) {
  constexpr int WM = BM / 2, WN = BN / 2;
  constexpr int MREP = WM / 16, NREP = WN / 16;
  __shared__ unsigned short As[BM * 64];
  __shared__ unsigned short Bs[BN * 64];
  const int n0 = blockIdx.x * BN, m0 = blockIdx.y * BM;
  const int z = blockIdx.z;
  const int kbeg = kz ? z * Klen : 0;
  const int tid = threadIdx.x, w = tid >> 6, l = tid & 63;
  const int wr = w >> 1, wc = w & 1;
  f32x4 acc[MREP][NREP] = {};

  const int rowA = l >> 3;        // 0..7 within an 8-row staging group
  const int colK = (l & 7) * 8;   // 0..56
  const unsigned short* gA =
      A + (size_t)z * zsA + (size_t)(m0 + w * (BM / 4) + rowA) * Kstride + colK + kbeg;
  const unsigned short* gB = nullptr;
  if constexpr (!BF32)
    gB = Bt + (size_t)z * zsB + (size_t)(n0 + w * (BN / 4) + rowA) * Kstride + colK + kbeg;

  for (int k0 = 0; k0 < Klen; k0 += 64) {
    __syncthreads();
    #pragma unroll
    for (int p = 0; p < BM / 32; p++)
      gld_lds16(gA + (size_t)(p * 8) * Kstride + k0, &As[(w * (BM / 4) + p * 8) * 64]);
    if constexpr (!BF32) {
      #pragma unroll
      for (int p = 0; p < BN / 32; p++)
        gld_lds16(gB + (size_t)(p * 8) * Kstride + k0, &Bs[(w * (BN / 4) + p * 8) * 64]);
    } else {
      #pragma unroll
      for (int p = 0; p < BN / 32; p++) {
        int grow = n0 + w * (BN / 4) + p * 8 + rowA;
        float4 f0 = make_float4(0.f, 0.f, 0.f, 0.f), f1 = f0;
        if (grow < NrowsB) {
          const float* srcp = Bf32 + (size_t)grow * Kstride + colK + k0 + kbeg;
          f0 = *(const float4*)srcp;
          f1 = *(const float4*)(srcp + 4);
        }
        union { unsigned short us[8]; s16x8 v; } pk;
        pk.us[0] = f2bf(f0.x); pk.us[1] = f2bf(f0.y);
        pk.us[2] = f2bf(f0.z); pk.us[3] = f2bf(f0.w);
        pk.us[4] = f2bf(f1.x); pk.us[5] = f2bf(f1.y);
        pk.us[6] = f2bf(f1.z); pk.us[7] = f2bf(f1.w);
        *(s16x8*)&Bs[(size_t)(w * (BN / 4) + p * 8 + rowA) * 64 + colK] = pk.v;
      }
    }
    __syncthreads();
    s16x8 aF[MREP][2], bF[NREP][2];
    #pragma unroll
    for (int m = 0; m < MREP; m++)
      #pragma unroll
      for (int kk = 0; kk < 2; kk++)
        aF[m][kk] = *(const s16x8*)&As[(wr * WM + m * 16 + (l & 15)) * 64 + kk * 32 + (l >> 4) * 8];
    #pragma unroll
    for (int n = 0; n < NREP; n++)
      #pragma unroll
      for (int kk = 0; kk < 2; kk++)
        bF[n][kk] = *(const s16x8*)&Bs[(wc * WN + n * 16 + (l & 15)) * 64 + kk * 32 + (l >> 4) * 8];
    #pragma unroll
    for (int m = 0; m < MREP; m++)
      #pragma unroll
      for (int n = 0; n < NREP; n++)
        #pragma unroll
        for (int kk = 0; kk < 2; kk++)
          acc[m][n] = __builtin_amdgcn_mfma_f32_16x16x32_bf16(aF[m][kk], bF[n][kk], acc[m][n], 0, 0, 0);
  }

  const float* biasz = (op & OP_BIAS) ? bias + (size_t)z * zsBias : nullptr;
  #pragma unroll
  for (int m = 0; m < MREP; m++) {
    int rr0 = m0 + wr * WM + m * 16 + (l >> 4) * 4;
    #pragma unroll
    for (int n = 0; n < NREP; n++) {
      int c = n0 + wc * WN + n * 16 + (l & 15);
      if (c < Nout) {
        float bval = (op & OP_BIAS) ? biasz[c] : 0.f;
        #pragma unroll
        for (int j = 0; j < 4; j++) {
          int r = rr0 + j;
          float val = acc[m][n][j] + bval;
          if (op & OP_GELU) val = 0.5f * val * (1.f + erff(val * 0.70710678118f));
          if (op & OP_RES)  val += resid[(size_t)r * Cld + c];
          if (op & OP_SCAT) {
            int hh = r >> 3;
            if (hh < HH)
              ((unsigned short*)Cv)[((size_t)hh * 256 + z * 8 + (r & 7)) * 768 + c] = f2bf(val);
          } else if (op & OP_BF16) {
            ((unsigned short*)Cv)[(size_t)z * zsC + (size_t)r * Cld + c] = f2bf(val);
          } else {
            ((float*)Cv)[(size_t)z * zsC + (size_t)r * Cld + c] = val;
          }
        }
      }
    }
  }
}

// ---------------- self attention (S=8, causal), q/k/v packed [256][2304] ----------
__global__ __launch_bounds__(64) void self_attn_k(
    const float* __restrict__ qkv, unsigned short* __restrict__ out) {
  int bh = blockIdx.x;
  int b = bh / HH, h = bh % HH;
  __shared__ float qs[8][65], ks[8][65], vs[8][65], ps[8][9];
  int l = threadIdx.x;
  for (int s = 0; s < 8; s++) {
    size_t base = ((size_t)(b * 8 + s)) * 2304 + h * 64 + l;
    qs[s][l] = qkv[base]; ks[s][l] = qkv[base + 768]; vs[s][l] = qkv[base + 1536];
  }
  __syncthreads();
  int s = l >> 3, t = l & 7;
  float sc = 0.f;
  #pragma unroll
  for (int d = 0; d < 64; d++) sc += qs[s][d] * ks[t][d];
  sc *= 0.125f;
  if (t > s) sc = -1e30f;
  float mx = sc;
  for (int o = 4; o; o >>= 1) mx = fmaxf(mx, __shfl_xor(mx, o, 8));
  float e = __expf(sc - mx);
  float sum = e;
  for (int o = 4; o; o >>= 1) sum += __shfl_xor(sum, o, 8);
  ps[s][t] = e / sum;
  __syncthreads();
  for (int s2 = 0; s2 < 8; s2++) {
    float acc = 0.f;
    #pragma unroll
    for (int t2 = 0; t2 < 8; t2++) acc += ps[s2][t2] * vs[t2][l];
    out[((size_t)(b * 8 + s2)) * DD + h * 64 + l] = f2bf(acc);
  }
}

// ---- Q' build from cq split-K partials: Q' = 0.125 * (p0+p1+cbq) . cWk[h-block] ----
__global__ __launch_bounds__(256) void qprime_k(
    const float* __restrict__ p2, const float* __restrict__ cbq,
    const float* __restrict__ cWk, unsigned short* __restrict__ Qp) {
  int bh = blockIdx.x;              // b*12 + h
  int b = bh / HH, h = bh % HH;
  __shared__ float qs[8][64];
  int tid = threadIdx.x;
  for (int i = tid; i < 512; i += 256) {
    int s = i >> 6, d = i & 63;
    size_t idx = (size_t)(b * 8 + s) * 768 + h * 64 + d;
    qs[s][d] = (p2[idx] + p2[(size_t)RR * DD + idx] + cbq[h * 64 + d]) * 0.125f;
  }
  __syncthreads();
  for (int e = tid; e < 768; e += 256) {
    const float* wr = cWk + (size_t)e * 768 + h * 64;
    float acc[8] = {};
    #pragma unroll 16
    for (int k = 0; k < 64; k++) {
      float wv = wr[k];
      #pragma unroll
      for (int s = 0; s < 8; s++) acc[s] += qs[s][k] * wv;
    }
    #pragma unroll
    for (int s = 0; s < 8; s++)
      Qp[((size_t)b * 128 + h * 8 + s) * 768 + e] = f2bf(acc[s]);
  }
}

// ---------------- cross softmax: S f32 [32][128][1536] -> P bf16 (normalized) ------
__global__ __launch_bounds__(256) void xsoftmax_k(
    const float* __restrict__ S, unsigned short* __restrict__ P) {
  int bh = blockIdx.x;              // b*12 + h
  int b = bh / HH, h = bh % HH;
  int w = threadIdx.x >> 6, ln = threadIdx.x & 63;
  for (int rr = w; rr < 8; rr += 4) {
    size_t row = (size_t)b * 128 + h * 8 + rr;
    const float* sr = S + row * TPAD;
    unsigned short* pr = P + row * TPAD;
    float v[24];
    float mx = -1e30f;
    #pragma unroll
    for (int i = 0; i < 24; i++) {
      int t = ln + i * 64;
      v[i] = (t < AAn) ? sr[t] : -1e30f;
      mx = fmaxf(mx, v[i]);
    }
    for (int o = 32; o; o >>= 1) mx = fmaxf(mx, __shfl_xor(mx, o));
    float sum = 0.f;
    #pragma unroll
    for (int i = 0; i < 24; i++) { v[i] = __expf(v[i] - mx); sum += v[i]; }
    for (int o = 32; o; o >>= 1) sum += __shfl_xor(sum, o);
    float inv = 1.f / sum;
    #pragma unroll
    for (int i = 0; i < 24; i++) {
      int t = ln + i * 64;
      pr[t] = f2bf((t < AAn) ? v[i] * inv : 0.f);
    }
  }
}

// ---------------- host ----------------
static inline void* carve(char*& p, size_t bytes) {
  void* r = p;
  p += (bytes + 255) & ~(size_t)255;
  return r;
}

extern "C" void kernel_launch(void* const* d_in, const int* in_sizes, int n_in,
                              void* d_out, int out_size, void* d_ws, size_t ws_size,
                              hipStream_t stream) {
  const int*   tokens = (const int*)d_in[0];
  const float* audio  = (const float*)d_in[1];
  const float* temb   = (const float*)d_in[2];
  const float* pemb   = (const float*)d_in[3];
  const float* aln_w  = (const float*)d_in[4];
  const float* aln_b  = (const float*)d_in[5];
  const float* Wq = (const float*)d_in[6];
  const float* bq = (const float*)d_in[7];
  const float* Wk = (const float*)d_in[8];
  const float* Wv = (const float*)d_in[9];
  const float* bv = (const float*)d_in[10];
  const float* Wo = (const float*)d_in[11];
  const float* bo = (const float*)d_in[12];
  const float* cln_w = (const float*)d_in[13];
  const float* cln_b = (const float*)d_in[14];
  const float* cWq = (const float*)d_in[15];
  const float* cbq = (const float*)d_in[16];
  const float* cWk = (const float*)d_in[17];
  const float* cWv = (const float*)d_in[18];
  const float* cbv = (const float*)d_in[19];
  const float* cWo = (const float*)d_in[20];
  const float* cbo = (const float*)d_in[21];
  const float* mln_w = (const float*)d_in[22];
  const float* mln_b = (const float*)d_in[23];
  const float* W1 = (const float*)d_in[24];
  const float* b1 = (const float*)d_in[25];
  const float* W2 = (const float*)d_in[26];
  const float* b2 = (const float*)d_in[27];
  const float* lnw = (const float*)d_in[28];
  const float* lnb = (const float*)d_in[29];

  char* cur = (char*)d_ws;
  float* x    = (float*)carve(cur, (size_t)RR * DD * 4);
  float* qkv  = (float*)carve(cur, (size_t)RR * 2304 * 4);
  unsigned short* hb    = (unsigned short*)carve(cur, (size_t)RR * DD * 2);
  unsigned short* attnb = (unsigned short*)carve(cur, (size_t)RR * DD * 2);
  unsigned short* ffb   = (unsigned short*)carve(cur, (size_t)RR * FFD * 2);
  unsigned short* wt    = (unsigned short*)carve(cur, LSTR * 6 * 2);
  unsigned short* audio_bf = (unsigned short*)carve(cur, (size_t)BBn * AAn * DD * 2);
  unsigned short* audioT   = (unsigned short*)carve(cur, (size_t)BBn * DD * TPAD * 2);
  float* Sb = (float*)carve(cur, (size_t)BBn * 128 * TPAD * 4);
  unsigned short* Pb  = (unsigned short*)carve(cur, (size_t)BBn * 128 * TPAD * 2);
  unsigned short* Qp  = (unsigned short*)carve(cur, (size_t)BBn * 128 * DD * 2);
  unsigned short* Rbf = (unsigned short*)carve(cur, (size_t)HH * 256 * DD * 2);
  float* qkvb  = (float*)carve(cur, (size_t)6 * 2304 * 4);
  float* mlp2p = (float*)carve(cur, (size_t)4 * RR * DD * 4);

  auto G64 = [&](const unsigned short* A_, const unsigned short* Bt_, void* C_,
                 const float* bias_, const float* res_, int M_, int Np_,
                 int Klen_, int Kstr_, int Nout_, int Cld_, int op_,
                 int Z_ = 1, long zsA_ = 0, long zsB_ = 0, long zsC_ = 0,
                 long zsBias_ = 0, int kz_ = 0) {
    dim3 g(Np_ / 64, M_ / 64, Z_);
    gemm_t<64, 64, 0><<<g, 256, 0, stream>>>(A_, Bt_, nullptr, 0, C_, bias_, res_,
        Klen_, Kstr_, Nout_, Cld_, zsA_, zsB_, zsC_, zsBias_, kz_, op_);
  };
  auto G128 = [&](const unsigned short* A_, const unsigned short* Bt_, void* C_,
                  const float* bias_, const float* res_, int M_, int Np_,
                  int Klen_, int Kstr_, int Nout_, int Cld_, int op_,
                  int Z_ = 1, long zsA_ = 0, long zsB_ = 0, long zsC_ = 0,
                  long zsBias_ = 0, int kz_ = 0) {
    dim3 g(Np_ / 128, M_ / 128, Z_);
    gemm_t<128, 128, 0><<<g, 256, 0, stream>>>(A_, Bt_, nullptr, 0, C_, bias_, res_,
        Klen_, Kstr_, Nout_, Cld_, zsA_, zsB_, zsC_, zsBias_, kz_, op_);
  };

  embed_k<<<RR, 256, 0, stream>>>(tokens, temb, pemb, x);
  audio_prep<<<dim3(24, 12, BBn), 256, 0, stream>>>(audio, audio_bf, audioT);
  build_biases<<<54, 256, 0, stream>>>(bq, bv, qkvb);

  WPtrs wp;
  wp.p[0] = Wq; wp.p[1] = Wk; wp.p[2] = Wv; wp.p[3] = Wo;
  wp.p[4] = cWq; wp.p[5] = cWk; wp.p[6] = cWv; wp.p[7] = cWo;
  wp.p[8] = W1; wp.p[9] = W2;
  transpose_w<<<dim3(2304, 6, 1), 256, 0, stream>>>(wp, wt);

  // first LN (layer 0 self-attn)
  ln_to_bf16<<<RR, 256, 0, stream>>>(x, aln_w, aln_b, hb);

  for (int l = 0; l < 6; l++) {
    size_t vD = (size_t)l * DD;
    size_t vF = (size_t)l * FFD;
    unsigned short* wtl = wt + (size_t)l * LSTR;

    // --- self attention block (hb already holds LN(x)) ---
    G64(hb, wtl, qkv, qkvb + (size_t)l * 2304, nullptr, RR, 2304, DD, DD, 2304, 2304, OP_BIAS);
    self_attn_k<<<BBn * HH, 64, 0, stream>>>(qkv, attnb);
    // o-proj split-K x2 -> partials; fused residual+LN(cross)
    G64(attnb, wtl + (size_t)3 * MAT, mlp2p, nullptr, nullptr, RR, DD, 384, DD, DD, DD,
        0, 2, 0, 0, (long)RR * DD, 0, 1);
    red_resid_ln<<<RR, 256, 0, stream>>>(mlp2p, 2, bo + vD, x, cln_w + vD, cln_b + vD, hb);

    // --- cross attention block (KV-free formulation) ---
    G64(hb, wtl + (size_t)4 * MAT, mlp2p, nullptr, nullptr, RR, DD, 384, DD, DD, DD,
        0, 2, 0, 0, (long)RR * DD, 0, 1);
    qprime_k<<<BBn * HH, 256, 0, stream>>>(mlp2p, cbq + vD, cWk + (size_t)l * MAT, Qp);
    // scores: per b, S[b] = Qp[b] (128x768) @ audio_b^T  -> [128][1536] f32
    G128(Qp, audio_bf, Sb, nullptr, nullptr, 128, TPAD, DD, DD, TPAD, TPAD, 0,
         BBn, (long)128 * DD, (long)AAn * DD, (long)128 * TPAD, 0, 0);
    xsoftmax_k<<<BBn * HH, 256, 0, stream>>>(Sb, Pb);
    // PV: per b, R = P[b] (128x1536) @ audioT_b^T -> scatter to Rbf[h][b*8+s][e]
    {
      dim3 g(DD / 64, 1, BBn);
      gemm_t<128, 64, 0><<<g, 256, 0, stream>>>(Pb, audioT, nullptr, 0, Rbf, nullptr,
          nullptr, TPAD, TPAD, DD, DD, (long)128 * TPAD, (long)DD * TPAD, 0, 0, 0, OP_SCAT);
    }
    // O head-proj: per h, attnb[.,h*64..] = Rbf[h] @ cWv_h + cbv_h
    G64(Rbf, wtl + (size_t)6 * MAT, attnb, cbv + vD, nullptr, RR, 64, DD, DD, 64, DD,
        OP_BIAS | OP_BF16, HH, (long)256 * DD, (long)64 * DD, 64, 64, 0);
    // co-proj split-K x2 -> partials; fused residual+LN(mlp)
    G64(attnb, wtl + (size_t)7 * MAT, mlp2p, nullptr, nullptr, RR, DD, 384, DD, DD, DD,
        0, 2, 0, 0, (long)RR * DD, 0, 1);
    red_resid_ln<<<RR, 256, 0, stream>>>(mlp2p, 2, cbo + vD, x, mln_w + vD, mln_b + vD, hb);

    // --- MLP block ---
    G64(hb, wtl + (size_t)8 * MAT, ffb, b1 + vF, nullptr, RR, FFD, DD, DD, FFD, FFD,
        OP_BIAS | OP_GELU | OP_BF16);
    G64(ffb, wtl + (size_t)8 * MAT + (size_t)DD * FFD, mlp2p, nullptr, nullptr,
        RR, DD, DD, FFD, DD, DD, 0, 4, 0, 0, (long)RR * DD, 0, 1);
    const float* nw = (l < 5) ? (aln_w + (size_t)(l + 1) * DD) : lnw;
    const float* nb = (l < 5) ? (aln_b + (size_t)(l + 1) * DD) : lnb;
    red_resid_ln<<<RR, 256, 0, stream>>>(mlp2p, 4, b2 + vD, x, nw, nb, hb);
  }

  // --- logits (hb holds final LN); B staged from f32 temb directly ---
  {
    dim3 g(VPAD / 128, RR / 128, 1);
    gemm_t<128, 128, 1><<<g, 256, 0, stream>>>(hb, nullptr, temb, VV, d_out, nullptr,
        nullptr, DD, DD, VV, VV, 0, 0, 0, 0, 0, 0);
  }
}

// Round 9
// 1442.069 us; speedup vs baseline: 3.5099x; 1.0133x over previous
//
#include <hip/hip_runtime.h>
#include <hip/hip_bf16.h>

// Whisper decoder step: L=6, D=768, H=12, FF=3072, V=51865, A=1500, B=32, S=8
#define HH 12
#define DD 768
#define FFD 3072
#define AAn 1500
#define BBn 32
#define RR 256          // B*S token rows
#define VV 51865
#define VPAD 51968      // 406*128
#define MAT (768*768)   // 589824
#define LSTR ((size_t)8 * MAT + 2 * (size_t)DD * FFD)   // wt elements per layer
#define TPAD 1536       // padded audio T

#define OP_BIAS 1
#define OP_GELU 2
#define OP_RES  4
#define OP_BF16 8
#define OP_SCAT 16

typedef float f32x4 __attribute__((ext_vector_type(4)));
typedef short s16x8 __attribute__((ext_vector_type(8)));

__device__ __forceinline__ unsigned short f2bf(float f) {
  union { float f; unsigned int u; } v; v.f = f;
  unsigned int r = (v.u + 0x7fffu + ((v.u >> 16) & 1u)) >> 16;
  return (unsigned short)r;
}
__device__ __forceinline__ float bf2f_lo(unsigned int u) {
  union { unsigned int u; float f; } v; v.u = u << 16; return v.f;
}
__device__ __forceinline__ float bf2f_hi(unsigned int u) {
  union { unsigned int u; float f; } v; v.u = u & 0xffff0000u; return v.f;
}

__device__ __forceinline__ void gld_lds16(const unsigned short* g, unsigned short* l) {
  __builtin_amdgcn_global_load_lds(
      (const __attribute__((address_space(1))) void*)g,
      (__attribute__((address_space(3))) void*)l, 16, 0, 0);
}

// ---------------- embedding ----------------
__global__ void embed_k(const int* __restrict__ toks, const float* __restrict__ emb,
                        const float* __restrict__ pos, float* __restrict__ x) {
  int r = blockIdx.x;
  int s = r & 7;
  int t = toks[r];
  for (int c = threadIdx.x; c < DD; c += 256)
    x[(size_t)r * DD + c] = emb[(size_t)t * DD + c] + pos[(size_t)s * DD + c];
}

// ---------------- build combined qkv bias ----------------
__global__ void build_biases(const float* __restrict__ bq, const float* __restrict__ bv,
                             float* __restrict__ qkvb) {
  int i = blockIdx.x * 256 + threadIdx.x;
  if (i < 6 * 2304) {
    int l = i / 2304, n = i % 2304;
    qkvb[i] = (n < 768) ? bq[l * 768 + n] : (n < 1536 ? 0.f : bv[l * 768 + (n - 1536)]);
  }
}

// ---------------- LayerNorm -> bf16 ----------------
__global__ __launch_bounds__(256) void ln_to_bf16(
    const float* __restrict__ x, const float* __restrict__ w,
    const float* __restrict__ b, unsigned short* __restrict__ out) {
  int row = blockIdx.x;
  const float* xr = x + (size_t)row * DD;
  int t = threadIdx.x;
  float v0 = xr[t], v1 = xr[t + 256], v2 = xr[t + 512];
  float s = v0 + v1 + v2;
  for (int o = 32; o; o >>= 1) s += __shfl_down(s, o);
  __shared__ float red[4], red2[4];
  int wid = t >> 6, lane = t & 63;
  if (!lane) red[wid] = s;
  __syncthreads();
  float mean = (red[0] + red[1] + red[2] + red[3]) * (1.f / DD);
  float d0 = v0 - mean, d1 = v1 - mean, d2 = v2 - mean;
  float s2 = d0 * d0 + d1 * d1 + d2 * d2;
  for (int o = 32; o; o >>= 1) s2 += __shfl_down(s2, o);
  if (!lane) red2[wid] = s2;
  __syncthreads();
  float var = (red2[0] + red2[1] + red2[2] + red2[3]) * (1.f / DD);
  float rstd = rsqrtf(var + 1e-5f);
  out[(size_t)row * DD + t]       = f2bf(d0 * rstd * w[t] + b[t]);
  out[(size_t)row * DD + t + 256] = f2bf(d1 * rstd * w[t + 256] + b[t + 256]);
  out[(size_t)row * DD + t + 512] = f2bf(d2 * rstd * w[t + 512] + b[t + 512]);
}

// ------- fused: x += bias + sum(nparts partials); out = LN(x) as bf16 --------
__global__ __launch_bounds__(256) void red_resid_ln(
    const float* __restrict__ part, int nparts, const float* __restrict__ bias,
    float* __restrict__ x, const float* __restrict__ w,
    const float* __restrict__ b, unsigned short* __restrict__ out) {
  int row = blockIdx.x;
  int t = threadIdx.x;
  float v[3];
  #pragma unroll
  for (int j = 0; j < 3; j++) {
    int c = t + j * 256;
    size_t i = (size_t)row * DD + c;
    float nv = x[i] + bias[c];
    for (int p = 0; p < nparts; p++) nv += part[(size_t)p * RR * DD + i];
    x[i] = nv;
    v[j] = nv;
  }
  float s = v[0] + v[1] + v[2];
  for (int o = 32; o; o >>= 1) s += __shfl_down(s, o);
  __shared__ float red[4], red2[4];
  int wid = t >> 6, lane = t & 63;
  if (!lane) red[wid] = s;
  __syncthreads();
  float mean = (red[0] + red[1] + red[2] + red[3]) * (1.f / DD);
  float d0 = v[0] - mean, d1 = v[1] - mean, d2 = v[2] - mean;
  float s2 = d0 * d0 + d1 * d1 + d2 * d2;
  for (int o = 32; o; o >>= 1) s2 += __shfl_down(s2, o);
  if (!lane) red2[wid] = s2;
  __syncthreads();
  float var = (red2[0] + red2[1] + red2[2] + red2[3]) * (1.f / DD);
  float rstd = rsqrtf(var + 1e-5f);
  out[(size_t)row * DD + t]       = f2bf(d0 * rstd * w[t] + b[t]);
  out[(size_t)row * DD + t + 256] = f2bf(d1 * rstd * w[t + 256] + b[t + 256]);
  out[(size_t)row * DD + t + 512] = f2bf(d2 * rstd * w[t + 512] + b[t + 512]);
}

// ---------- vectorized transpose of ALL layer weights -> bf16 (64x64 tiles) -------
struct WPtrs { const float* p[10]; };
__global__ __launch_bounds__(256) void transpose_w(
    WPtrs wp, unsigned short* __restrict__ dst) {
  int l = blockIdx.y;
  int idx = blockIdx.x;
  int zz, ct, rt, R, C;
  if (idx < 1152)      { zz = idx / 144; int t = idx % 144; ct = t % 12; rt = t / 12; R = DD; C = DD; }
  else if (idx < 1728) { zz = 8; int t = idx - 1152; ct = t % 48; rt = t / 48; R = DD; C = FFD; }
  else                 { zz = 9; int t = idx - 1728; rt = t % 48; ct = t / 48; R = FFD; C = DD; }
  const float* W = wp.p[zz] + (size_t)l * ((zz < 8) ? MAT : (size_t)DD * FFD);
  size_t doff = (zz < 8) ? (size_t)zz * MAT
                         : ((zz == 8) ? (size_t)8 * MAT : (size_t)8 * MAT + (size_t)FFD * DD);
  unsigned short* Wt = dst + (size_t)l * LSTR + doff;
  __shared__ unsigned short tile[64][65];
  int r0 = rt * 64, c0 = ct * 64;
  int tid = threadIdx.x;
  int rr = tid >> 3, cc = (tid & 7) * 8;
  #pragma unroll
  for (int j = 0; j < 2; j++) {
    int r = r0 + j * 32 + rr;
    const float* sp = W + (size_t)r * C + c0 + cc;
    float4 f0 = *(const float4*)sp, f1 = *(const float4*)(sp + 4);
    unsigned short* tp = &tile[j * 32 + rr][cc];
    tp[0] = f2bf(f0.x); tp[1] = f2bf(f0.y); tp[2] = f2bf(f0.z); tp[3] = f2bf(f0.w);
    tp[4] = f2bf(f1.x); tp[5] = f2bf(f1.y); tp[6] = f2bf(f1.z); tp[7] = f2bf(f1.w);
  }
  __syncthreads();
  #pragma unroll
  for (int j = 0; j < 2; j++) {
    int c = c0 + j * 32 + rr;       // output row
    union { unsigned short us[8]; s16x8 v; } pk;
    #pragma unroll
    for (int i = 0; i < 8; i++) pk.us[i] = tile[cc + i][j * 32 + rr];
    *(s16x8*)&Wt[(size_t)c * R + r0 + cc] = pk.v;
  }
}

// ------- vectorized audio prep: f32 [b][1500][768] -> bf16 straight + transposed ---
__global__ __launch_bounds__(256) void audio_prep(
    const float* __restrict__ audio, unsigned short* __restrict__ a_bf,
    unsigned short* __restrict__ aT) {
  int b = blockIdx.z;
  int t0 = blockIdx.x * 64, e0 = blockIdx.y * 64;
  __shared__ unsigned short tile[64][65];
  int tid = threadIdx.x;
  const float* src = audio + (size_t)b * AAn * DD;
  unsigned short* dstb = a_bf + (size_t)b * AAn * DD;
  int rr = tid >> 3, cc = (tid & 7) * 8;
  #pragma unroll
  for (int j = 0; j < 2; j++) {
    int t = t0 + j * 32 + rr;
    union { unsigned short us[8]; s16x8 v; } pk;
    if (t < AAn) {
      const float* sp = src + (size_t)t * DD + e0 + cc;
      float4 f0 = *(const float4*)sp, f1 = *(const float4*)(sp + 4);
      pk.us[0] = f2bf(f0.x); pk.us[1] = f2bf(f0.y); pk.us[2] = f2bf(f0.z); pk.us[3] = f2bf(f0.w);
      pk.us[4] = f2bf(f1.x); pk.us[5] = f2bf(f1.y); pk.us[6] = f2bf(f1.z); pk.us[7] = f2bf(f1.w);
      *(s16x8*)&dstb[(size_t)t * DD + e0 + cc] = pk.v;
    } else {
      #pragma unroll
      for (int i = 0; i < 8; i++) pk.us[i] = 0;
    }
    unsigned short* tp = &tile[j * 32 + rr][cc];
    #pragma unroll
    for (int i = 0; i < 8; i++) tp[i] = pk.us[i];
  }
  __syncthreads();
  unsigned short* dstT = aT + (size_t)b * DD * TPAD;
  #pragma unroll
  for (int j = 0; j < 2; j++) {
    int e = e0 + j * 32 + rr;       // output row
    union { unsigned short us[8]; s16x8 v; } pk;
    #pragma unroll
    for (int i = 0; i < 8; i++) pk.us[i] = tile[cc + i][j * 32 + rr];
    *(s16x8*)&dstT[(size_t)e * TPAD + t0 + cc] = pk.v;
  }
}

// ---------------- GEMM: C[M][*] = A[M][Klen](bf16) * Bt[N][Klen](bf16)^T ------------
// BK=64. Template tile BM x BN; BF32=1 stages B from f32 src (rows >= NrowsB = 0).
// grid mapping gmap: 0 = (x=n, y=m, z=batch); 1 = (x=batch, y=m, z=n) so that
// linear id = b + gridX*n keeps all n-tiles of one batch on one XCD; 2 = 1D pair
// map for logits: id -> n=(id>>4)*8+(id&7), m=(id>>3)&1 (ids i,i+8 same XCD).
// Per-z offsets zsA/zsB/zsC/zsBias (elements). kz=1: split-K.
// OP_SCAT: write bf16 at [(r>>3)*256 + z*8 + (r&7)]*768 + c, rows r>>3<12 only.
template <int BM, int BN, int BF32>
__global__ __launch_bounds__(256, 2) void gemm_t(
    const unsigned short* __restrict__ A, const unsigned short* __restrict__ Bt,
    const float* __restrict__ Bf32, int NrowsB,
    void* __restrict__ Cv, const float* __restrict__ bias,
    const float* __restrict__ resid, int Klen, int Kstride, int Nout, int Cld,
    long zsA, long zsB, long zsC, long zsBias, int kz, int gmap, int op) {
  constexpr int WM = BM / 2, WN = BN / 2;
  constexpr int MREP = WM / 16, NREP = WN / 16;
  __shared__ unsigned short As[BM * 64];
  __shared__ unsigned short Bs[BN * 64];
  int bx = blockIdx.x, by = blockIdx.y, bz = blockIdx.z;
  if (gmap == 1) { int t = bx; bx = bz; bz = t; }
  else if (gmap == 2) {
    int id = bx;
    bx = (id >> 4) * 8 + (id & 7);
    by = (id >> 3) & 1;
    bz = 0;
  }
  const int n0 = bx * BN, m0 = by * BM;
  const int z = bz;
  const int kbeg = kz ? z * Klen : 0;
  const int tid = threadIdx.x, w = tid >> 6, l = tid & 63;
  const int wr = w >> 1, wc = w & 1;
  f32x4 acc[MREP][NREP] = {};

  const int rowA = l >> 3;        // 0..7 within an 8-row staging group
  const int colK = (l & 7) * 8;   // 0..56
  const unsigned short* gA =
      A + (size_t)z * zsA + (size_t)(m0 + w * (BM / 4) + rowA) * Kstride + colK + kbeg;
  const unsigned short* gB = nullptr;
  if constexpr (!BF32)
    gB = Bt + (size_t)z * zsB + (size_t)(n0 + w * (BN / 4) + rowA) * Kstride + colK + kbeg;

  for (int k0 = 0; k0 < Klen; k0 += 64) {
    __syncthreads();
    #pragma unroll
    for (int p = 0; p < BM / 32; p++)
      gld_lds16(gA + (size_t)(p * 8) * Kstride + k0, &As[(w * (BM / 4) + p * 8) * 64]);
    if constexpr (!BF32) {
      #pragma unroll
      for (int p = 0; p < BN / 32; p++)
        gld_lds16(gB + (size_t)(p * 8) * Kstride + k0, &Bs[(w * (BN / 4) + p * 8) * 64]);
    } else {
      #pragma unroll
      for (int p = 0; p < BN / 32; p++) {
        int grow = n0 + w * (BN / 4) + p * 8 + rowA;
        float4 f0 = make_float4(0.f, 0.f, 0.f, 0.f), f1 = f0;
        if (grow < NrowsB) {
          const float* srcp = Bf32 + (size_t)grow * Kstride + colK + k0 + kbeg;
          f0 = *(const float4*)srcp;
          f1 = *(const float4*)(srcp + 4);
        }
        union { unsigned short us[8]; s16x8 v; } pk;
        pk.us[0] = f2bf(f0.x); pk.us[1] = f2bf(f0.y);
        pk.us[2] = f2bf(f0.z); pk.us[3] = f2bf(f0.w);
        pk.us[4] = f2bf(f1.x); pk.us[5] = f2bf(f1.y);
        pk.us[6] = f2bf(f1.z); pk.us[7] = f2bf(f1.w);
        *(s16x8*)&Bs[(size_t)(w * (BN / 4) + p * 8 + rowA) * 64 + colK] = pk.v;
      }
    }
    __syncthreads();
    s16x8 aF[MREP][2], bF[NREP][2];
    #pragma unroll
    for (int m = 0; m < MREP; m++)
      #pragma unroll
      for (int kk = 0; kk < 2; kk++)
        aF[m][kk] = *(const s16x8*)&As[(wr * WM + m * 16 + (l & 15)) * 64 + kk * 32 + (l >> 4) * 8];
    #pragma unroll
    for (int n = 0; n < NREP; n++)
      #pragma unroll
      for (int kk = 0; kk < 2; kk++)
        bF[n][kk] = *(const s16x8*)&Bs[(wc * WN + n * 16 + (l & 15)) * 64 + kk * 32 + (l >> 4) * 8];
    #pragma unroll
    for (int m = 0; m < MREP; m++)
      #pragma unroll
      for (int n = 0; n < NREP; n++)
        #pragma unroll
        for (int kk = 0; kk < 2; kk++)
          acc[m][n] = __builtin_amdgcn_mfma_f32_16x16x32_bf16(aF[m][kk], bF[n][kk], acc[m][n], 0, 0, 0);
  }

  const float* biasz = (op & OP_BIAS) ? bias + (size_t)z * zsBias : nullptr;
  #pragma unroll
  for (int m = 0; m < MREP; m++) {
    int rr0 = m0 + wr * WM + m * 16 + (l >> 4) * 4;
    #pragma unroll
    for (int n = 0; n < NREP; n++) {
      int c = n0 + wc * WN + n * 16 + (l & 15);
      if (c < Nout) {
        float bval = (op & OP_BIAS) ? biasz[c] : 0.f;
        #pragma unroll
        for (int j = 0; j < 4; j++) {
          int r = rr0 + j;
          float val = acc[m][n][j] + bval;
          if (op & OP_GELU) val = 0.5f * val * (1.f + erff(val * 0.70710678118f));
          if (op & OP_RES)  val += resid[(size_t)r * Cld + c];
          if (op & OP_SCAT) {
            int hh = r >> 3;
            if (hh < HH)
              ((unsigned short*)Cv)[((size_t)hh * 256 + z * 8 + (r & 7)) * 768 + c] = f2bf(val);
          } else if (op & OP_BF16) {
            ((unsigned short*)Cv)[(size_t)z * zsC + (size_t)r * Cld + c] = f2bf(val);
          } else {
            ((float*)Cv)[(size_t)z * zsC + (size_t)r * Cld + c] = val;
          }
        }
      }
    }
  }
}

// ---------------- self attention (S=8, causal), q/k/v packed [256][2304] ----------
__global__ __launch_bounds__(64) void self_attn_k(
    const float* __restrict__ qkv, unsigned short* __restrict__ out) {
  int bh = blockIdx.x;
  int b = bh / HH, h = bh % HH;
  __shared__ float qs[8][65], ks[8][65], vs[8][65], ps[8][9];
  int l = threadIdx.x;
  for (int s = 0; s < 8; s++) {
    size_t base = ((size_t)(b * 8 + s)) * 2304 + h * 64 + l;
    qs[s][l] = qkv[base]; ks[s][l] = qkv[base + 768]; vs[s][l] = qkv[base + 1536];
  }
  __syncthreads();
  int s = l >> 3, t = l & 7;
  float sc = 0.f;
  #pragma unroll
  for (int d = 0; d < 64; d++) sc += qs[s][d] * ks[t][d];
  sc *= 0.125f;
  if (t > s) sc = -1e30f;
  float mx = sc;
  for (int o = 4; o; o >>= 1) mx = fmaxf(mx, __shfl_xor(mx, o, 8));
  float e = __expf(sc - mx);
  float sum = e;
  for (int o = 4; o; o >>= 1) sum += __shfl_xor(sum, o, 8);
  ps[s][t] = e / sum;
  __syncthreads();
  for (int s2 = 0; s2 < 8; s2++) {
    float acc = 0.f;
    #pragma unroll
    for (int t2 = 0; t2 < 8; t2++) acc += ps[s2][t2] * vs[t2][l];
    out[((size_t)(b * 8 + s2)) * DD + h * 64 + l] = f2bf(acc);
  }
}

// ---- Q' build from cq split-K partials: Q' = 0.125 * (p0+p1+cbq) . cWk[h-block] ----
__global__ __launch_bounds__(256) void qprime_k(
    const float* __restrict__ p2, const float* __restrict__ cbq,
    const float* __restrict__ cWk, unsigned short* __restrict__ Qp) {
  int bh = blockIdx.x;              // b*12 + h
  int b = bh / HH, h = bh % HH;
  __shared__ float qs[8][64];
  int tid = threadIdx.x;
  for (int i = tid; i < 512; i += 256) {
    int s = i >> 6, d = i & 63;
    size_t idx = (size_t)(b * 8 + s) * 768 + h * 64 + d;
    qs[s][d] = (p2[idx] + p2[(size_t)RR * DD + idx] + cbq[h * 64 + d]) * 0.125f;
  }
  __syncthreads();
  for (int e = tid; e < 768; e += 256) {
    const float* wr = cWk + (size_t)e * 768 + h * 64;
    float acc[8] = {};
    #pragma unroll 16
    for (int k = 0; k < 64; k++) {
      float wv = wr[k];
      #pragma unroll
      for (int s = 0; s < 8; s++) acc[s] += qs[s][k] * wv;
    }
    #pragma unroll
    for (int s = 0; s < 8; s++)
      Qp[((size_t)b * 128 + h * 8 + s) * 768 + e] = f2bf(acc[s]);
  }
}

// -------- cross softmax: S bf16 [32][128][1536] -> P bf16 (normalized) -------------
__global__ __launch_bounds__(256) void xsoftmax_k(
    const unsigned short* __restrict__ S, unsigned short* __restrict__ P) {
  int bh = blockIdx.x;              // b*12 + h
  int b = bh / HH, h = bh % HH;
  int w = threadIdx.x >> 6, ln = threadIdx.x & 63;
  for (int rr = w; rr < 8; rr += 4) {
    size_t row = (size_t)b * 128 + h * 8 + rr;
    const unsigned int* sr = (const unsigned int*)(S + row * TPAD);
    unsigned int* pr = (unsigned int*)(P + row * TPAD);
    float v[24];
    float mx = -1e30f;
    #pragma unroll
    for (int i = 0; i < 12; i++) {
      unsigned int u = sr[ln + i * 64];
      int t0 = 2 * (ln + i * 64);
      v[2 * i]     = (t0 < AAn)     ? bf2f_lo(u) : -1e30f;
      v[2 * i + 1] = (t0 + 1 < AAn) ? bf2f_hi(u) : -1e30f;
      mx = fmaxf(mx, fmaxf(v[2 * i], v[2 * i + 1]));
    }
    for (int o = 32; o; o >>= 1) mx = fmaxf(mx, __shfl_xor(mx, o));
    float sum = 0.f;
    #pragma unroll
    for (int i = 0; i < 24; i++) { v[i] = __expf(v[i] - mx); sum += v[i]; }
    for (int o = 32; o; o >>= 1) sum += __shfl_xor(sum, o);
    float inv = 1.f / sum;
    #pragma unroll
    for (int i = 0; i < 12; i++) {
      int t0 = 2 * (ln + i * 64);
      unsigned int lo = (t0 < AAn)     ? f2bf(v[2 * i] * inv)     : 0;
      unsigned int hi = (t0 + 1 < AAn) ? f2bf(v[2 * i + 1] * inv) : 0;
      pr[ln + i * 64] = lo | (hi << 16);
    }
  }
}

// ---------------- host ----------------
static inline void* carve(char*& p, size_t bytes) {
  void* r = p;
  p += (bytes + 255) & ~(size_t)255;
  return r;
}

extern "C" void kernel_launch(void* const* d_in, const int* in_sizes, int n_in,
                              void* d_out, int out_size, void* d_ws, size_t ws_size,
                              hipStream_t stream) {
  const int*   tokens = (const int*)d_in[0];
  const float* audio  = (const float*)d_in[1];
  const float* temb   = (const float*)d_in[2];
  const float* pemb   = (const float*)d_in[3];
  const float* aln_w  = (const float*)d_in[4];
  const float* aln_b  = (const float*)d_in[5];
  const float* Wq = (const float*)d_in[6];
  const float* bq = (const float*)d_in[7];
  const float* Wk = (const float*)d_in[8];
  const float* Wv = (const float*)d_in[9];
  const float* bv = (const float*)d_in[10];
  const float* Wo = (const float*)d_in[11];
  const float* bo = (const float*)d_in[12];
  const float* cln_w = (const float*)d_in[13];
  const float* cln_b = (const float*)d_in[14];
  const float* cWq = (const float*)d_in[15];
  const float* cbq = (const float*)d_in[16];
  const float* cWk = (const float*)d_in[17];
  const float* cWv = (const float*)d_in[18];
  const float* cbv = (const float*)d_in[19];
  const float* cWo = (const float*)d_in[20];
  const float* cbo = (const float*)d_in[21];
  const float* mln_w = (const float*)d_in[22];
  const float* mln_b = (const float*)d_in[23];
  const float* W1 = (const float*)d_in[24];
  const float* b1 = (const float*)d_in[25];
  const float* W2 = (const float*)d_in[26];
  const float* b2 = (const float*)d_in[27];
  const float* lnw = (const float*)d_in[28];
  const float* lnb = (const float*)d_in[29];

  char* cur = (char*)d_ws;
  float* x    = (float*)carve(cur, (size_t)RR * DD * 4);
  float* qkv  = (float*)carve(cur, (size_t)RR * 2304 * 4);
  unsigned short* hb    = (unsigned short*)carve(cur, (size_t)RR * DD * 2);
  unsigned short* attnb = (unsigned short*)carve(cur, (size_t)RR * DD * 2);
  unsigned short* ffb   = (unsigned short*)carve(cur, (size_t)RR * FFD * 2);
  unsigned short* wt    = (unsigned short*)carve(cur, LSTR * 6 * 2);
  unsigned short* audio_bf = (unsigned short*)carve(cur, (size_t)BBn * AAn * DD * 2);
  unsigned short* audioT   = (unsigned short*)carve(cur, (size_t)BBn * DD * TPAD * 2);
  unsigned short* Sb = (unsigned short*)carve(cur, (size_t)BBn * 128 * TPAD * 2);
  unsigned short* Pb  = (unsigned short*)carve(cur, (size_t)BBn * 128 * TPAD * 2);
  unsigned short* Qp  = (unsigned short*)carve(cur, (size_t)BBn * 128 * DD * 2);
  unsigned short* Rbf = (unsigned short*)carve(cur, (size_t)HH * 256 * DD * 2);
  float* qkvb  = (float*)carve(cur, (size_t)6 * 2304 * 4);
  float* mlp2p = (float*)carve(cur, (size_t)4 * RR * DD * 4);

  auto G64 = [&](const unsigned short* A_, const unsigned short* Bt_, void* C_,
                 const float* bias_, const float* res_, int M_, int Np_,
                 int Klen_, int Kstr_, int Nout_, int Cld_, int op_,
                 int Z_ = 1, long zsA_ = 0, long zsB_ = 0, long zsC_ = 0,
                 long zsBias_ = 0, int kz_ = 0) {
    dim3 g(Np_ / 64, M_ / 64, Z_);
    gemm_t<64, 64, 0><<<g, 256, 0, stream>>>(A_, Bt_, nullptr, 0, C_, bias_, res_,
        Klen_, Kstr_, Nout_, Cld_, zsA_, zsB_, zsC_, zsBias_, kz_, 0, op_);
  };

  embed_k<<<RR, 256, 0, stream>>>(tokens, temb, pemb, x);
  audio_prep<<<dim3(24, 12, BBn), 256, 0, stream>>>(audio, audio_bf, audioT);
  build_biases<<<54, 256, 0, stream>>>(bq, bv, qkvb);

  WPtrs wp;
  wp.p[0] = Wq; wp.p[1] = Wk; wp.p[2] = Wv; wp.p[3] = Wo;
  wp.p[4] = cWq; wp.p[5] = cWk; wp.p[6] = cWv; wp.p[7] = cWo;
  wp.p[8] = W1; wp.p[9] = W2;
  transpose_w<<<dim3(2304, 6, 1), 256, 0, stream>>>(wp, wt);

  // first LN (layer 0 self-attn)
  ln_to_bf16<<<RR, 256, 0, stream>>>(x, aln_w, aln_b, hb);

  for (int l = 0; l < 6; l++) {
    size_t vD = (size_t)l * DD;
    size_t vF = (size_t)l * FFD;
    unsigned short* wtl = wt + (size_t)l * LSTR;

    // --- self attention block (hb already holds LN(x)) ---
    G64(hb, wtl, qkv, qkvb + (size_t)l * 2304, nullptr, RR, 2304, DD, DD, 2304, 2304, OP_BIAS);
    self_attn_k<<<BBn * HH, 64, 0, stream>>>(qkv, attnb);
    // o-proj split-K x2 -> partials; fused residual+LN(cross)
    G64(attnb, wtl + (size_t)3 * MAT, mlp2p, nullptr, nullptr, RR, DD, 384, DD, DD, DD,
        0, 2, 0, 0, (long)RR * DD, 0, 1);
    red_resid_ln<<<RR, 256, 0, stream>>>(mlp2p, 2, bo + vD, x, cln_w + vD, cln_b + vD, hb);

    // --- cross attention block (KV-free formulation) ---
    G64(hb, wtl + (size_t)4 * MAT, mlp2p, nullptr, nullptr, RR, DD, 384, DD, DD, DD,
        0, 2, 0, 0, (long)RR * DD, 0, 1);
    qprime_k<<<BBn * HH, 256, 0, stream>>>(mlp2p, cbq + vD, cWk + (size_t)l * MAT, Qp);
    // scores: per b, S[b] = Qp[b] (128x768) @ audio_b^T -> [128][1536] bf16
    // gmap=1: grid (b, 1, n-tile) -> all n-tiles of b on XCD b%8 (Qp L2-resident)
    {
      dim3 g(BBn, 1, TPAD / 128);
      gemm_t<128, 128, 0><<<g, 256, 0, stream>>>(Qp, audio_bf, nullptr, 0, Sb, nullptr,
          nullptr, DD, DD, TPAD, TPAD, (long)128 * DD, (long)AAn * DD,
          (long)128 * TPAD, 0, 0, 1, OP_BF16);
    }
    xsoftmax_k<<<BBn * HH, 256, 0, stream>>>(Sb, Pb);
    // PV: per b, R = P[b] (128x1536) @ audioT_b^T -> scatter to Rbf[h][b*8+s][e]
    {
      dim3 g(BBn, 1, DD / 64);
      gemm_t<128, 64, 0><<<g, 256, 0, stream>>>(Pb, audioT, nullptr, 0, Rbf, nullptr,
          nullptr, TPAD, TPAD, DD, DD, (long)128 * TPAD, (long)DD * TPAD, 0, 0, 0, 1, OP_SCAT);
    }
    // O head-proj: per h, attnb[.,h*64..] = Rbf[h] @ cWv_h + cbv_h
    G64(Rbf, wtl + (size_t)6 * MAT, attnb, cbv + vD, nullptr, RR, 64, DD, DD, 64, DD,
        OP_BIAS | OP_BF16, HH, (long)256 * DD, (long)64 * DD, 64, 64, 0);
    // co-proj split-K x2 -> partials; fused residual+LN(mlp)
    G64(attnb, wtl + (size_t)7 * MAT, mlp2p, nullptr, nullptr, RR, DD, 384, DD, DD, DD,
        0, 2, 0, 0, (long)RR * DD, 0, 1);
    red_resid_ln<<<RR, 256, 0, stream>>>(mlp2p, 2, cbo + vD, x, mln_w + vD, mln_b + vD, hb);

    // --- MLP block ---
    G64(hb, wtl + (size_t)8 * MAT, ffb, b1 + vF, nullptr, RR, FFD, DD, DD, FFD, FFD,
        OP_BIAS | OP_GELU | OP_BF16);
    G64(ffb, wtl + (size_t)8 * MAT + (size_t)DD * FFD, mlp2p, nullptr, nullptr,
        RR, DD, DD, FFD, DD, DD, 0, 4, 0, 0, (long)RR * DD, 0, 1);
    const float* nw = (l < 5) ? (aln_w + (size_t)(l + 1) * DD) : lnw;
    const float* nb = (l < 5) ? (aln_b + (size_t)(l + 1) * DD) : lnb;
    red_resid_ln<<<RR, 256, 0, stream>>>(mlp2p, 4, b2 + vD, x, nw, nb, hb);
  }

  // --- logits (hb holds final LN); B staged from f32 temb; gmap=2 pairs the two
  // m-tiles of each n-tile onto the same XCD so each temb row is fetched once ---
  {
    dim3 g(816, 1, 1);
    gemm_t<128, 128, 1><<<g, 256, 0, stream>>>(hb, nullptr, temb, VV, d_out, nullptr,
        nullptr, DD, DD, VV, VV, 0, 0, 0, 0, 0, 2, 0);
  }
}